// Round 6
// baseline (494.430 us; speedup 1.0000x reference)
//
#include <hip/hip_runtime.h>
#include <math.h>

// Problem constants (fixed by reference)
#define S   8000     // L = 20*20*20
#define BB  2
#define CC  96
#define DI  192      // d_inner
#define NS  16       // d_state
#define RK  6        // dt_rank
#define GG  6        // B * 3 directions
#define NC  250      // scan chunks
#define LC  32       // chunk length
#define ND  38       // dt_rank + 2*d_state

// l -> pos mapping per direction.
__device__ __forceinline__ int pos_from_l(int dir, int l) {
  if (dir == 0) return l;
  int a  = l / 400;
  int r  = l - a * 400;
  int bq = r / 20;
  int cq = r - bq * 20;
  if (dir == 1) return cq * 400 + a * 20 + bq;   // (h=a, w=bq, d=cq)
  return bq * 400 + cq * 20 + a;                 // (w=a, d=bq, h=cq)
}

// q[s] = r^(s+1), squaring ladder: 15 muls, dep depth <= 5
__device__ __forceinline__ void pow_ladder(float r, float* q) {
  float r2 = r * r, r4 = r2 * r2, r8 = r4 * r4;
  q[0] = r;        q[1] = r2;       q[2] = r2 * r;   q[3] = r4;
  q[4] = r4 * r;   q[5] = r4 * r2;  q[6] = q[5] * r; q[7] = r8;
  q[8] = r8 * r;   q[9] = r8 * r2;  q[10] = q[9] * r; q[11] = r8 * r4;
  q[12] = q[11] * r; q[13] = q[11] * r2; q[14] = q[13] * r; q[15] = r8 * r8;
}

// ---------------- K0: double LayerNorm over channels (per position) -------
__global__ __launch_bounds__(256) void k_ln2(const float* __restrict__ x,
    const float* __restrict__ lnw, const float* __restrict__ lnb,
    const float* __restrict__ mlnw, const float* __restrict__ mlnb,
    float* __restrict__ xn) {
  int t = blockIdx.x * blockDim.x + threadIdx.x;
  if (t >= BB * S) return;
  int b = t / S, pos = t - b * S;
  const float* xp = x + (size_t)b * CC * S + pos;
  float s1 = 0.f, s2 = 0.f;
  for (int c = 0; c < CC; ++c) { float v = xp[(size_t)c * S]; s1 += v; s2 += v * v; }
  float u = s1 * (1.f / CC);
  float var = s2 * (1.f / CC) - u * u;
  float rstd = rsqrtf(var + 1e-6f);
  float t1 = 0.f, t2 = 0.f;
  for (int c = 0; c < CC; ++c) {
    float y1 = fmaf(lnw[c], (xp[(size_t)c * S] - u) * rstd, lnb[c]);
    t1 += y1; t2 += y1 * y1;
  }
  float u2 = t1 * (1.f / CC);
  float var2 = t2 * (1.f / CC) - u2 * u2;
  float rstd2 = rsqrtf(var2 + 1e-5f);
  float* o = xn + (size_t)t * CC;
  for (int c = 0; c < CC; ++c) {
    float y1 = fmaf(lnw[c], (xp[(size_t)c * S] - u) * rstd, lnb[c]);
    o[c] = fmaf(mlnw[c], (y1 - u2) * rstd2, mlnb[c]);
  }
}

// ---------------- single LayerNorm (B,C,S) -> (B*S,C) --------------------
__global__ __launch_bounds__(256) void k_ln1(const float* __restrict__ xi,
    const float* __restrict__ lnw, const float* __restrict__ lnb,
    float* __restrict__ out) {
  int t = blockIdx.x * blockDim.x + threadIdx.x;
  if (t >= BB * S) return;
  int b = t / S, pos = t - b * S;
  const float* xp = xi + (size_t)b * CC * S + pos;
  float s1 = 0.f, s2 = 0.f;
  for (int c = 0; c < CC; ++c) { float v = xp[(size_t)c * S]; s1 += v; s2 += v * v; }
  float u = s1 * (1.f / CC);
  float var = s2 * (1.f / CC) - u * u;
  float rstd = rsqrtf(var + 1e-6f);
  float* o = out + (size_t)t * CC;
  for (int c = 0; c < CC; ++c)
    o[c] = fmaf(lnw[c], (xp[(size_t)c * S] - u) * rstd, lnb[c]);
}

// -------- old 64x64 fp32 GEMM (kept for Wx: N=38, K=192) -----------------
template <int ACT, bool BIAS, bool RESID, bool OUT_BCS>
__global__ __launch_bounds__(256) void k_gemm(const float* __restrict__ A,
    const float* __restrict__ Bw, const float* __restrict__ bias,
    const float* __restrict__ resid, float* __restrict__ Cmat,
    int M, int N, int K) {
  __shared__ float As[16][68];
  __shared__ float Bs[16][68];
  int tid = threadIdx.x;
  int tx = tid & 15, ty = tid >> 4;
  int m0 = blockIdx.x * 64, n0 = blockIdx.y * 64;
  float acc[4][4] = {};
  for (int kk = 0; kk < K; kk += 16) {
#pragma unroll
    for (int i = 0; i < 4; ++i) {
      int idx = tid + i * 256;
      int am = idx >> 4, ak = idx & 15;
      As[ak][am] = A[(size_t)(m0 + am) * K + kk + ak];
    }
#pragma unroll
    for (int i = 0; i < 4; ++i) {
      int idx = tid + i * 256;
      int bn = idx >> 4, bk = idx & 15;
      Bs[bk][bn] = (n0 + bn < N) ? Bw[(size_t)(n0 + bn) * K + kk + bk] : 0.f;
    }
    __syncthreads();
#pragma unroll
    for (int k = 0; k < 16; ++k) {
      float4 av = *(const float4*)&As[k][ty * 4];
      float4 bv = *(const float4*)&Bs[k][tx * 4];
      acc[0][0] = fmaf(av.x, bv.x, acc[0][0]);
      acc[0][1] = fmaf(av.x, bv.y, acc[0][1]);
      acc[0][2] = fmaf(av.x, bv.z, acc[0][2]);
      acc[0][3] = fmaf(av.x, bv.w, acc[0][3]);
      acc[1][0] = fmaf(av.y, bv.x, acc[1][0]);
      acc[1][1] = fmaf(av.y, bv.y, acc[1][1]);
      acc[1][2] = fmaf(av.y, bv.z, acc[1][2]);
      acc[1][3] = fmaf(av.y, bv.w, acc[1][3]);
      acc[2][0] = fmaf(av.z, bv.x, acc[2][0]);
      acc[2][1] = fmaf(av.z, bv.y, acc[2][1]);
      acc[2][2] = fmaf(av.z, bv.z, acc[2][2]);
      acc[2][3] = fmaf(av.z, bv.w, acc[2][3]);
      acc[3][0] = fmaf(av.w, bv.x, acc[3][0]);
      acc[3][1] = fmaf(av.w, bv.y, acc[3][1]);
      acc[3][2] = fmaf(av.w, bv.z, acc[3][2]);
      acc[3][3] = fmaf(av.w, bv.w, acc[3][3]);
    }
    __syncthreads();
  }
#pragma unroll
  for (int i = 0; i < 4; ++i) {
    int m = m0 + ty * 4 + i;
#pragma unroll
    for (int j = 0; j < 4; ++j) {
      int n = n0 + tx * 4 + j;
      if (n < N) {
        float v = acc[i][j];
        if (BIAS) v += bias[n];
        if (ACT == 1) v = 0.5f * v * (1.f + erff(v * 0.70710678118654752f));
        if (RESID || OUT_BCS) {
          int bb = m / S, pp = m - bb * S;
          size_t oidx = ((size_t)bb * CC + n) * S + pp;
          if (RESID) v += resid[oidx];
          if (OUT_BCS) { Cmat[oidx] = v; continue; }
        }
        Cmat[(size_t)m * N + n] = v;
      }
    }
  }
}

// -------- new big-tile fp32 GEMM: BMxBN tile, TMxTN micro, 256 thr -------
template <int BM, int BN, int TM, int TN, int ACT, bool BIAS, bool RESID, bool OUT_BCS>
__global__ __launch_bounds__(256) void k_gemm2(const float* __restrict__ A,
    const float* __restrict__ Bw, const float* __restrict__ bias,
    const float* __restrict__ resid, float* __restrict__ Cmat,
    int M, int N, int K) {
  constexpr int BK = 16;
  constexpr int NTX = BN / TN;   // threads along N
  constexpr int NTY = BM / TM;   // threads along M (NTX*NTY == 256)
  static_assert(NTX * NTY == 256, "bad tile cfg");
  __shared__ float As[BK][BM + 4];
  __shared__ float Bs[BK][BN + 4];
  int tid = threadIdx.x;
  int tx = tid % NTX, ty = tid / NTX;
  int m0 = blockIdx.x * BM, n0 = blockIdx.y * BN;
  float acc[TM][TN] = {};
  int r = tid >> 2, cq = tid & 3;       // 64 rows x 4 float4 chunks per pass
  for (int kk = 0; kk < K; kk += BK) {
#pragma unroll
    for (int rr = 0; rr < BM; rr += 64) {
      float4 v = *(const float4*)&A[(size_t)(m0 + rr + r) * K + kk + cq * 4];
      As[cq * 4 + 0][rr + r] = v.x; As[cq * 4 + 1][rr + r] = v.y;
      As[cq * 4 + 2][rr + r] = v.z; As[cq * 4 + 3][rr + r] = v.w;
    }
#pragma unroll
    for (int rr = 0; rr < BN; rr += 64) {
      int n = n0 + rr + r;
      float4 v = make_float4(0.f, 0.f, 0.f, 0.f);
      if (n < N) v = *(const float4*)&Bw[(size_t)n * K + kk + cq * 4];
      Bs[cq * 4 + 0][rr + r] = v.x; Bs[cq * 4 + 1][rr + r] = v.y;
      Bs[cq * 4 + 2][rr + r] = v.z; Bs[cq * 4 + 3][rr + r] = v.w;
    }
    __syncthreads();
#pragma unroll
    for (int k = 0; k < BK; ++k) {
      float a[TM], b[TN];
#pragma unroll
      for (int i = 0; i < TM; i += 4)
        *(float4*)&a[i] = *(const float4*)&As[k][ty * TM + i];
#pragma unroll
      for (int j = 0; j < TN; j += 4)
        *(float4*)&b[j] = *(const float4*)&Bs[k][tx * TN + j];
#pragma unroll
      for (int i = 0; i < TM; ++i)
#pragma unroll
        for (int j = 0; j < TN; ++j)
          acc[i][j] = fmaf(a[i], b[j], acc[i][j]);
    }
    __syncthreads();
  }
#pragma unroll
  for (int i = 0; i < TM; ++i) {
    int m = m0 + ty * TM + i;
#pragma unroll
    for (int j = 0; j < TN; ++j) {
      int n = n0 + tx * TN + j;
      if (n < N) {
        float v = acc[i][j];
        if (BIAS) v += bias[n];
        if (ACT == 1) v = 0.5f * v * (1.f + erff(v * 0.70710678118654752f));
        if (RESID || OUT_BCS) {
          int bb = m / S, pp = m - bb * S;
          size_t oidx = ((size_t)bb * CC + n) * S + pp;
          if (RESID) v += resid[oidx];
          if (OUT_BCS) { Cmat[oidx] = v; continue; }
        }
        Cmat[(size_t)m * N + n] = v;
      }
    }
  }
}

// ---------------- causal depthwise conv(4) + SiLU, gathered input --------
__global__ __launch_bounds__(256) void k_conv(const float* __restrict__ XZ,
    const float* __restrict__ cw, const float* __restrict__ cb,
    float* __restrict__ xc) {
  int t = blockIdx.x * blockDim.x + threadIdx.x;
  if (t >= GG * S * DI) return;
  int e = t % DI; int gl = t / DI; int l = gl % S; int g = gl / S;
  int b = g / 3, dir = g - (g / 3) * 3;
  float acc = cb[e];
#pragma unroll
  for (int k = 0; k < 4; ++k) {
    int ls = l + k - 3;
    if (ls >= 0) {
      int p = pos_from_l(dir, ls);
      acc = fmaf(cw[e * 4 + k], XZ[((size_t)b * S + p) * 384 + e], acc);
    }
  }
  float sg = 1.f / (1.f + __expf(-acc));
  xc[(size_t)gl * DI + e] = acc * sg;
}

// ======== scan kernels: 1 thread = (g, e, chunk), 16 states in regs ======
// LDS tile: sBC[l][j]: j 0..5 = dt_r, j 8..23 = B, j 24..39 = C (b128-aligned)
__device__ __forceinline__ void stage_bc(float (*sBC)[40],
    const float* __restrict__ xdbl, int g, int c, int tid) {
  const float* src = xdbl + ((size_t)g * S + c * LC) * ND;
  for (int i = tid; i < LC * ND; i += 192) {
    int row = i / ND, col = i - row * ND;
    int dst = (col < RK) ? col : col + 2;
    sBC[row][dst] = src[(size_t)row * ND + col];
  }
}

// common per-step prologue: dt via fast softplus
#define DT_COMMON(l)                                                     \
  float a = bde;                                                         \
  {                                                                      \
    float4 r0 = *(const float4*)&sBC[l][0];                              \
    float2 r1 = *(const float2*)&sBC[l][4];                              \
    a = fmaf(wdt[0], r0.x, a); a = fmaf(wdt[1], r0.y, a);                \
    a = fmaf(wdt[2], r0.z, a); a = fmaf(wdt[3], r0.w, a);                \
    a = fmaf(wdt[4], r1.x, a); a = fmaf(wdt[5], r1.y, a);                \
  }                                                                      \
  float d = fmaxf(a, 0.f) + __logf(1.f + __expf(-fabsf(a)));

__global__ __launch_bounds__(192, 4) void k_scanA(const float* __restrict__ xc,
    const float* __restrict__ xdbl, const float* __restrict__ Wdt,
    const float* __restrict__ bdt, const float* __restrict__ A_log,
    float* __restrict__ PA, float* __restrict__ EA) {
  __shared__ float sBC[LC][40];
  int c = blockIdx.x, g = blockIdx.y;
  int e = threadIdx.x;
  stage_bc(sBC, xdbl, g, c, e);
  float wdt[RK];
#pragma unroll
  for (int r = 0; r < RK; ++r) wdt[r] = Wdt[e * RK + r];
  float bde = bdt[e];
  float base = -__expf(A_log[e * NS]);
  bool fast = true;
#pragma unroll
  for (int s = 1; s < NS; ++s) {
    float aes = -__expf(A_log[e * NS + s]);
    fast = fast && (fabsf(aes / base - (float)(s + 1)) < 1e-3f);
  }
  float h[NS];
#pragma unroll
  for (int s = 0; s < NS; ++s) h[s] = 0.f;
  float T = 0.f;
  const float* xptr = xc + ((size_t)g * S + c * LC) * DI + e;
  __syncthreads();
  if (fast) {
    for (int l0 = 0; l0 < LC; l0 += 8) {
      float xb[8];
#pragma unroll
      for (int j = 0; j < 8; ++j) xb[j] = xptr[(size_t)(l0 + j) * DI];
#pragma unroll
      for (int j = 0; j < 8; ++j) {
        int l = l0 + j;
        DT_COMMON(l)
        T += d;
        float w = d * xb[j];
        float4 B0 = *(const float4*)&sBC[l][8];
        float4 B1 = *(const float4*)&sBC[l][12];
        float4 B2 = *(const float4*)&sBC[l][16];
        float4 B3 = *(const float4*)&sBC[l][20];
        float q[NS];
        pow_ladder(__expf(d * base), q);
        h[0]=fmaf(q[0],h[0],w*B0.x);  h[1]=fmaf(q[1],h[1],w*B0.y);
        h[2]=fmaf(q[2],h[2],w*B0.z);  h[3]=fmaf(q[3],h[3],w*B0.w);
        h[4]=fmaf(q[4],h[4],w*B1.x);  h[5]=fmaf(q[5],h[5],w*B1.y);
        h[6]=fmaf(q[6],h[6],w*B1.z);  h[7]=fmaf(q[7],h[7],w*B1.w);
        h[8]=fmaf(q[8],h[8],w*B2.x);  h[9]=fmaf(q[9],h[9],w*B2.y);
        h[10]=fmaf(q[10],h[10],w*B2.z); h[11]=fmaf(q[11],h[11],w*B2.w);
        h[12]=fmaf(q[12],h[12],w*B3.x); h[13]=fmaf(q[13],h[13],w*B3.y);
        h[14]=fmaf(q[14],h[14],w*B3.z); h[15]=fmaf(q[15],h[15],w*B3.w);
      }
    }
  } else {
    float Aes[NS];
#pragma unroll
    for (int s = 0; s < NS; ++s) Aes[s] = -__expf(A_log[e * NS + s]);
#pragma unroll 1
    for (int l = 0; l < LC; ++l) {
      DT_COMMON(l)
      T += d;
      float w = d * xptr[(size_t)l * DI];
#pragma unroll
      for (int s = 0; s < NS; ++s) {
        float q = __expf(d * Aes[s]);
        h[s] = fmaf(q, h[s], w * sBC[l][8 + s]);
      }
    }
  }
  float* pp = PA + (((size_t)g * NC + c) * DI + e) * NS;
  float* ep = EA + (((size_t)g * NC + c) * DI + e) * NS;
  float po[NS];
  if (fast) {
    pow_ladder(__expf(base * T), po);
  } else {
#pragma unroll
    for (int s = 0; s < NS; ++s)
      po[s] = __expf(-__expf(A_log[e * NS + s]) * T);
  }
#pragma unroll
  for (int s = 0; s < NS; s += 4) {
    *(float4*)&pp[s] = make_float4(po[s], po[s+1], po[s+2], po[s+3]);
    *(float4*)&ep[s] = make_float4(h[s], h[s+1], h[s+2], h[s+3]);
  }
}

// inter-chunk sequential combine (Hin aliases PA: loads precede stores)
__global__ __launch_bounds__(256) void k_scanB(const float* PA,
    const float* EA, float* Hin) {
  int idx = blockIdx.x * blockDim.x + threadIdx.x;
  if (idx >= GG * DI * NS) return;
  int g = idx / (DI * NS); int es = idx - g * (DI * NS);
  size_t stride = (size_t)DI * NS;
  size_t b0 = (size_t)g * NC * stride + es;
  float h = 0.f;
  for (int c0 = 0; c0 < NC; c0 += 5) {
    float p5[5], e5[5];
#pragma unroll
    for (int j = 0; j < 5; ++j) {
      size_t ix = b0 + (size_t)(c0 + j) * stride;
      p5[j] = PA[ix]; e5[j] = EA[ix];
    }
#pragma unroll
    for (int j = 0; j < 5; ++j) {
      size_t ix = b0 + (size_t)(c0 + j) * stride;
      Hin[ix] = h;
      h = fmaf(p5[j], h, e5[j]);
    }
  }
}

__global__ __launch_bounds__(192, 4) void k_scanC(const float* __restrict__ xc,
    const float* __restrict__ xdbl, const float* __restrict__ Wdt,
    const float* __restrict__ bdt, const float* __restrict__ A_log,
    const float* __restrict__ Hin, const float* __restrict__ Dp,
    float* __restrict__ yg) {
  __shared__ float sBC[LC][40];
  int c = blockIdx.x, g = blockIdx.y;
  int e = threadIdx.x;
  const float* hp = Hin + (((size_t)g * NC + c) * DI + e) * NS;
  float4 h0 = *(const float4*)(hp + 0);
  float4 h1v = *(const float4*)(hp + 4);
  float4 h2v = *(const float4*)(hp + 8);
  float4 h3v = *(const float4*)(hp + 12);
  stage_bc(sBC, xdbl, g, c, e);
  float wdt[RK];
#pragma unroll
  for (int r = 0; r < RK; ++r) wdt[r] = Wdt[e * RK + r];
  float bde = bdt[e];
  float dpe = Dp[e];
  float base = -__expf(A_log[e * NS]);
  bool fast = true;
#pragma unroll
  for (int s = 1; s < NS; ++s) {
    float aes = -__expf(A_log[e * NS + s]);
    fast = fast && (fabsf(aes / base - (float)(s + 1)) < 1e-3f);
  }
  float h[NS] = {h0.x, h0.y, h0.z, h0.w, h1v.x, h1v.y, h1v.z, h1v.w,
                 h2v.x, h2v.y, h2v.z, h2v.w, h3v.x, h3v.y, h3v.z, h3v.w};
  const float* xptr = xc + ((size_t)g * S + c * LC) * DI + e;
  int b = g / 3, dir = g - (g / 3) * 3;
  float* yo = yg + ((size_t)b * S + c * LC) * 576 + dir * DI + e;
  __syncthreads();
  if (fast) {
    for (int l0 = 0; l0 < LC; l0 += 8) {
      float xb[8];
#pragma unroll
      for (int j = 0; j < 8; ++j) xb[j] = xptr[(size_t)(l0 + j) * DI];
#pragma unroll
      for (int j = 0; j < 8; ++j) {
        int l = l0 + j;
        DT_COMMON(l)
        float xv = xb[j];
        float w = d * xv;
        float4 B0 = *(const float4*)&sBC[l][8];
        float4 B1 = *(const float4*)&sBC[l][12];
        float4 B2 = *(const float4*)&sBC[l][16];
        float4 B3 = *(const float4*)&sBC[l][20];
        float4 C0 = *(const float4*)&sBC[l][24];
        float4 C1 = *(const float4*)&sBC[l][28];
        float4 C2 = *(const float4*)&sBC[l][32];
        float4 C3 = *(const float4*)&sBC[l][36];
        float q[NS];
        pow_ladder(__expf(d * base), q);
        float y0 = xv * dpe, y1 = 0.f, y2 = 0.f, y3 = 0.f;
        h[0]=fmaf(q[0],h[0],w*B0.x);   y0=fmaf(h[0],C0.x,y0);
        h[1]=fmaf(q[1],h[1],w*B0.y);   y1=fmaf(h[1],C0.y,y1);
        h[2]=fmaf(q[2],h[2],w*B0.z);   y2=fmaf(h[2],C0.z,y2);
        h[3]=fmaf(q[3],h[3],w*B0.w);   y3=fmaf(h[3],C0.w,y3);
        h[4]=fmaf(q[4],h[4],w*B1.x);   y0=fmaf(h[4],C1.x,y0);
        h[5]=fmaf(q[5],h[5],w*B1.y);   y1=fmaf(h[5],C1.y,y1);
        h[6]=fmaf(q[6],h[6],w*B1.z);   y2=fmaf(h[6],C1.z,y2);
        h[7]=fmaf(q[7],h[7],w*B1.w);   y3=fmaf(h[7],C1.w,y3);
        h[8]=fmaf(q[8],h[8],w*B2.x);   y0=fmaf(h[8],C2.x,y0);
        h[9]=fmaf(q[9],h[9],w*B2.y);   y1=fmaf(h[9],C2.y,y1);
        h[10]=fmaf(q[10],h[10],w*B2.z); y2=fmaf(h[10],C2.z,y2);
        h[11]=fmaf(q[11],h[11],w*B2.w); y3=fmaf(h[11],C2.w,y3);
        h[12]=fmaf(q[12],h[12],w*B3.x); y0=fmaf(h[12],C3.x,y0);
        h[13]=fmaf(q[13],h[13],w*B3.y); y1=fmaf(h[13],C3.y,y1);
        h[14]=fmaf(q[14],h[14],w*B3.z); y2=fmaf(h[14],C3.z,y2);
        h[15]=fmaf(q[15],h[15],w*B3.w); y3=fmaf(h[15],C3.w,y3);
        yo[(size_t)l * 576] = (y0 + y1) + (y2 + y3);
      }
    }
  } else {
    float Aes[NS];
#pragma unroll
    for (int s = 0; s < NS; ++s) Aes[s] = -__expf(A_log[e * NS + s]);
#pragma unroll 1
    for (int l = 0; l < LC; ++l) {
      DT_COMMON(l)
      float xv = xptr[(size_t)l * DI];
      float w = d * xv;
      float y = xv * dpe;
#pragma unroll
      for (int s = 0; s < NS; ++s) {
        float q = __expf(d * Aes[s]);
        h[s] = fmaf(q, h[s], w * sBC[l][8 + s]);
        y = fmaf(h[s], sBC[l][24 + s], y);
      }
      yo[(size_t)l * 576] = y;
    }
  }
}

// ---------------- gate pass: yg *= silu(z gathered) ----------------------
__global__ __launch_bounds__(256) void k_gate(float* __restrict__ yg,
    const float* __restrict__ XZ) {
  int t = blockIdx.x * blockDim.x + threadIdx.x;
  if (t >= BB * S * 144) return;
  int row = t / 144;
  int j4 = t - row * 144;
  int j0 = j4 * 4;
  int dir = j0 / 192; int e0 = j0 - dir * 192;
  int b = row / S; int l = row - b * S;
  int p = pos_from_l(dir, l);
  const float4 z4 = *(const float4*)&XZ[((size_t)b * S + p) * 384 + DI + e0];
  float4* yp = (float4*)(yg + (size_t)row * 576 + j0);
  float4 y4 = *yp;
  y4.x *= z4.x / (1.f + __expf(-z4.x));
  y4.y *= z4.y / (1.f + __expf(-z4.y));
  y4.z *= z4.z / (1.f + __expf(-z4.z));
  y4.w *= z4.w / (1.f + __expf(-z4.w));
  *yp = y4;
}

// ---------------- fold Wout into proj_w: Mcat[o, dir*192+e] --------------
__global__ __launch_bounds__(256) void k_foldW(const float* __restrict__ proj_w,
    const float* __restrict__ Wout, float* __restrict__ Mcat) {
  int t = blockIdx.x * blockDim.x + threadIdx.x;
  if (t >= CC * 576) return;
  int o = t / 576; int j = t - o * 576; int dir = j / DI; int e = j - dir * DI;
  float a = 0.f;
  for (int c2 = 0; c2 < CC; ++c2)
    a = fmaf(proj_w[o * 288 + dir * CC + c2], Wout[c2 * DI + e], a);
  Mcat[t] = a;
}

extern "C" void kernel_launch(void* const* d_in, const int* in_sizes, int n_in,
                              void* d_out, int out_size, void* d_ws, size_t ws_size,
                              hipStream_t stream) {
  const float* x      = (const float*)d_in[0];
  const float* ln_w   = (const float*)d_in[1];
  const float* ln_b   = (const float*)d_in[2];
  const float* mln_w  = (const float*)d_in[3];
  const float* mln_b  = (const float*)d_in[4];
  const float* Win    = (const float*)d_in[5];
  const float* conv_w = (const float*)d_in[6];
  const float* conv_b = (const float*)d_in[7];
  const float* Wx     = (const float*)d_in[8];
  const float* Wdt    = (const float*)d_in[9];
  const float* bdt    = (const float*)d_in[10];
  const float* A_log  = (const float*)d_in[11];
  const float* Dp     = (const float*)d_in[12];
  const float* Wout   = (const float*)d_in[13];
  const float* proj_w = (const float*)d_in[14];
  const float* proj_b = (const float*)d_in[15];
  const float* fc1_w  = (const float*)d_in[16];
  const float* fc1_b  = (const float*)d_in[17];
  const float* fc2_w  = (const float*)d_in[18];
  const float* fc2_b  = (const float*)d_in[19];

  float* ws = (float*)d_ws;
  size_t off = 0;
  float* xn   = ws + off; off += (size_t)BB * S * CC;       // 1.536M
  float* XZ   = ws + off; off += (size_t)BB * S * 384;      // 6.144M
  float* xc   = ws + off; off += (size_t)GG * S * DI;       // 9.216M
  float* xdbl = ws + off; off += (size_t)GG * S * ND;       // 1.824M
  float* PA   = ws + off; off += (size_t)GG * NC * DI * NS; // 4.608M
  float* EA   = ws + off; off += (size_t)GG * NC * DI * NS; // 4.608M
  float* yg   = ws + off; off += (size_t)BB * S * 576;      // 9.216M
  float* Mcat = ws + off; off += (size_t)CC * 576;
  if (ws_size < off * sizeof(float)) return;                // ~149 MB; guard
  float* Hin  = PA;     // in-place in scanB (group loads precede stores)
  float* ores = xn;     // xn dead after Win GEMM
  float* xln2 = xc;     // xc dead after scanC
  float* h1   = XZ;     // XZ dead after gate

  k_ln2<<<(BB * S + 255) / 256, 256, 0, stream>>>(x, ln_w, ln_b, mln_w, mln_b, xn);
  k_gemm2<128, 128, 8, 8, 0, false, false, false>
      <<<dim3(BB * S / 128, 3), 256, 0, stream>>>(
      xn, Win, nullptr, nullptr, XZ, BB * S, 384, CC);
  k_conv<<<(GG * S * DI + 255) / 256, 256, 0, stream>>>(XZ, conv_w, conv_b, xc);
  k_gemm<0, false, false, false><<<dim3(GG * S / 64, 1), 256, 0, stream>>>(
      xc, Wx, nullptr, nullptr, xdbl, GG * S, ND, DI);
  k_scanA<<<dim3(NC, GG), 192, 0, stream>>>(xc, xdbl, Wdt, bdt, A_log, PA, EA);
  k_scanB<<<(GG * DI * NS + 255) / 256, 256, 0, stream>>>(PA, EA, Hin);
  k_scanC<<<dim3(NC, GG), 192, 0, stream>>>(xc, xdbl, Wdt, bdt, A_log, Hin, Dp, yg);
  k_gate<<<(BB * S * 144 + 255) / 256, 256, 0, stream>>>(yg, XZ);
  k_foldW<<<(CC * 576 + 255) / 256, 256, 0, stream>>>(proj_w, Wout, Mcat);
  k_gemm2<64, 128, 4, 8, 0, true, true, true>
      <<<dim3(BB * S / 64, 1), 256, 0, stream>>>(
      yg, Mcat, proj_b, x, ores, BB * S, CC, 576);
  k_ln1<<<(BB * S + 255) / 256, 256, 0, stream>>>(ores, ln_w, ln_b, xln2);
  k_gemm2<128, 128, 8, 8, 1, true, false, false>
      <<<dim3(BB * S / 128, 3), 256, 0, stream>>>(
      xln2, fc1_w, fc1_b, nullptr, h1, BB * S, 384, CC);
  k_gemm2<64, 128, 4, 8, 0, true, true, true>
      <<<dim3(BB * S / 64, 1), 256, 0, stream>>>(
      h1, fc2_w, fc2_b, ores, (float*)d_out, BB * S, CC, 384);
}

// Round 7
// 458.720 us; speedup vs baseline: 1.0778x; 1.0778x over previous
//
#include <hip/hip_runtime.h>
#include <math.h>

// Problem constants (fixed by reference)
#define S   8000     // L = 20*20*20
#define BB  2
#define CC  96
#define DI  192      // d_inner
#define NS  16       // d_state
#define RK  6        // dt_rank
#define GG  6        // B * 3 directions
#define NC  200      // scan chunks
#define LC  40       // chunk length
#define ND  38       // dt_rank + 2*d_state

// l -> pos mapping per direction.
__device__ __forceinline__ int pos_from_l(int dir, int l) {
  if (dir == 0) return l;
  int a  = l / 400;
  int r  = l - a * 400;
  int bq = r / 20;
  int cq = r - bq * 20;
  if (dir == 1) return cq * 400 + a * 20 + bq;   // (h=a, w=bq, d=cq)
  return bq * 400 + cq * 20 + a;                 // (w=a, d=bq, h=cq)
}

__device__ __forceinline__ float silu(float z) {
  return z / (1.f + __expf(-z));
}

// ---------------- K0: double LayerNorm over channels (per position) -------
__global__ __launch_bounds__(256) void k_ln2(const float* __restrict__ x,
    const float* __restrict__ lnw, const float* __restrict__ lnb,
    const float* __restrict__ mlnw, const float* __restrict__ mlnb,
    float* __restrict__ xn) {
  int t = blockIdx.x * blockDim.x + threadIdx.x;
  if (t >= BB * S) return;
  int b = t / S, pos = t - b * S;
  const float* xp = x + (size_t)b * CC * S + pos;
  float s1 = 0.f, s2 = 0.f;
  for (int c = 0; c < CC; ++c) { float v = xp[(size_t)c * S]; s1 += v; s2 += v * v; }
  float u = s1 * (1.f / CC);
  float var = s2 * (1.f / CC) - u * u;
  float rstd = rsqrtf(var + 1e-6f);
  float t1 = 0.f, t2 = 0.f;
  for (int c = 0; c < CC; ++c) {
    float y1 = fmaf(lnw[c], (xp[(size_t)c * S] - u) * rstd, lnb[c]);
    t1 += y1; t2 += y1 * y1;
  }
  float u2 = t1 * (1.f / CC);
  float var2 = t2 * (1.f / CC) - u2 * u2;
  float rstd2 = rsqrtf(var2 + 1e-5f);
  float* o = xn + (size_t)t * CC;
  for (int c = 0; c < CC; ++c) {
    float y1 = fmaf(lnw[c], (xp[(size_t)c * S] - u) * rstd, lnb[c]);
    o[c] = fmaf(mlnw[c], (y1 - u2) * rstd2, mlnb[c]);
  }
}

// ---------------- single LayerNorm (B,C,S) -> (B*S,C) --------------------
__global__ __launch_bounds__(256) void k_ln1(const float* __restrict__ xi,
    const float* __restrict__ lnw, const float* __restrict__ lnb,
    float* __restrict__ out) {
  int t = blockIdx.x * blockDim.x + threadIdx.x;
  if (t >= BB * S) return;
  int b = t / S, pos = t - b * S;
  const float* xp = xi + (size_t)b * CC * S + pos;
  float s1 = 0.f, s2 = 0.f;
  for (int c = 0; c < CC; ++c) { float v = xp[(size_t)c * S]; s1 += v; s2 += v * v; }
  float u = s1 * (1.f / CC);
  float var = s2 * (1.f / CC) - u * u;
  float rstd = rsqrtf(var + 1e-6f);
  float* o = out + (size_t)t * CC;
  for (int c = 0; c < CC; ++c)
    o[c] = fmaf(lnw[c], (xp[(size_t)c * S] - u) * rstd, lnb[c]);
}

// -------- old 64x64 fp32 GEMM (kept for Wx: N=38, K=192) -----------------
template <int ACT, bool BIAS, bool RESID, bool OUT_BCS>
__global__ __launch_bounds__(256) void k_gemm(const float* __restrict__ A,
    const float* __restrict__ Bw, const float* __restrict__ bias,
    const float* __restrict__ resid, float* __restrict__ Cmat,
    int M, int N, int K) {
  __shared__ float As[16][68];
  __shared__ float Bs[16][68];
  int tid = threadIdx.x;
  int tx = tid & 15, ty = tid >> 4;
  int m0 = blockIdx.x * 64, n0 = blockIdx.y * 64;
  float acc[4][4] = {};
  for (int kk = 0; kk < K; kk += 16) {
#pragma unroll
    for (int i = 0; i < 4; ++i) {
      int idx = tid + i * 256;
      int am = idx >> 4, ak = idx & 15;
      As[ak][am] = A[(size_t)(m0 + am) * K + kk + ak];
    }
#pragma unroll
    for (int i = 0; i < 4; ++i) {
      int idx = tid + i * 256;
      int bn = idx >> 4, bk = idx & 15;
      Bs[bk][bn] = (n0 + bn < N) ? Bw[(size_t)(n0 + bn) * K + kk + bk] : 0.f;
    }
    __syncthreads();
#pragma unroll
    for (int k = 0; k < 16; ++k) {
      float4 av = *(const float4*)&As[k][ty * 4];
      float4 bv = *(const float4*)&Bs[k][tx * 4];
      acc[0][0] = fmaf(av.x, bv.x, acc[0][0]);
      acc[0][1] = fmaf(av.x, bv.y, acc[0][1]);
      acc[0][2] = fmaf(av.x, bv.z, acc[0][2]);
      acc[0][3] = fmaf(av.x, bv.w, acc[0][3]);
      acc[1][0] = fmaf(av.y, bv.x, acc[1][0]);
      acc[1][1] = fmaf(av.y, bv.y, acc[1][1]);
      acc[1][2] = fmaf(av.y, bv.z, acc[1][2]);
      acc[1][3] = fmaf(av.y, bv.w, acc[1][3]);
      acc[2][0] = fmaf(av.z, bv.x, acc[2][0]);
      acc[2][1] = fmaf(av.z, bv.y, acc[2][1]);
      acc[2][2] = fmaf(av.z, bv.z, acc[2][2]);
      acc[2][3] = fmaf(av.z, bv.w, acc[2][3]);
      acc[3][0] = fmaf(av.w, bv.x, acc[3][0]);
      acc[3][1] = fmaf(av.w, bv.y, acc[3][1]);
      acc[3][2] = fmaf(av.w, bv.z, acc[3][2]);
      acc[3][3] = fmaf(av.w, bv.w, acc[3][3]);
    }
    __syncthreads();
  }
#pragma unroll
  for (int i = 0; i < 4; ++i) {
    int m = m0 + ty * 4 + i;
#pragma unroll
    for (int j = 0; j < 4; ++j) {
      int n = n0 + tx * 4 + j;
      if (n < N) {
        float v = acc[i][j];
        if (BIAS) v += bias[n];
        if (ACT == 1) v = 0.5f * v * (1.f + erff(v * 0.70710678118654752f));
        if (RESID || OUT_BCS) {
          int bb = m / S, pp = m - bb * S;
          size_t oidx = ((size_t)bb * CC + n) * S + pp;
          if (RESID) v += resid[oidx];
          if (OUT_BCS) { Cmat[oidx] = v; continue; }
        }
        Cmat[(size_t)m * N + n] = v;
      }
    }
  }
}

// -------- big-tile fp32 GEMM: BMxBN tile, TMxTN micro, 256 thr -----------
// GATEA: multiply A element (m=(b,l), k=dir*192+e) by silu(z[b,pos(dir,l),e])
template <int BM, int BN, int TM, int TN, int ACT, bool BIAS, bool RESID,
          bool OUT_BCS, bool GATEA>
__global__ __launch_bounds__(256) void k_gemm2(const float* __restrict__ A,
    const float* __restrict__ Bw, const float* __restrict__ bias,
    const float* __restrict__ resid, const float* __restrict__ XZg,
    float* __restrict__ Cmat, int M, int N, int K) {
  constexpr int BK = 16;
  constexpr int NTX = BN / TN;
  constexpr int NTY = BM / TM;
  static_assert(NTX * NTY == 256, "bad tile cfg");
  __shared__ float As[BK][BM + 4];
  __shared__ float Bs[BK][BN + 4];
  int tid = threadIdx.x;
  int tx = tid % NTX, ty = tid / NTX;
  int m0 = blockIdx.x * BM, n0 = blockIdx.y * BN;
  float acc[TM][TN] = {};
  int r = tid >> 2, cq = tid & 3;
  for (int kk = 0; kk < K; kk += BK) {
#pragma unroll
    for (int rr = 0; rr < BM; rr += 64) {
      int m = m0 + rr + r;
      float4 v = *(const float4*)&A[(size_t)m * K + kk + cq * 4];
      if (GATEA) {
        int bb = m / S, ll = m - bb * S;
        int j = kk + cq * 4;
        int dir = j / DI; int e0 = j - dir * DI;
        int p = pos_from_l(dir, ll);
        const float4 z4 = *(const float4*)&XZg[((size_t)bb * S + p) * 384 + DI + e0];
        v.x *= silu(z4.x); v.y *= silu(z4.y);
        v.z *= silu(z4.z); v.w *= silu(z4.w);
      }
      As[cq * 4 + 0][rr + r] = v.x; As[cq * 4 + 1][rr + r] = v.y;
      As[cq * 4 + 2][rr + r] = v.z; As[cq * 4 + 3][rr + r] = v.w;
    }
#pragma unroll
    for (int rr = 0; rr < BN; rr += 64) {
      int n = n0 + rr + r;
      float4 v = make_float4(0.f, 0.f, 0.f, 0.f);
      if (n < N) v = *(const float4*)&Bw[(size_t)n * K + kk + cq * 4];
      Bs[cq * 4 + 0][rr + r] = v.x; Bs[cq * 4 + 1][rr + r] = v.y;
      Bs[cq * 4 + 2][rr + r] = v.z; Bs[cq * 4 + 3][rr + r] = v.w;
    }
    __syncthreads();
#pragma unroll
    for (int k = 0; k < BK; ++k) {
      float a[TM], b[TN];
#pragma unroll
      for (int i = 0; i < TM; i += 4)
        *(float4*)&a[i] = *(const float4*)&As[k][ty * TM + i];
#pragma unroll
      for (int j = 0; j < TN; j += 4)
        *(float4*)&b[j] = *(const float4*)&Bs[k][tx * TN + j];
#pragma unroll
      for (int i = 0; i < TM; ++i)
#pragma unroll
        for (int j = 0; j < TN; ++j)
          acc[i][j] = fmaf(a[i], b[j], acc[i][j]);
    }
    __syncthreads();
  }
#pragma unroll
  for (int i = 0; i < TM; ++i) {
    int m = m0 + ty * TM + i;
#pragma unroll
    for (int j = 0; j < TN; ++j) {
      int n = n0 + tx * TN + j;
      if (n < N) {
        float v = acc[i][j];
        if (BIAS) v += bias[n];
        if (ACT == 1) v = 0.5f * v * (1.f + erff(v * 0.70710678118654752f));
        if (RESID || OUT_BCS) {
          int bb = m / S, pp = m - bb * S;
          size_t oidx = ((size_t)bb * CC + n) * S + pp;
          if (RESID) v += resid[oidx];
          if (OUT_BCS) { Cmat[oidx] = v; continue; }
        }
        Cmat[(size_t)m * N + n] = v;
      }
    }
  }
}

// ---------------- causal depthwise conv(4) + SiLU, gathered input --------
__global__ __launch_bounds__(256) void k_conv(const float* __restrict__ XZ,
    const float* __restrict__ cw, const float* __restrict__ cb,
    float* __restrict__ xc) {
  int t = blockIdx.x * blockDim.x + threadIdx.x;
  if (t >= GG * S * DI) return;
  int e = t % DI; int gl = t / DI; int l = gl % S; int g = gl / S;
  int b = g / 3, dir = g - (g / 3) * 3;
  float acc = cb[e];
#pragma unroll
  for (int k = 0; k < 4; ++k) {
    int ls = l + k - 3;
    if (ls >= 0) {
      int p = pos_from_l(dir, ls);
      acc = fmaf(cw[e * 4 + k], XZ[((size_t)b * S + p) * 384 + e], acc);
    }
  }
  xc[(size_t)gl * DI + e] = acc * (1.f / (1.f + __expf(-acc)));
}

// ======== scan kernels: 1 thread = (g, e, chunk), 16 states in regs ======
// LDS tile: sBC[l][j]: j 0..5 = dt_r, j 8..23 = B, j 24..39 = C (b128-aligned)
__device__ __forceinline__ void stage_bc(float (*sBC)[40],
    const float* __restrict__ xdbl, int g, int c, int tid) {
  const float* src = xdbl + ((size_t)g * S + c * LC) * ND;
  for (int i = tid; i < LC * ND; i += 192) {
    int row = i / ND, col = i - row * ND;
    int dst = (col < RK) ? col : col + 2;
    sBC[row][dst] = src[(size_t)row * ND + col];
  }
}

// common per-step prologue: dt via fast softplus
#define DT_COMMON(l)                                                     \
  float a = bde;                                                         \
  {                                                                      \
    float4 r0 = *(const float4*)&sBC[l][0];                              \
    float2 r1 = *(const float2*)&sBC[l][4];                              \
    a = fmaf(wdt[0], r0.x, a); a = fmaf(wdt[1], r0.y, a);                \
    a = fmaf(wdt[2], r0.z, a); a = fmaf(wdt[3], r0.w, a);                \
    a = fmaf(wdt[4], r1.x, a); a = fmaf(wdt[5], r1.y, a);                \
  }                                                                      \
  float d = fmaxf(a, 0.f) + __logf(1.f + __expf(-fabsf(a)));

__global__ __launch_bounds__(192, 4) void k_scanA(const float* __restrict__ xc,
    const float* __restrict__ xdbl, const float* __restrict__ Wdt,
    const float* __restrict__ bdt, const float* __restrict__ A_log,
    float* __restrict__ PA, float* __restrict__ EA) {
  __shared__ float sBC[LC][40];
  int c = blockIdx.x, g = blockIdx.y;
  int e = threadIdx.x;
  stage_bc(sBC, xdbl, g, c, e);
  float wdt[RK];
#pragma unroll
  for (int r = 0; r < RK; ++r) wdt[r] = Wdt[e * RK + r];
  float bde = bdt[e];
  float base = -__expf(A_log[e * NS]);
  bool fast = true;
#pragma unroll
  for (int s = 1; s < NS; ++s) {
    float aes = -__expf(A_log[e * NS + s]);
    fast = fast && (fabsf(aes / base - (float)(s + 1)) < 1e-3f);
  }
  float h[NS];
#pragma unroll
  for (int s = 0; s < NS; ++s) h[s] = 0.f;
  float T = 0.f;
  const float* xptr = xc + ((size_t)g * S + c * LC) * DI + e;
  __syncthreads();
  if (fast) {
    for (int l0 = 0; l0 < LC; l0 += 8) {
      float xb[8];
#pragma unroll
      for (int j = 0; j < 8; ++j) xb[j] = xptr[(size_t)(l0 + j) * DI];
#pragma unroll
      for (int j = 0; j < 8; ++j) {
        int l = l0 + j;
        DT_COMMON(l)
        T += d;
        float w = d * xb[j];
        float r = __expf(d * base);
        float r2 = r * r, r3 = r2 * r, r4 = r2 * r2;
        float r6 = r4 * r2, r8 = r4 * r4, r12 = r8 * r4;
        {
          float4 B0 = *(const float4*)&sBC[l][8];
          h[0] = fmaf(r,  h[0], w * B0.x); h[1] = fmaf(r2, h[1], w * B0.y);
          h[2] = fmaf(r3, h[2], w * B0.z); h[3] = fmaf(r4, h[3], w * B0.w);
        }
        {
          float4 B1 = *(const float4*)&sBC[l][12];
          h[4] = fmaf(r4 * r, h[4], w * B1.x); h[5] = fmaf(r6, h[5], w * B1.y);
          h[6] = fmaf(r6 * r, h[6], w * B1.z); h[7] = fmaf(r8, h[7], w * B1.w);
        }
        {
          float4 B2 = *(const float4*)&sBC[l][16];
          h[8] = fmaf(r8 * r, h[8], w * B2.x);  h[9] = fmaf(r8 * r2, h[9], w * B2.y);
          h[10] = fmaf(r8 * r3, h[10], w * B2.z); h[11] = fmaf(r12, h[11], w * B2.w);
        }
        {
          float4 B3 = *(const float4*)&sBC[l][20];
          h[12] = fmaf(r12 * r, h[12], w * B3.x);  h[13] = fmaf(r12 * r2, h[13], w * B3.y);
          h[14] = fmaf(r12 * r3, h[14], w * B3.z); h[15] = fmaf(r8 * r8, h[15], w * B3.w);
        }
      }
    }
  } else {
#pragma unroll 1
    for (int l = 0; l < LC; ++l) {
      DT_COMMON(l)
      T += d;
      float w = d * xptr[(size_t)l * DI];
#pragma unroll
      for (int s = 0; s < NS; ++s) {
        float q = __expf(d * (-__expf(A_log[e * NS + s])));
        h[s] = fmaf(q, h[s], w * sBC[l][8 + s]);
      }
    }
  }
  float* pp = PA + (((size_t)g * NC + c) * DI + e) * NS;
  float* ep = EA + (((size_t)g * NC + c) * DI + e) * NS;
  float po[NS];
  if (fast) {
    float r = __expf(base * T);
    float r2 = r * r, r3 = r2 * r, r4 = r2 * r2;
    float r6 = r4 * r2, r8 = r4 * r4, r12 = r8 * r4;
    po[0] = r; po[1] = r2; po[2] = r3; po[3] = r4;
    po[4] = r4 * r; po[5] = r6; po[6] = r6 * r; po[7] = r8;
    po[8] = r8 * r; po[9] = r8 * r2; po[10] = r8 * r3; po[11] = r12;
    po[12] = r12 * r; po[13] = r12 * r2; po[14] = r12 * r3; po[15] = r8 * r8;
  } else {
#pragma unroll
    for (int s = 0; s < NS; ++s)
      po[s] = __expf(-__expf(A_log[e * NS + s]) * T);
  }
#pragma unroll
  for (int s = 0; s < NS; s += 4) {
    *(float4*)&pp[s] = make_float4(po[s], po[s+1], po[s+2], po[s+3]);
    *(float4*)&ep[s] = make_float4(h[s], h[s+1], h[s+2], h[s+3]);
  }
}

// inter-chunk sequential combine (Hin aliases PA: loads precede stores)
__global__ __launch_bounds__(256) void k_scanB(const float* PA,
    const float* EA, float* Hin) {
  int idx = blockIdx.x * blockDim.x + threadIdx.x;
  if (idx >= GG * DI * NS) return;
  int g = idx / (DI * NS); int es = idx - g * (DI * NS);
  size_t stride = (size_t)DI * NS;
  size_t b0 = (size_t)g * NC * stride + es;
  float h = 0.f;
  for (int c0 = 0; c0 < NC; c0 += 8) {
    float p8[8], e8[8];
#pragma unroll
    for (int j = 0; j < 8; ++j) {
      size_t ix = b0 + (size_t)(c0 + j) * stride;
      p8[j] = PA[ix]; e8[j] = EA[ix];
    }
#pragma unroll
    for (int j = 0; j < 8; ++j) {
      size_t ix = b0 + (size_t)(c0 + j) * stride;
      Hin[ix] = h;
      h = fmaf(p8[j], h, e8[j]);
    }
  }
}

__global__ __launch_bounds__(192, 4) void k_scanC(const float* __restrict__ xc,
    const float* __restrict__ xdbl, const float* __restrict__ Wdt,
    const float* __restrict__ bdt, const float* __restrict__ A_log,
    const float* __restrict__ Hin, const float* __restrict__ Dp,
    float* __restrict__ yg) {
  __shared__ float sBC[LC][40];
  int c = blockIdx.x, g = blockIdx.y;
  int e = threadIdx.x;
  const float* hp = Hin + (((size_t)g * NC + c) * DI + e) * NS;
  float4 h0 = *(const float4*)(hp + 0);
  float4 h1v = *(const float4*)(hp + 4);
  float4 h2v = *(const float4*)(hp + 8);
  float4 h3v = *(const float4*)(hp + 12);
  stage_bc(sBC, xdbl, g, c, e);
  float wdt[RK];
#pragma unroll
  for (int r = 0; r < RK; ++r) wdt[r] = Wdt[e * RK + r];
  float bde = bdt[e];
  float dpe = Dp[e];
  float base = -__expf(A_log[e * NS]);
  bool fast = true;
#pragma unroll
  for (int s = 1; s < NS; ++s) {
    float aes = -__expf(A_log[e * NS + s]);
    fast = fast && (fabsf(aes / base - (float)(s + 1)) < 1e-3f);
  }
  float h[NS] = {h0.x, h0.y, h0.z, h0.w, h1v.x, h1v.y, h1v.z, h1v.w,
                 h2v.x, h2v.y, h2v.z, h2v.w, h3v.x, h3v.y, h3v.z, h3v.w};
  const float* xptr = xc + ((size_t)g * S + c * LC) * DI + e;
  int b = g / 3, dir = g - (g / 3) * 3;
  float* yo = yg + ((size_t)b * S + c * LC) * 576 + dir * DI + e;
  __syncthreads();
  if (fast) {
    for (int l0 = 0; l0 < LC; l0 += 8) {
      float xb[8];
#pragma unroll
      for (int j = 0; j < 8; ++j) xb[j] = xptr[(size_t)(l0 + j) * DI];
#pragma unroll
      for (int j = 0; j < 8; ++j) {
        int l = l0 + j;
        DT_COMMON(l)
        float xv = xb[j];
        float w = d * xv;
        float r = __expf(d * base);
        float r2 = r * r, r3 = r2 * r, r4 = r2 * r2;
        float r6 = r4 * r2, r8 = r4 * r4, r12 = r8 * r4;
        float y0 = xv * dpe, y1 = 0.f, y2 = 0.f, y3 = 0.f;
        {
          float4 B0 = *(const float4*)&sBC[l][8];
          h[0] = fmaf(r,  h[0], w * B0.x); h[1] = fmaf(r2, h[1], w * B0.y);
          h[2] = fmaf(r3, h[2], w * B0.z); h[3] = fmaf(r4, h[3], w * B0.w);
          float4 C0 = *(const float4*)&sBC[l][24];
          y0 = fmaf(h[0], C0.x, y0); y1 = fmaf(h[1], C0.y, y1);
          y2 = fmaf(h[2], C0.z, y2); y3 = fmaf(h[3], C0.w, y3);
        }
        {
          float4 B1 = *(const float4*)&sBC[l][12];
          h[4] = fmaf(r4 * r, h[4], w * B1.x); h[5] = fmaf(r6, h[5], w * B1.y);
          h[6] = fmaf(r6 * r, h[6], w * B1.z); h[7] = fmaf(r8, h[7], w * B1.w);
          float4 C1 = *(const float4*)&sBC[l][28];
          y0 = fmaf(h[4], C1.x, y0); y1 = fmaf(h[5], C1.y, y1);
          y2 = fmaf(h[6], C1.z, y2); y3 = fmaf(h[7], C1.w, y3);
        }
        {
          float4 B2 = *(const float4*)&sBC[l][16];
          h[8] = fmaf(r8 * r, h[8], w * B2.x);  h[9] = fmaf(r8 * r2, h[9], w * B2.y);
          h[10] = fmaf(r8 * r3, h[10], w * B2.z); h[11] = fmaf(r12, h[11], w * B2.w);
          float4 C2 = *(const float4*)&sBC[l][32];
          y0 = fmaf(h[8], C2.x, y0); y1 = fmaf(h[9], C2.y, y1);
          y2 = fmaf(h[10], C2.z, y2); y3 = fmaf(h[11], C2.w, y3);
        }
        {
          float4 B3 = *(const float4*)&sBC[l][20];
          h[12] = fmaf(r12 * r, h[12], w * B3.x);  h[13] = fmaf(r12 * r2, h[13], w * B3.y);
          h[14] = fmaf(r12 * r3, h[14], w * B3.z); h[15] = fmaf(r8 * r8, h[15], w * B3.w);
          float4 C3 = *(const float4*)&sBC[l][36];
          y0 = fmaf(h[12], C3.x, y0); y1 = fmaf(h[13], C3.y, y1);
          y2 = fmaf(h[14], C3.z, y2); y3 = fmaf(h[15], C3.w, y3);
        }
        yo[(size_t)l * 576] = (y0 + y1) + (y2 + y3);
      }
    }
  } else {
#pragma unroll 1
    for (int l = 0; l < LC; ++l) {
      DT_COMMON(l)
      float xv = xptr[(size_t)l * DI];
      float w = d * xv;
      float y = xv * dpe;
#pragma unroll
      for (int s = 0; s < NS; ++s) {
        float q = __expf(d * (-__expf(A_log[e * NS + s])));
        h[s] = fmaf(q, h[s], w * sBC[l][8 + s]);
        y = fmaf(h[s], sBC[l][24 + s], y);
      }
      yo[(size_t)l * 576] = y;
    }
  }
}

// ---------------- fold Wout into proj_w: Mcat[o, dir*192+e] --------------
__global__ __launch_bounds__(256) void k_foldW(const float* __restrict__ proj_w,
    const float* __restrict__ Wout, float* __restrict__ Mcat) {
  int t = blockIdx.x * blockDim.x + threadIdx.x;
  if (t >= CC * 576) return;
  int o = t / 576; int j = t - o * 576; int dir = j / DI; int e = j - dir * DI;
  float a = 0.f;
  for (int c2 = 0; c2 < CC; ++c2)
    a = fmaf(proj_w[o * 288 + dir * CC + c2], Wout[c2 * DI + e], a);
  Mcat[t] = a;
}

extern "C" void kernel_launch(void* const* d_in, const int* in_sizes, int n_in,
                              void* d_out, int out_size, void* d_ws, size_t ws_size,
                              hipStream_t stream) {
  const float* x      = (const float*)d_in[0];
  const float* ln_w   = (const float*)d_in[1];
  const float* ln_b   = (const float*)d_in[2];
  const float* mln_w  = (const float*)d_in[3];
  const float* mln_b  = (const float*)d_in[4];
  const float* Win    = (const float*)d_in[5];
  const float* conv_w = (const float*)d_in[6];
  const float* conv_b = (const float*)d_in[7];
  const float* Wx     = (const float*)d_in[8];
  const float* Wdt    = (const float*)d_in[9];
  const float* bdt    = (const float*)d_in[10];
  const float* A_log  = (const float*)d_in[11];
  const float* Dp     = (const float*)d_in[12];
  const float* Wout   = (const float*)d_in[13];
  const float* proj_w = (const float*)d_in[14];
  const float* proj_b = (const float*)d_in[15];
  const float* fc1_w  = (const float*)d_in[16];
  const float* fc1_b  = (const float*)d_in[17];
  const float* fc2_w  = (const float*)d_in[18];
  const float* fc2_b  = (const float*)d_in[19];

  float* ws = (float*)d_ws;
  size_t off = 0;
  float* xn   = ws + off; off += (size_t)BB * S * CC;       // 1.536M
  float* XZ   = ws + off; off += (size_t)BB * S * 384;      // 6.144M
  float* xc   = ws + off; off += (size_t)GG * S * DI;       // 9.216M
  float* xdbl = ws + off; off += (size_t)GG * S * ND;       // 1.824M
  float* PA   = ws + off; off += (size_t)GG * NC * DI * NS; // 3.686M
  float* EA   = ws + off; off += (size_t)GG * NC * DI * NS; // 3.686M
  float* yg   = ws + off; off += (size_t)BB * S * 576;      // 9.216M
  float* Mcat = ws + off; off += (size_t)CC * 576;
  if (ws_size < off * sizeof(float)) return;                // ~142 MB; guard
  float* Hin  = PA;     // in-place in scanB (group loads precede stores)
  float* ores = xn;     // xn dead after Win GEMM
  float* xln2 = xc;     // xc dead after scanC
  float* h1   = XZ;     // XZ dead after proj (gate fused there)

  k_ln2<<<(BB * S + 255) / 256, 256, 0, stream>>>(x, ln_w, ln_b, mln_w, mln_b, xn);
  k_gemm2<128, 128, 8, 8, 0, false, false, false, false>
      <<<dim3(BB * S / 128, 3), 256, 0, stream>>>(
      xn, Win, nullptr, nullptr, nullptr, XZ, BB * S, 384, CC);
  k_conv<<<(GG * S * DI + 255) / 256, 256, 0, stream>>>(XZ, conv_w, conv_b, xc);
  k_gemm<0, false, false, false><<<dim3(GG * S / 64, 1), 256, 0, stream>>>(
      xc, Wx, nullptr, nullptr, xdbl, GG * S, ND, DI);
  k_scanA<<<dim3(NC, GG), 192, 0, stream>>>(xc, xdbl, Wdt, bdt, A_log, PA, EA);
  k_scanB<<<(GG * DI * NS + 255) / 256, 256, 0, stream>>>(PA, EA, Hin);
  k_scanC<<<dim3(NC, GG), 192, 0, stream>>>(xc, xdbl, Wdt, bdt, A_log, Hin, Dp, yg);
  k_foldW<<<(CC * 576 + 255) / 256, 256, 0, stream>>>(proj_w, Wout, Mcat);
  k_gemm2<64, 128, 4, 8, 0, true, true, true, true>
      <<<dim3(BB * S / 64, 1), 256, 0, stream>>>(
      yg, Mcat, proj_b, x, XZ, ores, BB * S, CC, 576);
  k_ln1<<<(BB * S + 255) / 256, 256, 0, stream>>>(ores, ln_w, ln_b, xln2);
  k_gemm2<128, 128, 8, 8, 1, true, false, false, false>
      <<<dim3(BB * S / 128, 3), 256, 0, stream>>>(
      xln2, fc1_w, fc1_b, nullptr, nullptr, h1, BB * S, 384, CC);
  k_gemm2<64, 128, 4, 8, 0, true, true, true, false>
      <<<dim3(BB * S / 64, 1), 256, 0, stream>>>(
      h1, fc2_w, fc2_b, ores, nullptr, (float*)d_out, BB * S, CC, 384);
}

// Round 8
// 436.204 us; speedup vs baseline: 1.1335x; 1.0516x over previous
//
#include <hip/hip_runtime.h>
#include <math.h>

// Problem constants (fixed by reference)
#define S   8000     // L = 20*20*20
#define BB  2
#define CC  96
#define DI  192      // d_inner
#define NS  16       // d_state
#define RK  6        // dt_rank
#define GG  6        // B * 3 directions
#define NC  200      // scan chunks
#define LC  40       // chunk length
#define ND  38       // dt_rank + 2*d_state

// l -> pos mapping per direction.
__device__ __forceinline__ int pos_from_l(int dir, int l) {
  if (dir == 0) return l;
  int a  = l / 400;
  int r  = l - a * 400;
  int bq = r / 20;
  int cq = r - bq * 20;
  if (dir == 1) return cq * 400 + a * 20 + bq;   // (h=a, w=bq, d=cq)
  return bq * 400 + cq * 20 + a;                 // (w=a, d=bq, h=cq)
}

__device__ __forceinline__ float silu(float z) {
  return z / (1.f + __expf(-z));
}

// sum across lane pairs (xor 1) via DPP quad_perm [1,0,3,2]
__device__ __forceinline__ float pair_sum(float y) {
  return y + __int_as_float(__builtin_amdgcn_update_dpp(
      0, __float_as_int(y), 0xB1, 0xF, 0xF, true));
}

// ---------------- K0: double LayerNorm over channels (per position) -------
__global__ __launch_bounds__(256) void k_ln2(const float* __restrict__ x,
    const float* __restrict__ lnw, const float* __restrict__ lnb,
    const float* __restrict__ mlnw, const float* __restrict__ mlnb,
    float* __restrict__ xn) {
  int t = blockIdx.x * blockDim.x + threadIdx.x;
  if (t >= BB * S) return;
  int b = t / S, pos = t - b * S;
  const float* xp = x + (size_t)b * CC * S + pos;
  float s1 = 0.f, s2 = 0.f;
  for (int c = 0; c < CC; ++c) { float v = xp[(size_t)c * S]; s1 += v; s2 += v * v; }
  float u = s1 * (1.f / CC);
  float var = s2 * (1.f / CC) - u * u;
  float rstd = rsqrtf(var + 1e-6f);
  float t1 = 0.f, t2 = 0.f;
  for (int c = 0; c < CC; ++c) {
    float y1 = fmaf(lnw[c], (xp[(size_t)c * S] - u) * rstd, lnb[c]);
    t1 += y1; t2 += y1 * y1;
  }
  float u2 = t1 * (1.f / CC);
  float var2 = t2 * (1.f / CC) - u2 * u2;
  float rstd2 = rsqrtf(var2 + 1e-5f);
  float* o = xn + (size_t)t * CC;
  for (int c = 0; c < CC; ++c) {
    float y1 = fmaf(lnw[c], (xp[(size_t)c * S] - u) * rstd, lnb[c]);
    o[c] = fmaf(mlnw[c], (y1 - u2) * rstd2, mlnb[c]);
  }
}

// ---------------- single LayerNorm (B,C,S) -> (B*S,C) --------------------
__global__ __launch_bounds__(256) void k_ln1(const float* __restrict__ xi,
    const float* __restrict__ lnw, const float* __restrict__ lnb,
    float* __restrict__ out) {
  int t = blockIdx.x * blockDim.x + threadIdx.x;
  if (t >= BB * S) return;
  int b = t / S, pos = t - b * S;
  const float* xp = xi + (size_t)b * CC * S + pos;
  float s1 = 0.f, s2 = 0.f;
  for (int c = 0; c < CC; ++c) { float v = xp[(size_t)c * S]; s1 += v; s2 += v * v; }
  float u = s1 * (1.f / CC);
  float var = s2 * (1.f / CC) - u * u;
  float rstd = rsqrtf(var + 1e-6f);
  float* o = out + (size_t)t * CC;
  for (int c = 0; c < CC; ++c)
    o[c] = fmaf(lnw[c], (xp[(size_t)c * S] - u) * rstd, lnb[c]);
}

// -------- old 64x64 fp32 GEMM (kept for Wx: N=38, K=192) -----------------
template <int ACT, bool BIAS, bool RESID, bool OUT_BCS>
__global__ __launch_bounds__(256) void k_gemm(const float* __restrict__ A,
    const float* __restrict__ Bw, const float* __restrict__ bias,
    const float* __restrict__ resid, float* __restrict__ Cmat,
    int M, int N, int K) {
  __shared__ float As[16][68];
  __shared__ float Bs[16][68];
  int tid = threadIdx.x;
  int tx = tid & 15, ty = tid >> 4;
  int m0 = blockIdx.x * 64, n0 = blockIdx.y * 64;
  float acc[4][4] = {};
  for (int kk = 0; kk < K; kk += 16) {
#pragma unroll
    for (int i = 0; i < 4; ++i) {
      int idx = tid + i * 256;
      int am = idx >> 4, ak = idx & 15;
      As[ak][am] = A[(size_t)(m0 + am) * K + kk + ak];
    }
#pragma unroll
    for (int i = 0; i < 4; ++i) {
      int idx = tid + i * 256;
      int bn = idx >> 4, bk = idx & 15;
      Bs[bk][bn] = (n0 + bn < N) ? Bw[(size_t)(n0 + bn) * K + kk + bk] : 0.f;
    }
    __syncthreads();
#pragma unroll
    for (int k = 0; k < 16; ++k) {
      float4 av = *(const float4*)&As[k][ty * 4];
      float4 bv = *(const float4*)&Bs[k][tx * 4];
      acc[0][0] = fmaf(av.x, bv.x, acc[0][0]);
      acc[0][1] = fmaf(av.x, bv.y, acc[0][1]);
      acc[0][2] = fmaf(av.x, bv.z, acc[0][2]);
      acc[0][3] = fmaf(av.x, bv.w, acc[0][3]);
      acc[1][0] = fmaf(av.y, bv.x, acc[1][0]);
      acc[1][1] = fmaf(av.y, bv.y, acc[1][1]);
      acc[1][2] = fmaf(av.y, bv.z, acc[1][2]);
      acc[1][3] = fmaf(av.y, bv.w, acc[1][3]);
      acc[2][0] = fmaf(av.z, bv.x, acc[2][0]);
      acc[2][1] = fmaf(av.z, bv.y, acc[2][1]);
      acc[2][2] = fmaf(av.z, bv.z, acc[2][2]);
      acc[2][3] = fmaf(av.z, bv.w, acc[2][3]);
      acc[3][0] = fmaf(av.w, bv.x, acc[3][0]);
      acc[3][1] = fmaf(av.w, bv.y, acc[3][1]);
      acc[3][2] = fmaf(av.w, bv.z, acc[3][2]);
      acc[3][3] = fmaf(av.w, bv.w, acc[3][3]);
    }
    __syncthreads();
  }
#pragma unroll
  for (int i = 0; i < 4; ++i) {
    int m = m0 + ty * 4 + i;
#pragma unroll
    for (int j = 0; j < 4; ++j) {
      int n = n0 + tx * 4 + j;
      if (n < N) {
        float v = acc[i][j];
        if (BIAS) v += bias[n];
        if (ACT == 1) v = 0.5f * v * (1.f + erff(v * 0.70710678118654752f));
        if (RESID || OUT_BCS) {
          int bb = m / S, pp = m - bb * S;
          size_t oidx = ((size_t)bb * CC + n) * S + pp;
          if (RESID) v += resid[oidx];
          if (OUT_BCS) { Cmat[oidx] = v; continue; }
        }
        Cmat[(size_t)m * N + n] = v;
      }
    }
  }
}

// -------- big-tile fp32 GEMM: BMxBN tile, TMxTN micro, 256 thr -----------
// GATEA: multiply A element (m=(b,l), k=dir*192+e) by silu(z[b,pos(dir,l),e])
template <int BM, int BN, int TM, int TN, int ACT, bool BIAS, bool RESID,
          bool OUT_BCS, bool GATEA>
__global__ __launch_bounds__(256) void k_gemm2(const float* __restrict__ A,
    const float* __restrict__ Bw, const float* __restrict__ bias,
    const float* __restrict__ resid, const float* __restrict__ XZg,
    float* __restrict__ Cmat, int M, int N, int K) {
  constexpr int BK = 16;
  constexpr int NTX = BN / TN;
  constexpr int NTY = BM / TM;
  static_assert(NTX * NTY == 256, "bad tile cfg");
  __shared__ float As[BK][BM + 4];
  __shared__ float Bs[BK][BN + 4];
  int tid = threadIdx.x;
  int tx = tid % NTX, ty = tid / NTX;
  int m0 = blockIdx.x * BM, n0 = blockIdx.y * BN;
  float acc[TM][TN] = {};
  int r = tid >> 2, cq = tid & 3;
  for (int kk = 0; kk < K; kk += BK) {
#pragma unroll
    for (int rr = 0; rr < BM; rr += 64) {
      int m = m0 + rr + r;
      float4 v = *(const float4*)&A[(size_t)m * K + kk + cq * 4];
      if (GATEA) {
        int bb = m / S, ll = m - bb * S;
        int j = kk + cq * 4;
        int dir = j / DI; int e0 = j - dir * DI;
        int p = pos_from_l(dir, ll);
        const float4 z4 = *(const float4*)&XZg[((size_t)bb * S + p) * 384 + DI + e0];
        v.x *= silu(z4.x); v.y *= silu(z4.y);
        v.z *= silu(z4.z); v.w *= silu(z4.w);
      }
      As[cq * 4 + 0][rr + r] = v.x; As[cq * 4 + 1][rr + r] = v.y;
      As[cq * 4 + 2][rr + r] = v.z; As[cq * 4 + 3][rr + r] = v.w;
    }
#pragma unroll
    for (int rr = 0; rr < BN; rr += 64) {
      int n = n0 + rr + r;
      float4 v = make_float4(0.f, 0.f, 0.f, 0.f);
      if (n < N) v = *(const float4*)&Bw[(size_t)n * K + kk + cq * 4];
      Bs[cq * 4 + 0][rr + r] = v.x; Bs[cq * 4 + 1][rr + r] = v.y;
      Bs[cq * 4 + 2][rr + r] = v.z; Bs[cq * 4 + 3][rr + r] = v.w;
    }
    __syncthreads();
#pragma unroll
    for (int k = 0; k < BK; ++k) {
      float a[TM], b[TN];
#pragma unroll
      for (int i = 0; i < TM; i += 4)
        *(float4*)&a[i] = *(const float4*)&As[k][ty * TM + i];
#pragma unroll
      for (int j = 0; j < TN; j += 4)
        *(float4*)&b[j] = *(const float4*)&Bs[k][tx * TN + j];
#pragma unroll
      for (int i = 0; i < TM; ++i)
#pragma unroll
        for (int j = 0; j < TN; ++j)
          acc[i][j] = fmaf(a[i], b[j], acc[i][j]);
    }
    __syncthreads();
  }
#pragma unroll
  for (int i = 0; i < TM; ++i) {
    int m = m0 + ty * TM + i;
#pragma unroll
    for (int j = 0; j < TN; ++j) {
      int n = n0 + tx * TN + j;
      if (n < N) {
        float v = acc[i][j];
        if (BIAS) v += bias[n];
        if (ACT == 1) v = 0.5f * v * (1.f + erff(v * 0.70710678118654752f));
        if (RESID || OUT_BCS) {
          int bb = m / S, pp = m - bb * S;
          size_t oidx = ((size_t)bb * CC + n) * S + pp;
          if (RESID) v += resid[oidx];
          if (OUT_BCS) { Cmat[oidx] = v; continue; }
        }
        Cmat[(size_t)m * N + n] = v;
      }
    }
  }
}

// ---------------- causal depthwise conv(4) + SiLU, gathered input --------
__global__ __launch_bounds__(256) void k_conv(const float* __restrict__ XZ,
    const float* __restrict__ cw, const float* __restrict__ cb,
    float* __restrict__ xc) {
  int t = blockIdx.x * blockDim.x + threadIdx.x;
  if (t >= GG * S * DI) return;
  int e = t % DI; int gl = t / DI; int l = gl % S; int g = gl / S;
  int b = g / 3, dir = g - (g / 3) * 3;
  float acc = cb[e];
#pragma unroll
  for (int k = 0; k < 4; ++k) {
    int ls = l + k - 3;
    if (ls >= 0) {
      int p = pos_from_l(dir, ls);
      acc = fmaf(cw[e * 4 + k], XZ[((size_t)b * S + p) * 384 + e], acc);
    }
  }
  xc[(size_t)gl * DI + e] = acc * (1.f / (1.f + __expf(-acc)));
}

// ======== scan kernels: pair-split — 2 lanes per (g,e), 8 states each ====
// LDS tile: sBC[l][j]: j 0..5 = dt_r, j 8..23 = B, j 24..39 = C
__device__ __forceinline__ void stage_bc(float (*sBC)[40],
    const float* __restrict__ xdbl, int g, int c, int tid) {
  const float* src = xdbl + ((size_t)g * S + c * LC) * ND;
  for (int i = tid; i < LC * ND; i += 192) {
    int row = i / ND, col = i - row * ND;
    int dst = (col < RK) ? col : col + 2;
    sBC[row][dst] = src[(size_t)row * ND + col];
  }
}

// common per-step prologue: dt via fast softplus
#define DT_COMMON(l)                                                     \
  float a = bde;                                                         \
  {                                                                      \
    float4 r0 = *(const float4*)&sBC[l][0];                              \
    float2 r1 = *(const float2*)&sBC[l][4];                              \
    a = fmaf(wdt[0], r0.x, a); a = fmaf(wdt[1], r0.y, a);                \
    a = fmaf(wdt[2], r0.z, a); a = fmaf(wdt[3], r0.w, a);                \
    a = fmaf(wdt[4], r1.x, a); a = fmaf(wdt[5], r1.y, a);                \
  }                                                                      \
  float d = fmaxf(a, 0.f) + __logf(1.f + __expf(-fabsf(a)));

__global__ __launch_bounds__(192) void k_scanA(const float* __restrict__ xc,
    const float* __restrict__ xdbl, const float* __restrict__ Wdt,
    const float* __restrict__ bdt, const float* __restrict__ A_log,
    float* __restrict__ PA, float* __restrict__ EA) {
  __shared__ float sBC[LC][40];
  int c = blockIdx.x, g = blockIdx.y;
  int tid = threadIdx.x;
  int e = blockIdx.z * 96 + (tid >> 1);
  int hf = tid & 1;
  stage_bc(sBC, xdbl, g, c, tid);
  float wdt[RK];
#pragma unroll
  for (int r = 0; r < RK; ++r) wdt[r] = Wdt[e * RK + r];
  float bde = bdt[e];
  float base = -__expf(A_log[e * NS]);
  bool fast = true;
#pragma unroll
  for (int s = 1; s < NS; ++s) {
    float aes = -__expf(A_log[e * NS + s]);
    fast = fast && (fabsf(aes / base - (float)(s + 1)) < 1e-3f);
  }
  float h[8];
#pragma unroll
  for (int k = 0; k < 8; ++k) h[k] = 0.f;
  float T = 0.f;
  const float* xptr = xc + ((size_t)g * S + c * LC) * DI + e;
  __syncthreads();
  if (fast) {
    for (int l0 = 0; l0 < LC; l0 += 8) {
      float xb[8];
#pragma unroll
      for (int j = 0; j < 8; ++j) xb[j] = xptr[(size_t)(l0 + j) * DI];
#pragma unroll
      for (int j = 0; j < 8; ++j) {
        int l = l0 + j;
        DT_COMMON(l)
        T += d;
        float w = d * xb[j];
        float r = __expf(d * base);
        float r2 = r * r, r3 = r2 * r, r4 = r2 * r2;
        float r5 = r4 * r, r6 = r4 * r2, r7 = r6 * r;
        float f = hf ? r4 * r5 : r;       // r^(8*hf+1)
        float4 Ba = *(const float4*)&sBC[l][8 + hf * 8];
        float4 Bb = *(const float4*)&sBC[l][12 + hf * 8];
        h[0] = fmaf(f,      h[0], w * Ba.x);
        h[1] = fmaf(f * r,  h[1], w * Ba.y);
        h[2] = fmaf(f * r2, h[2], w * Ba.z);
        h[3] = fmaf(f * r3, h[3], w * Ba.w);
        h[4] = fmaf(f * r4, h[4], w * Bb.x);
        h[5] = fmaf(f * r5, h[5], w * Bb.y);
        h[6] = fmaf(f * r6, h[6], w * Bb.z);
        h[7] = fmaf(f * r7, h[7], w * Bb.w);
      }
    }
  } else {
    float Aes[8];
#pragma unroll
    for (int k = 0; k < 8; ++k) Aes[k] = -__expf(A_log[e * NS + hf * 8 + k]);
#pragma unroll 1
    for (int l = 0; l < LC; ++l) {
      DT_COMMON(l)
      T += d;
      float w = d * xptr[(size_t)l * DI];
#pragma unroll
      for (int k = 0; k < 8; ++k) {
        float q = __expf(d * Aes[k]);
        h[k] = fmaf(q, h[k], w * sBC[l][8 + hf * 8 + k]);
      }
    }
  }
  float* pp = PA + (((size_t)g * NC + c) * DI + e) * NS + hf * 8;
  float* ep = EA + (((size_t)g * NC + c) * DI + e) * NS + hf * 8;
  float po[8];
  if (fast) {
    float r = __expf(base * T);
    float r2 = r * r, r3 = r2 * r, r4 = r2 * r2;
    float r5 = r4 * r, r6 = r4 * r2, r7 = r6 * r;
    float f = hf ? r4 * r5 : r;
    po[0] = f; po[1] = f * r; po[2] = f * r2; po[3] = f * r3;
    po[4] = f * r4; po[5] = f * r5; po[6] = f * r6; po[7] = f * r7;
  } else {
#pragma unroll
    for (int k = 0; k < 8; ++k)
      po[k] = __expf(-__expf(A_log[e * NS + hf * 8 + k]) * T);
  }
  *(float4*)&pp[0] = make_float4(po[0], po[1], po[2], po[3]);
  *(float4*)&pp[4] = make_float4(po[4], po[5], po[6], po[7]);
  *(float4*)&ep[0] = make_float4(h[0], h[1], h[2], h[3]);
  *(float4*)&ep[4] = make_float4(h[4], h[5], h[6], h[7]);
}

// inter-chunk sequential combine (Hin aliases PA: loads precede stores)
__global__ __launch_bounds__(256) void k_scanB(const float* PA,
    const float* EA, float* Hin) {
  int idx = blockIdx.x * blockDim.x + threadIdx.x;
  if (idx >= GG * DI * NS) return;
  int g = idx / (DI * NS); int es = idx - g * (DI * NS);
  size_t stride = (size_t)DI * NS;
  size_t b0 = (size_t)g * NC * stride + es;
  float h = 0.f;
  for (int c0 = 0; c0 < NC; c0 += 8) {
    float p8[8], e8[8];
#pragma unroll
    for (int j = 0; j < 8; ++j) {
      size_t ix = b0 + (size_t)(c0 + j) * stride;
      p8[j] = PA[ix]; e8[j] = EA[ix];
    }
#pragma unroll
    for (int j = 0; j < 8; ++j) {
      size_t ix = b0 + (size_t)(c0 + j) * stride;
      Hin[ix] = h;
      h = fmaf(p8[j], h, e8[j]);
    }
  }
}

__global__ __launch_bounds__(192) void k_scanC(const float* __restrict__ xc,
    const float* __restrict__ xdbl, const float* __restrict__ Wdt,
    const float* __restrict__ bdt, const float* __restrict__ A_log,
    const float* __restrict__ Hin, const float* __restrict__ Dp,
    float* __restrict__ yg) {
  __shared__ float sBC[LC][40];
  int c = blockIdx.x, g = blockIdx.y;
  int tid = threadIdx.x;
  int e = blockIdx.z * 96 + (tid >> 1);
  int hf = tid & 1;
  const float* hp = Hin + (((size_t)g * NC + c) * DI + e) * NS + hf * 8;
  float4 h0 = *(const float4*)(hp + 0);
  float4 h1v = *(const float4*)(hp + 4);
  stage_bc(sBC, xdbl, g, c, tid);
  float wdt[RK];
#pragma unroll
  for (int r = 0; r < RK; ++r) wdt[r] = Wdt[e * RK + r];
  float bde = bdt[e];
  float dpe = Dp[e];
  float base = -__expf(A_log[e * NS]);
  bool fast = true;
#pragma unroll
  for (int s = 1; s < NS; ++s) {
    float aes = -__expf(A_log[e * NS + s]);
    fast = fast && (fabsf(aes / base - (float)(s + 1)) < 1e-3f);
  }
  float h[8] = {h0.x, h0.y, h0.z, h0.w, h1v.x, h1v.y, h1v.z, h1v.w};
  const float* xptr = xc + ((size_t)g * S + c * LC) * DI + e;
  int b = g / 3, dir = g - (g / 3) * 3;
  float* yo = yg + ((size_t)b * S + c * LC) * 576 + dir * DI + e;
  __syncthreads();
  if (fast) {
    for (int l0 = 0; l0 < LC; l0 += 8) {
      float xb[8];
#pragma unroll
      for (int j = 0; j < 8; ++j) xb[j] = xptr[(size_t)(l0 + j) * DI];
#pragma unroll
      for (int j = 0; j < 8; ++j) {
        int l = l0 + j;
        DT_COMMON(l)
        float xv = xb[j];
        float w = d * xv;
        float r = __expf(d * base);
        float r2 = r * r, r3 = r2 * r, r4 = r2 * r2;
        float r5 = r4 * r, r6 = r4 * r2, r7 = r6 * r;
        float f = hf ? r4 * r5 : r;       // r^(8*hf+1)
        float4 Ba = *(const float4*)&sBC[l][8 + hf * 8];
        float4 Bb = *(const float4*)&sBC[l][12 + hf * 8];
        float4 Ca = *(const float4*)&sBC[l][24 + hf * 8];
        float4 Cb = *(const float4*)&sBC[l][28 + hf * 8];
        float y0 = hf ? 0.f : xv * dpe;
        float y1 = 0.f;
        h[0] = fmaf(f,      h[0], w * Ba.x); y0 = fmaf(h[0], Ca.x, y0);
        h[1] = fmaf(f * r,  h[1], w * Ba.y); y1 = fmaf(h[1], Ca.y, y1);
        h[2] = fmaf(f * r2, h[2], w * Ba.z); y0 = fmaf(h[2], Ca.z, y0);
        h[3] = fmaf(f * r3, h[3], w * Ba.w); y1 = fmaf(h[3], Ca.w, y1);
        h[4] = fmaf(f * r4, h[4], w * Bb.x); y0 = fmaf(h[4], Cb.x, y0);
        h[5] = fmaf(f * r5, h[5], w * Bb.y); y1 = fmaf(h[5], Cb.y, y1);
        h[6] = fmaf(f * r6, h[6], w * Bb.z); y0 = fmaf(h[6], Cb.z, y0);
        h[7] = fmaf(f * r7, h[7], w * Bb.w); y1 = fmaf(h[7], Cb.w, y1);
        float ysum = pair_sum(y0 + y1);
        if (!hf) yo[(size_t)l * 576] = ysum;
      }
    }
  } else {
    float Aes[8];
#pragma unroll
    for (int k = 0; k < 8; ++k) Aes[k] = -__expf(A_log[e * NS + hf * 8 + k]);
#pragma unroll 1
    for (int l = 0; l < LC; ++l) {
      DT_COMMON(l)
      float xv = xptr[(size_t)l * DI];
      float w = d * xv;
      float y = hf ? 0.f : xv * dpe;
#pragma unroll
      for (int k = 0; k < 8; ++k) {
        float q = __expf(d * Aes[k]);
        h[k] = fmaf(q, h[k], w * sBC[l][8 + hf * 8 + k]);
        y = fmaf(h[k], sBC[l][24 + hf * 8 + k], y);
      }
      float ysum = pair_sum(y);
      if (!hf) yo[(size_t)l * 576] = ysum;
    }
  }
}

// ---------------- fold Wout into proj_w: Mcat[o, dir*192+e] --------------
__global__ __launch_bounds__(256) void k_foldW(const float* __restrict__ proj_w,
    const float* __restrict__ Wout, float* __restrict__ Mcat) {
  int t = blockIdx.x * blockDim.x + threadIdx.x;
  if (t >= CC * 576) return;
  int o = t / 576; int j = t - o * 576; int dir = j / DI; int e = j - dir * DI;
  float a = 0.f;
  for (int c2 = 0; c2 < CC; ++c2)
    a = fmaf(proj_w[o * 288 + dir * CC + c2], Wout[c2 * DI + e], a);
  Mcat[t] = a;
}

extern "C" void kernel_launch(void* const* d_in, const int* in_sizes, int n_in,
                              void* d_out, int out_size, void* d_ws, size_t ws_size,
                              hipStream_t stream) {
  const float* x      = (const float*)d_in[0];
  const float* ln_w   = (const float*)d_in[1];
  const float* ln_b   = (const float*)d_in[2];
  const float* mln_w  = (const float*)d_in[3];
  const float* mln_b  = (const float*)d_in[4];
  const float* Win    = (const float*)d_in[5];
  const float* conv_w = (const float*)d_in[6];
  const float* conv_b = (const float*)d_in[7];
  const float* Wx     = (const float*)d_in[8];
  const float* Wdt    = (const float*)d_in[9];
  const float* bdt    = (const float*)d_in[10];
  const float* A_log  = (const float*)d_in[11];
  const float* Dp     = (const float*)d_in[12];
  const float* Wout   = (const float*)d_in[13];
  const float* proj_w = (const float*)d_in[14];
  const float* proj_b = (const float*)d_in[15];
  const float* fc1_w  = (const float*)d_in[16];
  const float* fc1_b  = (const float*)d_in[17];
  const float* fc2_w  = (const float*)d_in[18];
  const float* fc2_b  = (const float*)d_in[19];

  float* ws = (float*)d_ws;
  size_t off = 0;
  float* xn   = ws + off; off += (size_t)BB * S * CC;       // 1.536M
  float* XZ   = ws + off; off += (size_t)BB * S * 384;      // 6.144M
  float* xc   = ws + off; off += (size_t)GG * S * DI;       // 9.216M
  float* xdbl = ws + off; off += (size_t)GG * S * ND;       // 1.824M
  float* PA   = ws + off; off += (size_t)GG * NC * DI * NS; // 3.686M
  float* EA   = ws + off; off += (size_t)GG * NC * DI * NS; // 3.686M
  float* yg   = ws + off; off += (size_t)BB * S * 576;      // 9.216M
  float* Mcat = ws + off; off += (size_t)CC * 576;
  if (ws_size < off * sizeof(float)) return;                // ~142 MB; guard
  float* Hin  = PA;     // in-place in scanB (group loads precede stores)
  float* ores = xn;     // xn dead after Win GEMM
  float* xln2 = xc;     // xc dead after scanC
  float* h1   = XZ;     // XZ dead after proj (gate fused there)

  k_ln2<<<(BB * S + 255) / 256, 256, 0, stream>>>(x, ln_w, ln_b, mln_w, mln_b, xn);
  k_gemm2<128, 128, 8, 8, 0, false, false, false, false>
      <<<dim3(BB * S / 128, 3), 256, 0, stream>>>(
      xn, Win, nullptr, nullptr, nullptr, XZ, BB * S, 384, CC);
  k_conv<<<(GG * S * DI + 255) / 256, 256, 0, stream>>>(XZ, conv_w, conv_b, xc);
  k_gemm<0, false, false, false><<<dim3(GG * S / 64, 1), 256, 0, stream>>>(
      xc, Wx, nullptr, nullptr, xdbl, GG * S, ND, DI);
  k_scanA<<<dim3(NC, GG, 2), 192, 0, stream>>>(xc, xdbl, Wdt, bdt, A_log, PA, EA);
  k_scanB<<<(GG * DI * NS + 255) / 256, 256, 0, stream>>>(PA, EA, Hin);
  k_scanC<<<dim3(NC, GG, 2), 192, 0, stream>>>(xc, xdbl, Wdt, bdt, A_log, Hin, Dp, yg);
  k_foldW<<<(CC * 576 + 255) / 256, 256, 0, stream>>>(proj_w, Wout, Mcat);
  k_gemm2<64, 128, 4, 8, 0, true, true, true, true>
      <<<dim3(BB * S / 64, 1), 256, 0, stream>>>(
      yg, Mcat, proj_b, x, XZ, ores, BB * S, CC, 576);
  k_ln1<<<(BB * S + 255) / 256, 256, 0, stream>>>(ores, ln_w, ln_b, xln2);
  k_gemm2<128, 128, 8, 8, 1, true, false, false, false>
      <<<dim3(BB * S / 128, 3), 256, 0, stream>>>(
      xln2, fc1_w, fc1_b, nullptr, nullptr, h1, BB * S, 384, CC);
  k_gemm2<64, 128, 4, 8, 0, true, true, true, false>
      <<<dim3(BB * S / 64, 1), 256, 0, stream>>>(
      h1, fc2_w, fc2_b, ores, nullptr, (float*)d_out, BB * S, CC, 384);
}

// Round 9
// 381.052 us; speedup vs baseline: 1.2975x; 1.1447x over previous
//
#include <hip/hip_runtime.h>
#include <math.h>

// Problem constants (fixed by reference)
#define S   8000     // L = 20*20*20
#define BB  2
#define CC  96
#define DI  192      // d_inner
#define NS  16       // d_state
#define RK  6        // dt_rank
#define GG  6        // B * 3 directions
#define NC  200      // scan chunks
#define LC  40       // chunk length
#define ND  38       // dt_rank + 2*d_state

// l -> pos mapping per direction.
__device__ __forceinline__ int pos_from_l(int dir, int l) {
  if (dir == 0) return l;
  int a  = l / 400;
  int r  = l - a * 400;
  int bq = r / 20;
  int cq = r - bq * 20;
  if (dir == 1) return cq * 400 + a * 20 + bq;   // (h=a, w=bq, d=cq)
  return bq * 400 + cq * 20 + a;                 // (w=a, d=bq, h=cq)
}

__device__ __forceinline__ float silu(float z) {
  return z / (1.f + __expf(-z));
}

// sum across lane pairs (xor 1) via DPP quad_perm [1,0,3,2]
__device__ __forceinline__ float pair_sum(float y) {
  return y + __int_as_float(__builtin_amdgcn_update_dpp(
      0, __float_as_int(y), 0xB1, 0xF, 0xF, true));
}

// ---------------- K0: double LayerNorm over channels (per position) -------
__global__ __launch_bounds__(256) void k_ln2(const float* __restrict__ x,
    const float* __restrict__ lnw, const float* __restrict__ lnb,
    const float* __restrict__ mlnw, const float* __restrict__ mlnb,
    float* __restrict__ xn) {
  int t = blockIdx.x * blockDim.x + threadIdx.x;
  if (t >= BB * S) return;
  int b = t / S, pos = t - b * S;
  const float* xp = x + (size_t)b * CC * S + pos;
  float s1 = 0.f, s2 = 0.f;
  for (int c = 0; c < CC; ++c) { float v = xp[(size_t)c * S]; s1 += v; s2 += v * v; }
  float u = s1 * (1.f / CC);
  float var = s2 * (1.f / CC) - u * u;
  float rstd = rsqrtf(var + 1e-6f);
  float t1 = 0.f, t2 = 0.f;
  for (int c = 0; c < CC; ++c) {
    float y1 = fmaf(lnw[c], (xp[(size_t)c * S] - u) * rstd, lnb[c]);
    t1 += y1; t2 += y1 * y1;
  }
  float u2 = t1 * (1.f / CC);
  float var2 = t2 * (1.f / CC) - u2 * u2;
  float rstd2 = rsqrtf(var2 + 1e-5f);
  float* o = xn + (size_t)t * CC;
  for (int c = 0; c < CC; ++c) {
    float y1 = fmaf(lnw[c], (xp[(size_t)c * S] - u) * rstd, lnb[c]);
    o[c] = fmaf(mlnw[c], (y1 - u2) * rstd2, mlnb[c]);
  }
}

// ---------------- single LayerNorm (B,C,S) -> (B*S,C) --------------------
__global__ __launch_bounds__(256) void k_ln1(const float* __restrict__ xi,
    const float* __restrict__ lnw, const float* __restrict__ lnb,
    float* __restrict__ out) {
  int t = blockIdx.x * blockDim.x + threadIdx.x;
  if (t >= BB * S) return;
  int b = t / S, pos = t - b * S;
  const float* xp = xi + (size_t)b * CC * S + pos;
  float s1 = 0.f, s2 = 0.f;
  for (int c = 0; c < CC; ++c) { float v = xp[(size_t)c * S]; s1 += v; s2 += v * v; }
  float u = s1 * (1.f / CC);
  float var = s2 * (1.f / CC) - u * u;
  float rstd = rsqrtf(var + 1e-6f);
  float* o = out + (size_t)t * CC;
  for (int c = 0; c < CC; ++c)
    o[c] = fmaf(lnw[c], (xp[(size_t)c * S] - u) * rstd, lnb[c]);
}

// -------- old 64x64 fp32 GEMM (kept for Wx: N=38, K=192) -----------------
template <int ACT, bool BIAS, bool RESID, bool OUT_BCS>
__global__ __launch_bounds__(256) void k_gemm(const float* __restrict__ A,
    const float* __restrict__ Bw, const float* __restrict__ bias,
    const float* __restrict__ resid, float* __restrict__ Cmat,
    int M, int N, int K) {
  __shared__ float As[16][68];
  __shared__ float Bs[16][68];
  int tid = threadIdx.x;
  int tx = tid & 15, ty = tid >> 4;
  int m0 = blockIdx.x * 64, n0 = blockIdx.y * 64;
  float acc[4][4] = {};
  for (int kk = 0; kk < K; kk += 16) {
#pragma unroll
    for (int i = 0; i < 4; ++i) {
      int idx = tid + i * 256;
      int am = idx >> 4, ak = idx & 15;
      As[ak][am] = A[(size_t)(m0 + am) * K + kk + ak];
    }
#pragma unroll
    for (int i = 0; i < 4; ++i) {
      int idx = tid + i * 256;
      int bn = idx >> 4, bk = idx & 15;
      Bs[bk][bn] = (n0 + bn < N) ? Bw[(size_t)(n0 + bn) * K + kk + bk] : 0.f;
    }
    __syncthreads();
#pragma unroll
    for (int k = 0; k < 16; ++k) {
      float4 av = *(const float4*)&As[k][ty * 4];
      float4 bv = *(const float4*)&Bs[k][tx * 4];
      acc[0][0] = fmaf(av.x, bv.x, acc[0][0]);
      acc[0][1] = fmaf(av.x, bv.y, acc[0][1]);
      acc[0][2] = fmaf(av.x, bv.z, acc[0][2]);
      acc[0][3] = fmaf(av.x, bv.w, acc[0][3]);
      acc[1][0] = fmaf(av.y, bv.x, acc[1][0]);
      acc[1][1] = fmaf(av.y, bv.y, acc[1][1]);
      acc[1][2] = fmaf(av.y, bv.z, acc[1][2]);
      acc[1][3] = fmaf(av.y, bv.w, acc[1][3]);
      acc[2][0] = fmaf(av.z, bv.x, acc[2][0]);
      acc[2][1] = fmaf(av.z, bv.y, acc[2][1]);
      acc[2][2] = fmaf(av.z, bv.z, acc[2][2]);
      acc[2][3] = fmaf(av.z, bv.w, acc[2][3]);
      acc[3][0] = fmaf(av.w, bv.x, acc[3][0]);
      acc[3][1] = fmaf(av.w, bv.y, acc[3][1]);
      acc[3][2] = fmaf(av.w, bv.z, acc[3][2]);
      acc[3][3] = fmaf(av.w, bv.w, acc[3][3]);
    }
    __syncthreads();
  }
#pragma unroll
  for (int i = 0; i < 4; ++i) {
    int m = m0 + ty * 4 + i;
#pragma unroll
    for (int j = 0; j < 4; ++j) {
      int n = n0 + tx * 4 + j;
      if (n < N) {
        float v = acc[i][j];
        if (BIAS) v += bias[n];
        if (ACT == 1) v = 0.5f * v * (1.f + erff(v * 0.70710678118654752f));
        if (RESID || OUT_BCS) {
          int bb = m / S, pp = m - bb * S;
          size_t oidx = ((size_t)bb * CC + n) * S + pp;
          if (RESID) v += resid[oidx];
          if (OUT_BCS) { Cmat[oidx] = v; continue; }
        }
        Cmat[(size_t)m * N + n] = v;
      }
    }
  }
}

// -------- conflict-free fp32 GEMM: BMxBN tile, TMxTN micro ---------------
// Reads: b = contiguous float4 at tx*4 (lanes span banks, conflict-free);
//        a = broadcast float4(s). Stores land 2-way max (stride%32==4).
// GATEA: multiply A element (m=(b,l), k=dir*192+e) by silu(z[b,pos(dir,l),e])
template <int THREADS, int BM, int BN, int TM, int TN, int ACT, bool BIAS,
          bool RESID, bool OUT_BCS, bool GATEA>
__global__ __launch_bounds__(THREADS) void k_gemm3(const float* __restrict__ A,
    const float* __restrict__ Bw, const float* __restrict__ bias,
    const float* __restrict__ resid, const float* __restrict__ XZg,
    float* __restrict__ Cmat, int M, int N, int K) {
  constexpr int BK = 16;
  constexpr int NTX = BN / TN;
  constexpr int NTY = BM / TM;
  static_assert(NTX * NTY == THREADS, "bad tile cfg");
  static_assert(TM % 4 == 0 && TN % 4 == 0, "micro must be x4");
  __shared__ float As[BK][BM + 4];
  __shared__ float Bs[BK][BN + 4];
  int tid = threadIdx.x;
  int tx = tid % NTX, ty = tid / NTX;
  int m0 = blockIdx.x * BM, n0 = blockIdx.y * BN;
  float acc[TM][TN] = {};
  constexpr int AF4 = BM * BK / 4;
  constexpr int BF4 = BN * BK / 4;
  for (int kk = 0; kk < K; kk += BK) {
#pragma unroll
    for (int idx = tid; idx < AF4; idx += THREADS) {
      int am = idx >> 2, kq = idx & 3;
      int m = m0 + am;
      float4 v = *(const float4*)&A[(size_t)m * K + kk + kq * 4];
      if (GATEA) {
        int bb = m / S, ll = m - bb * S;
        int j = kk + kq * 4;
        int dir = j / DI; int e0 = j - dir * DI;
        int p = pos_from_l(dir, ll);
        const float4 z4 = *(const float4*)&XZg[((size_t)bb * S + p) * 384 + DI + e0];
        v.x *= silu(z4.x); v.y *= silu(z4.y);
        v.z *= silu(z4.z); v.w *= silu(z4.w);
      }
      As[kq * 4 + 0][am] = v.x; As[kq * 4 + 1][am] = v.y;
      As[kq * 4 + 2][am] = v.z; As[kq * 4 + 3][am] = v.w;
    }
#pragma unroll
    for (int idx = tid; idx < BF4; idx += THREADS) {
      int bn = idx >> 2, kq = idx & 3;
      int n = n0 + bn;
      float4 v = make_float4(0.f, 0.f, 0.f, 0.f);
      if (n < N) v = *(const float4*)&Bw[(size_t)n * K + kk + kq * 4];
      Bs[kq * 4 + 0][bn] = v.x; Bs[kq * 4 + 1][bn] = v.y;
      Bs[kq * 4 + 2][bn] = v.z; Bs[kq * 4 + 3][bn] = v.w;
    }
    __syncthreads();
#pragma unroll
    for (int k = 0; k < BK; ++k) {
      float a[TM], b[TN];
#pragma unroll
      for (int i = 0; i < TM; i += 4)
        *(float4*)&a[i] = *(const float4*)&As[k][ty * TM + i];
#pragma unroll
      for (int j = 0; j < TN; j += 4)
        *(float4*)&b[j] = *(const float4*)&Bs[k][tx * TN + j];
#pragma unroll
      for (int i = 0; i < TM; ++i)
#pragma unroll
        for (int j = 0; j < TN; ++j)
          acc[i][j] = fmaf(a[i], b[j], acc[i][j]);
    }
    __syncthreads();
  }
#pragma unroll
  for (int i = 0; i < TM; ++i) {
    int m = m0 + ty * TM + i;
#pragma unroll
    for (int j = 0; j < TN; ++j) {
      int n = n0 + tx * TN + j;
      if (n < N) {
        float v = acc[i][j];
        if (BIAS) v += bias[n];
        if (ACT == 1) v = 0.5f * v * (1.f + erff(v * 0.70710678118654752f));
        if (RESID || OUT_BCS) {
          int bb = m / S, pp = m - bb * S;
          size_t oidx = ((size_t)bb * CC + n) * S + pp;
          if (RESID) v += resid[oidx];
          if (OUT_BCS) { Cmat[oidx] = v; continue; }
        }
        Cmat[(size_t)m * N + n] = v;
      }
    }
  }
}

// ---------------- causal depthwise conv(4) + SiLU, gathered input --------
__global__ __launch_bounds__(256) void k_conv(const float* __restrict__ XZ,
    const float* __restrict__ cw, const float* __restrict__ cb,
    float* __restrict__ xc) {
  int t = blockIdx.x * blockDim.x + threadIdx.x;
  if (t >= GG * S * DI) return;
  int e = t % DI; int gl = t / DI; int l = gl % S; int g = gl / S;
  int b = g / 3, dir = g - (g / 3) * 3;
  float acc = cb[e];
#pragma unroll
  for (int k = 0; k < 4; ++k) {
    int ls = l + k - 3;
    if (ls >= 0) {
      int p = pos_from_l(dir, ls);
      acc = fmaf(cw[e * 4 + k], XZ[((size_t)b * S + p) * 384 + e], acc);
    }
  }
  xc[(size_t)gl * DI + e] = acc * (1.f / (1.f + __expf(-acc)));
}

// ======== scan kernels: pair-split — 2 lanes per (g,e), 8 states each ====
// LDS tile: sBC[l][j]: j 0..5 = dt_r, j 8..23 = B, j 24..39 = C
__device__ __forceinline__ void stage_bc(float (*sBC)[40],
    const float* __restrict__ xdbl, int g, int c, int tid) {
  const float* src = xdbl + ((size_t)g * S + c * LC) * ND;
  for (int i = tid; i < LC * ND; i += 192) {
    int row = i / ND, col = i - row * ND;
    int dst = (col < RK) ? col : col + 2;
    sBC[row][dst] = src[(size_t)row * ND + col];
  }
}

// common per-step prologue: dt via fast softplus
#define DT_COMMON(l)                                                     \
  float a = bde;                                                         \
  {                                                                      \
    float4 r0 = *(const float4*)&sBC[l][0];                              \
    float2 r1 = *(const float2*)&sBC[l][4];                              \
    a = fmaf(wdt[0], r0.x, a); a = fmaf(wdt[1], r0.y, a);                \
    a = fmaf(wdt[2], r0.z, a); a = fmaf(wdt[3], r0.w, a);                \
    a = fmaf(wdt[4], r1.x, a); a = fmaf(wdt[5], r1.y, a);                \
  }                                                                      \
  float d = fmaxf(a, 0.f) + __logf(1.f + __expf(-fabsf(a)));

__global__ __launch_bounds__(192) void k_scanA(const float* __restrict__ xc,
    const float* __restrict__ xdbl, const float* __restrict__ Wdt,
    const float* __restrict__ bdt, const float* __restrict__ A_log,
    float* __restrict__ PA, float* __restrict__ EA) {
  __shared__ float sBC[LC][40];
  int c = blockIdx.x, g = blockIdx.y;
  int tid = threadIdx.x;
  int e = blockIdx.z * 96 + (tid >> 1);
  int hf = tid & 1;
  stage_bc(sBC, xdbl, g, c, tid);
  float wdt[RK];
#pragma unroll
  for (int r = 0; r < RK; ++r) wdt[r] = Wdt[e * RK + r];
  float bde = bdt[e];
  float base = -__expf(A_log[e * NS]);
  bool fast = true;
#pragma unroll
  for (int s = 1; s < NS; ++s) {
    float aes = -__expf(A_log[e * NS + s]);
    fast = fast && (fabsf(aes / base - (float)(s + 1)) < 1e-3f);
  }
  float h[8];
#pragma unroll
  for (int k = 0; k < 8; ++k) h[k] = 0.f;
  float T = 0.f;
  const float* xptr = xc + ((size_t)g * S + c * LC) * DI + e;
  __syncthreads();
  if (fast) {
    for (int l0 = 0; l0 < LC; l0 += 8) {
      float xb[8];
#pragma unroll
      for (int j = 0; j < 8; ++j) xb[j] = xptr[(size_t)(l0 + j) * DI];
#pragma unroll
      for (int j = 0; j < 8; ++j) {
        int l = l0 + j;
        DT_COMMON(l)
        T += d;
        float w = d * xb[j];
        float r = __expf(d * base);
        float r2 = r * r, r3 = r2 * r, r4 = r2 * r2;
        float r5 = r4 * r, r6 = r4 * r2, r7 = r6 * r;
        float f = hf ? r4 * r5 : r;       // r^(8*hf+1)
        float4 Ba = *(const float4*)&sBC[l][8 + hf * 8];
        float4 Bb = *(const float4*)&sBC[l][12 + hf * 8];
        h[0] = fmaf(f,      h[0], w * Ba.x);
        h[1] = fmaf(f * r,  h[1], w * Ba.y);
        h[2] = fmaf(f * r2, h[2], w * Ba.z);
        h[3] = fmaf(f * r3, h[3], w * Ba.w);
        h[4] = fmaf(f * r4, h[4], w * Bb.x);
        h[5] = fmaf(f * r5, h[5], w * Bb.y);
        h[6] = fmaf(f * r6, h[6], w * Bb.z);
        h[7] = fmaf(f * r7, h[7], w * Bb.w);
      }
    }
  } else {
    float Aes[8];
#pragma unroll
    for (int k = 0; k < 8; ++k) Aes[k] = -__expf(A_log[e * NS + hf * 8 + k]);
#pragma unroll 1
    for (int l = 0; l < LC; ++l) {
      DT_COMMON(l)
      T += d;
      float w = d * xptr[(size_t)l * DI];
#pragma unroll
      for (int k = 0; k < 8; ++k) {
        float q = __expf(d * Aes[k]);
        h[k] = fmaf(q, h[k], w * sBC[l][8 + hf * 8 + k]);
      }
    }
  }
  float* pp = PA + (((size_t)g * NC + c) * DI + e) * NS + hf * 8;
  float* ep = EA + (((size_t)g * NC + c) * DI + e) * NS + hf * 8;
  float po[8];
  if (fast) {
    float r = __expf(base * T);
    float r2 = r * r, r3 = r2 * r, r4 = r2 * r2;
    float r5 = r4 * r, r6 = r4 * r2, r7 = r6 * r;
    float f = hf ? r4 * r5 : r;
    po[0] = f; po[1] = f * r; po[2] = f * r2; po[3] = f * r3;
    po[4] = f * r4; po[5] = f * r5; po[6] = f * r6; po[7] = f * r7;
  } else {
#pragma unroll
    for (int k = 0; k < 8; ++k)
      po[k] = __expf(-__expf(A_log[e * NS + hf * 8 + k]) * T);
  }
  *(float4*)&pp[0] = make_float4(po[0], po[1], po[2], po[3]);
  *(float4*)&pp[4] = make_float4(po[4], po[5], po[6], po[7]);
  *(float4*)&ep[0] = make_float4(h[0], h[1], h[2], h[3]);
  *(float4*)&ep[4] = make_float4(h[4], h[5], h[6], h[7]);
}

// inter-chunk sequential combine (Hin aliases PA: loads precede stores)
__global__ __launch_bounds__(256) void k_scanB(const float* PA,
    const float* EA, float* Hin) {
  int idx = blockIdx.x * blockDim.x + threadIdx.x;
  if (idx >= GG * DI * NS) return;
  int g = idx / (DI * NS); int es = idx - g * (DI * NS);
  size_t stride = (size_t)DI * NS;
  size_t b0 = (size_t)g * NC * stride + es;
  float h = 0.f;
  for (int c0 = 0; c0 < NC; c0 += 8) {
    float p8[8], e8[8];
#pragma unroll
    for (int j = 0; j < 8; ++j) {
      size_t ix = b0 + (size_t)(c0 + j) * stride;
      p8[j] = PA[ix]; e8[j] = EA[ix];
    }
#pragma unroll
    for (int j = 0; j < 8; ++j) {
      size_t ix = b0 + (size_t)(c0 + j) * stride;
      Hin[ix] = h;
      h = fmaf(p8[j], h, e8[j]);
    }
  }
}

__global__ __launch_bounds__(192) void k_scanC(const float* __restrict__ xc,
    const float* __restrict__ xdbl, const float* __restrict__ Wdt,
    const float* __restrict__ bdt, const float* __restrict__ A_log,
    const float* __restrict__ Hin, const float* __restrict__ Dp,
    float* __restrict__ yg) {
  __shared__ float sBC[LC][40];
  int c = blockIdx.x, g = blockIdx.y;
  int tid = threadIdx.x;
  int e = blockIdx.z * 96 + (tid >> 1);
  int hf = tid & 1;
  const float* hp = Hin + (((size_t)g * NC + c) * DI + e) * NS + hf * 8;
  float4 h0 = *(const float4*)(hp + 0);
  float4 h1v = *(const float4*)(hp + 4);
  stage_bc(sBC, xdbl, g, c, tid);
  float wdt[RK];
#pragma unroll
  for (int r = 0; r < RK; ++r) wdt[r] = Wdt[e * RK + r];
  float bde = bdt[e];
  float dpe = Dp[e];
  float base = -__expf(A_log[e * NS]);
  bool fast = true;
#pragma unroll
  for (int s = 1; s < NS; ++s) {
    float aes = -__expf(A_log[e * NS + s]);
    fast = fast && (fabsf(aes / base - (float)(s + 1)) < 1e-3f);
  }
  float h[8] = {h0.x, h0.y, h0.z, h0.w, h1v.x, h1v.y, h1v.z, h1v.w};
  const float* xptr = xc + ((size_t)g * S + c * LC) * DI + e;
  int b = g / 3, dir = g - (g / 3) * 3;
  float* yo = yg + ((size_t)b * S + c * LC) * 576 + dir * DI + e;
  __syncthreads();
  if (fast) {
    for (int l0 = 0; l0 < LC; l0 += 8) {
      float xb[8];
#pragma unroll
      for (int j = 0; j < 8; ++j) xb[j] = xptr[(size_t)(l0 + j) * DI];
#pragma unroll
      for (int j = 0; j < 8; ++j) {
        int l = l0 + j;
        DT_COMMON(l)
        float xv = xb[j];
        float w = d * xv;
        float r = __expf(d * base);
        float r2 = r * r, r3 = r2 * r, r4 = r2 * r2;
        float r5 = r4 * r, r6 = r4 * r2, r7 = r6 * r;
        float f = hf ? r4 * r5 : r;       // r^(8*hf+1)
        float4 Ba = *(const float4*)&sBC[l][8 + hf * 8];
        float4 Bb = *(const float4*)&sBC[l][12 + hf * 8];
        float4 Ca = *(const float4*)&sBC[l][24 + hf * 8];
        float4 Cb = *(const float4*)&sBC[l][28 + hf * 8];
        float y0 = hf ? 0.f : xv * dpe;
        float y1 = 0.f;
        h[0] = fmaf(f,      h[0], w * Ba.x); y0 = fmaf(h[0], Ca.x, y0);
        h[1] = fmaf(f * r,  h[1], w * Ba.y); y1 = fmaf(h[1], Ca.y, y1);
        h[2] = fmaf(f * r2, h[2], w * Ba.z); y0 = fmaf(h[2], Ca.z, y0);
        h[3] = fmaf(f * r3, h[3], w * Ba.w); y1 = fmaf(h[3], Ca.w, y1);
        h[4] = fmaf(f * r4, h[4], w * Bb.x); y0 = fmaf(h[4], Cb.x, y0);
        h[5] = fmaf(f * r5, h[5], w * Bb.y); y1 = fmaf(h[5], Cb.y, y1);
        h[6] = fmaf(f * r6, h[6], w * Bb.z); y0 = fmaf(h[6], Cb.z, y0);
        h[7] = fmaf(f * r7, h[7], w * Bb.w); y1 = fmaf(h[7], Cb.w, y1);
        float ysum = pair_sum(y0 + y1);
        if (!hf) yo[(size_t)l * 576] = ysum;
      }
    }
  } else {
    float Aes[8];
#pragma unroll
    for (int k = 0; k < 8; ++k) Aes[k] = -__expf(A_log[e * NS + hf * 8 + k]);
#pragma unroll 1
    for (int l = 0; l < LC; ++l) {
      DT_COMMON(l)
      float xv = xptr[(size_t)l * DI];
      float w = d * xv;
      float y = hf ? 0.f : xv * dpe;
#pragma unroll
      for (int k = 0; k < 8; ++k) {
        float q = __expf(d * Aes[k]);
        h[k] = fmaf(q, h[k], w * sBC[l][8 + hf * 8 + k]);
        y = fmaf(h[k], sBC[l][24 + hf * 8 + k], y);
      }
      float ysum = pair_sum(y);
      if (!hf) yo[(size_t)l * 576] = ysum;
    }
  }
}

// ---------------- fold Wout into proj_w: Mcat[o, dir*192+e] --------------
__global__ __launch_bounds__(256) void k_foldW(const float* __restrict__ proj_w,
    const float* __restrict__ Wout, float* __restrict__ Mcat) {
  int t = blockIdx.x * blockDim.x + threadIdx.x;
  if (t >= CC * 576) return;
  int o = t / 576; int j = t - o * 576; int dir = j / DI; int e = j - dir * DI;
  float a = 0.f;
  for (int c2 = 0; c2 < CC; ++c2)
    a = fmaf(proj_w[o * 288 + dir * CC + c2], Wout[c2 * DI + e], a);
  Mcat[t] = a;
}

extern "C" void kernel_launch(void* const* d_in, const int* in_sizes, int n_in,
                              void* d_out, int out_size, void* d_ws, size_t ws_size,
                              hipStream_t stream) {
  const float* x      = (const float*)d_in[0];
  const float* ln_w   = (const float*)d_in[1];
  const float* ln_b   = (const float*)d_in[2];
  const float* mln_w  = (const float*)d_in[3];
  const float* mln_b  = (const float*)d_in[4];
  const float* Win    = (const float*)d_in[5];
  const float* conv_w = (const float*)d_in[6];
  const float* conv_b = (const float*)d_in[7];
  const float* Wx     = (const float*)d_in[8];
  const float* Wdt    = (const float*)d_in[9];
  const float* bdt    = (const float*)d_in[10];
  const float* A_log  = (const float*)d_in[11];
  const float* Dp     = (const float*)d_in[12];
  const float* Wout   = (const float*)d_in[13];
  const float* proj_w = (const float*)d_in[14];
  const float* proj_b = (const float*)d_in[15];
  const float* fc1_w  = (const float*)d_in[16];
  const float* fc1_b  = (const float*)d_in[17];
  const float* fc2_w  = (const float*)d_in[18];
  const float* fc2_b  = (const float*)d_in[19];

  float* ws = (float*)d_ws;
  size_t off = 0;
  float* xn   = ws + off; off += (size_t)BB * S * CC;       // 1.536M
  float* XZ   = ws + off; off += (size_t)BB * S * 384;      // 6.144M
  float* xc   = ws + off; off += (size_t)GG * S * DI;       // 9.216M
  float* xdbl = ws + off; off += (size_t)GG * S * ND;       // 1.824M
  float* PA   = ws + off; off += (size_t)GG * NC * DI * NS; // 3.686M
  float* EA   = ws + off; off += (size_t)GG * NC * DI * NS; // 3.686M
  float* yg   = ws + off; off += (size_t)BB * S * 576;      // 9.216M
  float* Mcat = ws + off; off += (size_t)CC * 576;
  if (ws_size < off * sizeof(float)) return;                // ~142 MB; guard
  float* Hin  = PA;     // in-place in scanB (group loads precede stores)
  float* ores = xn;     // xn dead after Win GEMM
  float* xln2 = xc;     // xc dead after scanC
  float* h1   = XZ;     // XZ dead after proj (gate fused there)

  k_ln2<<<(BB * S + 255) / 256, 256, 0, stream>>>(x, ln_w, ln_b, mln_w, mln_b, xn);
  k_gemm3<256, 64, 128, 8, 4, 0, false, false, false, false>
      <<<dim3(BB * S / 64, 3), 256, 0, stream>>>(
      xn, Win, nullptr, nullptr, nullptr, XZ, BB * S, 384, CC);
  k_conv<<<(GG * S * DI + 255) / 256, 256, 0, stream>>>(XZ, conv_w, conv_b, xc);
  k_gemm<0, false, false, false><<<dim3(GG * S / 64, 1), 256, 0, stream>>>(
      xc, Wx, nullptr, nullptr, xdbl, GG * S, ND, DI);
  k_scanA<<<dim3(NC, GG, 2), 192, 0, stream>>>(xc, xdbl, Wdt, bdt, A_log, PA, EA);
  k_scanB<<<(GG * DI * NS + 255) / 256, 256, 0, stream>>>(PA, EA, Hin);
  k_scanC<<<dim3(NC, GG, 2), 192, 0, stream>>>(xc, xdbl, Wdt, bdt, A_log, Hin, Dp, yg);
  k_foldW<<<(CC * 576 + 255) / 256, 256, 0, stream>>>(proj_w, Wout, Mcat);
  k_gemm3<192, 32, 96, 4, 4, 0, true, true, true, true>
      <<<dim3(BB * S / 32, 1), 192, 0, stream>>>(
      yg, Mcat, proj_b, x, XZ, ores, BB * S, CC, 576);
  k_ln1<<<(BB * S + 255) / 256, 256, 0, stream>>>(ores, ln_w, ln_b, xln2);
  k_gemm3<256, 64, 128, 8, 4, 1, true, false, false, false>
      <<<dim3(BB * S / 64, 3), 256, 0, stream>>>(
      xln2, fc1_w, fc1_b, nullptr, nullptr, h1, BB * S, 384, CC);
  k_gemm3<192, 32, 96, 4, 4, 0, true, true, true, false>
      <<<dim3(BB * S / 32, 1), 192, 0, stream>>>(
      h1, fc2_w, fc2_b, ores, nullptr, (float*)d_out, BB * S, CC, 384);
}

// Round 10
// 312.849 us; speedup vs baseline: 1.5804x; 1.2180x over previous
//
#include <hip/hip_runtime.h>
#include <math.h>

// Problem constants (fixed by reference)
#define S   8000     // L = 20*20*20
#define BB  2
#define CC  96
#define DI  192      // d_inner
#define NS  16       // d_state
#define RK  6        // dt_rank
#define GG  6        // B * 3 directions
#define NC  200      // scan chunks
#define LC  40       // chunk length
#define ND  38       // dt_rank + 2*d_state

typedef __attribute__((ext_vector_type(8))) short bf16x8;
typedef __attribute__((ext_vector_type(4))) float f32x4;

// l -> pos mapping per direction.
__device__ __forceinline__ int pos_from_l(int dir, int l) {
  if (dir == 0) return l;
  int a  = l / 400;
  int r  = l - a * 400;
  int bq = r / 20;
  int cq = r - bq * 20;
  if (dir == 1) return cq * 400 + a * 20 + bq;   // (h=a, w=bq, d=cq)
  return bq * 400 + cq * 20 + a;                 // (w=a, d=bq, h=cq)
}

__device__ __forceinline__ float silu(float z) {
  return z / (1.f + __expf(-z));
}

// f32 -> bf16 with round-to-nearest-even
__device__ __forceinline__ unsigned short f2bf(float x) {
  unsigned int u = __float_as_uint(x);
  u += 0x7FFFu + ((u >> 16) & 1u);
  return (unsigned short)(u >> 16);
}

// sum across lane pairs (xor 1) via DPP quad_perm [1,0,3,2]
__device__ __forceinline__ float pair_sum(float y) {
  return y + __int_as_float(__builtin_amdgcn_update_dpp(
      0, __float_as_int(y), 0xB1, 0xF, 0xF, true));
}

// ---------------- K0: double LayerNorm over channels (per position) -------
__global__ __launch_bounds__(256) void k_ln2(const float* __restrict__ x,
    const float* __restrict__ lnw, const float* __restrict__ lnb,
    const float* __restrict__ mlnw, const float* __restrict__ mlnb,
    float* __restrict__ xn) {
  int t = blockIdx.x * blockDim.x + threadIdx.x;
  if (t >= BB * S) return;
  int b = t / S, pos = t - b * S;
  const float* xp = x + (size_t)b * CC * S + pos;
  float s1 = 0.f, s2 = 0.f;
  for (int c = 0; c < CC; ++c) { float v = xp[(size_t)c * S]; s1 += v; s2 += v * v; }
  float u = s1 * (1.f / CC);
  float var = s2 * (1.f / CC) - u * u;
  float rstd = rsqrtf(var + 1e-6f);
  float t1 = 0.f, t2 = 0.f;
  for (int c = 0; c < CC; ++c) {
    float y1 = fmaf(lnw[c], (xp[(size_t)c * S] - u) * rstd, lnb[c]);
    t1 += y1; t2 += y1 * y1;
  }
  float u2 = t1 * (1.f / CC);
  float var2 = t2 * (1.f / CC) - u2 * u2;
  float rstd2 = rsqrtf(var2 + 1e-5f);
  float* o = xn + (size_t)t * CC;
  for (int c = 0; c < CC; ++c) {
    float y1 = fmaf(lnw[c], (xp[(size_t)c * S] - u) * rstd, lnb[c]);
    o[c] = fmaf(mlnw[c], (y1 - u2) * rstd2, mlnb[c]);
  }
}

// ---------------- single LayerNorm (B,C,S) -> (B*S,C) --------------------
__global__ __launch_bounds__(256) void k_ln1(const float* __restrict__ xi,
    const float* __restrict__ lnw, const float* __restrict__ lnb,
    float* __restrict__ out) {
  int t = blockIdx.x * blockDim.x + threadIdx.x;
  if (t >= BB * S) return;
  int b = t / S, pos = t - b * S;
  const float* xp = xi + (size_t)b * CC * S + pos;
  float s1 = 0.f, s2 = 0.f;
  for (int c = 0; c < CC; ++c) { float v = xp[(size_t)c * S]; s1 += v; s2 += v * v; }
  float u = s1 * (1.f / CC);
  float var = s2 * (1.f / CC) - u * u;
  float rstd = rsqrtf(var + 1e-6f);
  float* o = out + (size_t)t * CC;
  for (int c = 0; c < CC; ++c)
    o[c] = fmaf(lnw[c], (xp[(size_t)c * S] - u) * rstd, lnb[c]);
}

// -------- old 64x64 fp32 GEMM (kept for Wx: N=38, K=192) -----------------
template <int ACT, bool BIAS, bool RESID, bool OUT_BCS>
__global__ __launch_bounds__(256) void k_gemm(const float* __restrict__ A,
    const float* __restrict__ Bw, const float* __restrict__ bias,
    const float* __restrict__ resid, float* __restrict__ Cmat,
    int M, int N, int K) {
  __shared__ float As[16][68];
  __shared__ float Bs[16][68];
  int tid = threadIdx.x;
  int tx = tid & 15, ty = tid >> 4;
  int m0 = blockIdx.x * 64, n0 = blockIdx.y * 64;
  float acc[4][4] = {};
  for (int kk = 0; kk < K; kk += 16) {
#pragma unroll
    for (int i = 0; i < 4; ++i) {
      int idx = tid + i * 256;
      int am = idx >> 4, ak = idx & 15;
      As[ak][am] = A[(size_t)(m0 + am) * K + kk + ak];
    }
#pragma unroll
    for (int i = 0; i < 4; ++i) {
      int idx = tid + i * 256;
      int bn = idx >> 4, bk = idx & 15;
      Bs[bk][bn] = (n0 + bn < N) ? Bw[(size_t)(n0 + bn) * K + kk + bk] : 0.f;
    }
    __syncthreads();
#pragma unroll
    for (int k = 0; k < 16; ++k) {
      float4 av = *(const float4*)&As[k][ty * 4];
      float4 bv = *(const float4*)&Bs[k][tx * 4];
      acc[0][0] = fmaf(av.x, bv.x, acc[0][0]);
      acc[0][1] = fmaf(av.x, bv.y, acc[0][1]);
      acc[0][2] = fmaf(av.x, bv.z, acc[0][2]);
      acc[0][3] = fmaf(av.x, bv.w, acc[0][3]);
      acc[1][0] = fmaf(av.y, bv.x, acc[1][0]);
      acc[1][1] = fmaf(av.y, bv.y, acc[1][1]);
      acc[1][2] = fmaf(av.y, bv.z, acc[1][2]);
      acc[1][3] = fmaf(av.y, bv.w, acc[1][3]);
      acc[2][0] = fmaf(av.z, bv.x, acc[2][0]);
      acc[2][1] = fmaf(av.z, bv.y, acc[2][1]);
      acc[2][2] = fmaf(av.z, bv.z, acc[2][2]);
      acc[2][3] = fmaf(av.z, bv.w, acc[2][3]);
      acc[3][0] = fmaf(av.w, bv.x, acc[3][0]);
      acc[3][1] = fmaf(av.w, bv.y, acc[3][1]);
      acc[3][2] = fmaf(av.w, bv.z, acc[3][2]);
      acc[3][3] = fmaf(av.w, bv.w, acc[3][3]);
    }
    __syncthreads();
  }
#pragma unroll
  for (int i = 0; i < 4; ++i) {
    int m = m0 + ty * 4 + i;
#pragma unroll
    for (int j = 0; j < 4; ++j) {
      int n = n0 + tx * 4 + j;
      if (n < N) {
        float v = acc[i][j];
        if (BIAS) v += bias[n];
        if (ACT == 1) v = 0.5f * v * (1.f + erff(v * 0.70710678118654752f));
        if (RESID || OUT_BCS) {
          int bb = m / S, pp = m - bb * S;
          size_t oidx = ((size_t)bb * CC + n) * S + pp;
          if (RESID) v += resid[oidx];
          if (OUT_BCS) { Cmat[oidx] = v; continue; }
        }
        Cmat[(size_t)m * N + n] = v;
      }
    }
  }
}

// -------- bf16 MFMA GEMM: C[M,N] = act(A[M,K] @ Bw[N,K]^T + bias) --------
// BM=64, BN=96, BK=32; 4 waves (2x2), each wave 32x48 = 6 mfma 16x16x32.
// A,B converted f32->bf16 (RNE) during LDS staging.
// Fragment mapping (m89/m97-verified): A row=l&15,k=(l>>4)*8+j; B col=l&15;
// D col=l&15, row=(l>>4)*4+v.
#define BKP 40   // 32 + 8 pad (ushorts)
template <int ACT, bool BIAS, bool RESID, bool OUT_BCS, bool GATEA>
__global__ __launch_bounds__(256) void k_mfma(const float* __restrict__ A,
    const float* __restrict__ Bw, const float* __restrict__ bias,
    const float* __restrict__ resid, const float* __restrict__ XZg,
    float* __restrict__ Cmat, int M, int N, int K) {
  __shared__ unsigned short Al[64][BKP];
  __shared__ unsigned short Bl[96][BKP];
  int tid = threadIdx.x;
  int m0 = blockIdx.x * 64, n0 = blockIdx.y * 96;
  int wid = tid >> 6, lane = tid & 63;
  int wr = wid >> 1, wc = wid & 1;          // wave -> (rowhalf, colhalf)
  int l16 = lane & 15, lk = (lane >> 4) * 8;
  f32x4 acc[2][3];
#pragma unroll
  for (int i = 0; i < 2; ++i)
#pragma unroll
    for (int j = 0; j < 3; ++j) acc[i][j] = (f32x4){0.f, 0.f, 0.f, 0.f};

  for (int kk = 0; kk < K; kk += 32) {
    // stage A: 64 rows x 8 float4  (512 f4 / 256 thr = 2 each)
#pragma unroll
    for (int i = 0; i < 2; ++i) {
      int idx = tid + i * 256;
      int row = idx >> 3, kq = idx & 7;
      int m = m0 + row;
      float4 v = *(const float4*)&A[(size_t)m * K + kk + kq * 4];
      if (GATEA) {
        int bb = m / S, ll = m - bb * S;
        int j = kk + kq * 4;
        int dir = j / DI; int e0 = j - dir * DI;
        int p = pos_from_l(dir, ll);
        const float4 z4 = *(const float4*)&XZg[((size_t)bb * S + p) * 384 + DI + e0];
        v.x *= silu(z4.x); v.y *= silu(z4.y);
        v.z *= silu(z4.z); v.w *= silu(z4.w);
      }
      unsigned short* dst = &Al[row][kq * 4];
      dst[0] = f2bf(v.x); dst[1] = f2bf(v.y);
      dst[2] = f2bf(v.z); dst[3] = f2bf(v.w);
    }
    // stage B: 96 rows x 8 float4 (768 f4 / 256 thr = 3 each)
#pragma unroll
    for (int i = 0; i < 3; ++i) {
      int idx = tid + i * 256;
      int bn = idx >> 3, kq = idx & 7;
      float4 v = *(const float4*)&Bw[(size_t)(n0 + bn) * K + kk + kq * 4];
      unsigned short* dst = &Bl[bn][kq * 4];
      dst[0] = f2bf(v.x); dst[1] = f2bf(v.y);
      dst[2] = f2bf(v.z); dst[3] = f2bf(v.w);
    }
    __syncthreads();
    bf16x8 af[2], bfr[3];
#pragma unroll
    for (int i = 0; i < 2; ++i)
      af[i] = *(const bf16x8*)&Al[wr * 32 + i * 16 + l16][lk];
#pragma unroll
    for (int j = 0; j < 3; ++j)
      bfr[j] = *(const bf16x8*)&Bl[wc * 48 + j * 16 + l16][lk];
#pragma unroll
    for (int i = 0; i < 2; ++i)
#pragma unroll
      for (int j = 0; j < 3; ++j)
        acc[i][j] = __builtin_amdgcn_mfma_f32_16x16x32_bf16(
            af[i], bfr[j], acc[i][j], 0, 0, 0);
    __syncthreads();
  }
  // epilogue: D col=l&15, row=(l>>4)*4+v
#pragma unroll
  for (int i = 0; i < 2; ++i) {
#pragma unroll
    for (int j = 0; j < 3; ++j) {
#pragma unroll
      for (int v = 0; v < 4; ++v) {
        int m = m0 + wr * 32 + i * 16 + (lane >> 4) * 4 + v;
        int n = n0 + wc * 48 + j * 16 + l16;
        if (n < N) {
          float val = acc[i][j][v];
          if (BIAS) val += bias[n];
          if (ACT == 1) val = 0.5f * val * (1.f + erff(val * 0.70710678118654752f));
          if (RESID || OUT_BCS) {
            int bb = m / S, pp = m - bb * S;
            size_t oidx = ((size_t)bb * CC + n) * S + pp;
            if (RESID) val += resid[oidx];
            if (OUT_BCS) { Cmat[oidx] = val; continue; }
          }
          Cmat[(size_t)m * N + n] = val;
        }
      }
    }
  }
}

// ---------------- causal depthwise conv(4) + SiLU, gathered input --------
__global__ __launch_bounds__(256) void k_conv(const float* __restrict__ XZ,
    const float* __restrict__ cw, const float* __restrict__ cb,
    float* __restrict__ xc) {
  int t = blockIdx.x * blockDim.x + threadIdx.x;
  if (t >= GG * S * DI) return;
  int e = t % DI; int gl = t / DI; int l = gl % S; int g = gl / S;
  int b = g / 3, dir = g - (g / 3) * 3;
  float acc = cb[e];
#pragma unroll
  for (int k = 0; k < 4; ++k) {
    int ls = l + k - 3;
    if (ls >= 0) {
      int p = pos_from_l(dir, ls);
      acc = fmaf(cw[e * 4 + k], XZ[((size_t)b * S + p) * 384 + e], acc);
    }
  }
  xc[(size_t)gl * DI + e] = acc * (1.f / (1.f + __expf(-acc)));
}

// ======== scan kernels: pair-split — 2 lanes per (g,e), 8 states each ====
// LDS tile: sBC[l][j]: j 0..5 = dt_r, j 8..23 = B, j 24..39 = C
__device__ __forceinline__ void stage_bc(float (*sBC)[40],
    const float* __restrict__ xdbl, int g, int c, int tid) {
  const float* src = xdbl + ((size_t)g * S + c * LC) * ND;
  for (int i = tid; i < LC * ND; i += 192) {
    int row = i / ND, col = i - row * ND;
    int dst = (col < RK) ? col : col + 2;
    sBC[row][dst] = src[(size_t)row * ND + col];
  }
}

// common per-step prologue: dt via fast softplus
#define DT_COMMON(l)                                                     \
  float a = bde;                                                         \
  {                                                                      \
    float4 r0 = *(const float4*)&sBC[l][0];                              \
    float2 r1 = *(const float2*)&sBC[l][4];                              \
    a = fmaf(wdt[0], r0.x, a); a = fmaf(wdt[1], r0.y, a);                \
    a = fmaf(wdt[2], r0.z, a); a = fmaf(wdt[3], r0.w, a);                \
    a = fmaf(wdt[4], r1.x, a); a = fmaf(wdt[5], r1.y, a);                \
  }                                                                      \
  float d = fmaxf(a, 0.f) + __logf(1.f + __expf(-fabsf(a)));

__global__ __launch_bounds__(192) void k_scanA(const float* __restrict__ xc,
    const float* __restrict__ xdbl, const float* __restrict__ Wdt,
    const float* __restrict__ bdt, const float* __restrict__ A_log,
    float* __restrict__ PA, float* __restrict__ EA) {
  __shared__ float sBC[LC][40];
  int c = blockIdx.x, g = blockIdx.y;
  int tid = threadIdx.x;
  int e = blockIdx.z * 96 + (tid >> 1);
  int hf = tid & 1;
  stage_bc(sBC, xdbl, g, c, tid);
  float wdt[RK];
#pragma unroll
  for (int r = 0; r < RK; ++r) wdt[r] = Wdt[e * RK + r];
  float bde = bdt[e];
  float base = -__expf(A_log[e * NS]);
  bool fast = true;
#pragma unroll
  for (int s = 1; s < NS; ++s) {
    float aes = -__expf(A_log[e * NS + s]);
    fast = fast && (fabsf(aes / base - (float)(s + 1)) < 1e-3f);
  }
  float h[8];
#pragma unroll
  for (int k = 0; k < 8; ++k) h[k] = 0.f;
  float T = 0.f;
  const float* xptr = xc + ((size_t)g * S + c * LC) * DI + e;
  __syncthreads();
  if (fast) {
    for (int l0 = 0; l0 < LC; l0 += 8) {
      float xb[8];
#pragma unroll
      for (int j = 0; j < 8; ++j) xb[j] = xptr[(size_t)(l0 + j) * DI];
#pragma unroll
      for (int j = 0; j < 8; ++j) {
        int l = l0 + j;
        DT_COMMON(l)
        T += d;
        float w = d * xb[j];
        float r = __expf(d * base);
        float r2 = r * r, r3 = r2 * r, r4 = r2 * r2;
        float r5 = r4 * r, r6 = r4 * r2, r7 = r6 * r;
        float f = hf ? r4 * r5 : r;       // r^(8*hf+1)
        float4 Ba = *(const float4*)&sBC[l][8 + hf * 8];
        float4 Bb = *(const float4*)&sBC[l][12 + hf * 8];
        h[0] = fmaf(f,      h[0], w * Ba.x);
        h[1] = fmaf(f * r,  h[1], w * Ba.y);
        h[2] = fmaf(f * r2, h[2], w * Ba.z);
        h[3] = fmaf(f * r3, h[3], w * Ba.w);
        h[4] = fmaf(f * r4, h[4], w * Bb.x);
        h[5] = fmaf(f * r5, h[5], w * Bb.y);
        h[6] = fmaf(f * r6, h[6], w * Bb.z);
        h[7] = fmaf(f * r7, h[7], w * Bb.w);
      }
    }
  } else {
    float Aes[8];
#pragma unroll
    for (int k = 0; k < 8; ++k) Aes[k] = -__expf(A_log[e * NS + hf * 8 + k]);
#pragma unroll 1
    for (int l = 0; l < LC; ++l) {
      DT_COMMON(l)
      T += d;
      float w = d * xptr[(size_t)l * DI];
#pragma unroll
      for (int k = 0; k < 8; ++k) {
        float q = __expf(d * Aes[k]);
        h[k] = fmaf(q, h[k], w * sBC[l][8 + hf * 8 + k]);
      }
    }
  }
  float* pp = PA + (((size_t)g * NC + c) * DI + e) * NS + hf * 8;
  float* ep = EA + (((size_t)g * NC + c) * DI + e) * NS + hf * 8;
  float po[8];
  if (fast) {
    float r = __expf(base * T);
    float r2 = r * r, r3 = r2 * r, r4 = r2 * r2;
    float r5 = r4 * r, r6 = r4 * r2, r7 = r6 * r;
    float f = hf ? r4 * r5 : r;
    po[0] = f; po[1] = f * r; po[2] = f * r2; po[3] = f * r3;
    po[4] = f * r4; po[5] = f * r5; po[6] = f * r6; po[7] = f * r7;
  } else {
#pragma unroll
    for (int k = 0; k < 8; ++k)
      po[k] = __expf(-__expf(A_log[e * NS + hf * 8 + k]) * T);
  }
  *(float4*)&pp[0] = make_float4(po[0], po[1], po[2], po[3]);
  *(float4*)&pp[4] = make_float4(po[4], po[5], po[6], po[7]);
  *(float4*)&ep[0] = make_float4(h[0], h[1], h[2], h[3]);
  *(float4*)&ep[4] = make_float4(h[4], h[5], h[6], h[7]);
}

// inter-chunk sequential combine (Hin aliases PA: loads precede stores)
__global__ __launch_bounds__(256) void k_scanB(const float* PA,
    const float* EA, float* Hin) {
  int idx = blockIdx.x * blockDim.x + threadIdx.x;
  if (idx >= GG * DI * NS) return;
  int g = idx / (DI * NS); int es = idx - g * (DI * NS);
  size_t stride = (size_t)DI * NS;
  size_t b0 = (size_t)g * NC * stride + es;
  float h = 0.f;
  for (int c0 = 0; c0 < NC; c0 += 8) {
    float p8[8], e8[8];
#pragma unroll
    for (int j = 0; j < 8; ++j) {
      size_t ix = b0 + (size_t)(c0 + j) * stride;
      p8[j] = PA[ix]; e8[j] = EA[ix];
    }
#pragma unroll
    for (int j = 0; j < 8; ++j) {
      size_t ix = b0 + (size_t)(c0 + j) * stride;
      Hin[ix] = h;
      h = fmaf(p8[j], h, e8[j]);
    }
  }
}

__global__ __launch_bounds__(192) void k_scanC(const float* __restrict__ xc,
    const float* __restrict__ xdbl, const float* __restrict__ Wdt,
    const float* __restrict__ bdt, const float* __restrict__ A_log,
    const float* __restrict__ Hin, const float* __restrict__ Dp,
    float* __restrict__ yg) {
  __shared__ float sBC[LC][40];
  int c = blockIdx.x, g = blockIdx.y;
  int tid = threadIdx.x;
  int e = blockIdx.z * 96 + (tid >> 1);
  int hf = tid & 1;
  const float* hp = Hin + (((size_t)g * NC + c) * DI + e) * NS + hf * 8;
  float4 h0 = *(const float4*)(hp + 0);
  float4 h1v = *(const float4*)(hp + 4);
  stage_bc(sBC, xdbl, g, c, tid);
  float wdt[RK];
#pragma unroll
  for (int r = 0; r < RK; ++r) wdt[r] = Wdt[e * RK + r];
  float bde = bdt[e];
  float dpe = Dp[e];
  float base = -__expf(A_log[e * NS]);
  bool fast = true;
#pragma unroll
  for (int s = 1; s < NS; ++s) {
    float aes = -__expf(A_log[e * NS + s]);
    fast = fast && (fabsf(aes / base - (float)(s + 1)) < 1e-3f);
  }
  float h[8] = {h0.x, h0.y, h0.z, h0.w, h1v.x, h1v.y, h1v.z, h1v.w};
  const float* xptr = xc + ((size_t)g * S + c * LC) * DI + e;
  int b = g / 3, dir = g - (g / 3) * 3;
  float* yo = yg + ((size_t)b * S + c * LC) * 576 + dir * DI + e;
  __syncthreads();
  if (fast) {
    for (int l0 = 0; l0 < LC; l0 += 8) {
      float xb[8];
#pragma unroll
      for (int j = 0; j < 8; ++j) xb[j] = xptr[(size_t)(l0 + j) * DI];
#pragma unroll
      for (int j = 0; j < 8; ++j) {
        int l = l0 + j;
        DT_COMMON(l)
        float xv = xb[j];
        float w = d * xv;
        float r = __expf(d * base);
        float r2 = r * r, r3 = r2 * r, r4 = r2 * r2;
        float r5 = r4 * r, r6 = r4 * r2, r7 = r6 * r;
        float f = hf ? r4 * r5 : r;       // r^(8*hf+1)
        float4 Ba = *(const float4*)&sBC[l][8 + hf * 8];
        float4 Bb = *(const float4*)&sBC[l][12 + hf * 8];
        float4 Ca = *(const float4*)&sBC[l][24 + hf * 8];
        float4 Cb = *(const float4*)&sBC[l][28 + hf * 8];
        float y0 = hf ? 0.f : xv * dpe;
        float y1 = 0.f;
        h[0] = fmaf(f,      h[0], w * Ba.x); y0 = fmaf(h[0], Ca.x, y0);
        h[1] = fmaf(f * r,  h[1], w * Ba.y); y1 = fmaf(h[1], Ca.y, y1);
        h[2] = fmaf(f * r2, h[2], w * Ba.z); y0 = fmaf(h[2], Ca.z, y0);
        h[3] = fmaf(f * r3, h[3], w * Ba.w); y1 = fmaf(h[3], Ca.w, y1);
        h[4] = fmaf(f * r4, h[4], w * Bb.x); y0 = fmaf(h[4], Cb.x, y0);
        h[5] = fmaf(f * r5, h[5], w * Bb.y); y1 = fmaf(h[5], Cb.y, y1);
        h[6] = fmaf(f * r6, h[6], w * Bb.z); y0 = fmaf(h[6], Cb.z, y0);
        h[7] = fmaf(f * r7, h[7], w * Bb.w); y1 = fmaf(h[7], Cb.w, y1);
        float ysum = pair_sum(y0 + y1);
        if (!hf) yo[(size_t)l * 576] = ysum;
      }
    }
  } else {
    float Aes[8];
#pragma unroll
    for (int k = 0; k < 8; ++k) Aes[k] = -__expf(A_log[e * NS + hf * 8 + k]);
#pragma unroll 1
    for (int l = 0; l < LC; ++l) {
      DT_COMMON(l)
      float xv = xptr[(size_t)l * DI];
      float w = d * xv;
      float y = hf ? 0.f : xv * dpe;
#pragma unroll
      for (int k = 0; k < 8; ++k) {
        float q = __expf(d * Aes[k]);
        h[k] = fmaf(q, h[k], w * sBC[l][8 + hf * 8 + k]);
        y = fmaf(h[k], sBC[l][24 + hf * 8 + k], y);
      }
      float ysum = pair_sum(y);
      if (!hf) yo[(size_t)l * 576] = ysum;
    }
  }
}

// ---------------- fold Wout into proj_w: Mcat[o, dir*192+e] --------------
__global__ __launch_bounds__(256) void k_foldW(const float* __restrict__ proj_w,
    const float* __restrict__ Wout, float* __restrict__ Mcat) {
  int t = blockIdx.x * blockDim.x + threadIdx.x;
  if (t >= CC * 576) return;
  int o = t / 576; int j = t - o * 576; int dir = j / DI; int e = j - dir * DI;
  float a = 0.f;
  for (int c2 = 0; c2 < CC; ++c2)
    a = fmaf(proj_w[o * 288 + dir * CC + c2], Wout[c2 * DI + e], a);
  Mcat[t] = a;
}

extern "C" void kernel_launch(void* const* d_in, const int* in_sizes, int n_in,
                              void* d_out, int out_size, void* d_ws, size_t ws_size,
                              hipStream_t stream) {
  const float* x      = (const float*)d_in[0];
  const float* ln_w   = (const float*)d_in[1];
  const float* ln_b   = (const float*)d_in[2];
  const float* mln_w  = (const float*)d_in[3];
  const float* mln_b  = (const float*)d_in[4];
  const float* Win    = (const float*)d_in[5];
  const float* conv_w = (const float*)d_in[6];
  const float* conv_b = (const float*)d_in[7];
  const float* Wx     = (const float*)d_in[8];
  const float* Wdt    = (const float*)d_in[9];
  const float* bdt    = (const float*)d_in[10];
  const float* A_log  = (const float*)d_in[11];
  const float* Dp     = (const float*)d_in[12];
  const float* Wout   = (const float*)d_in[13];
  const float* proj_w = (const float*)d_in[14];
  const float* proj_b = (const float*)d_in[15];
  const float* fc1_w  = (const float*)d_in[16];
  const float* fc1_b  = (const float*)d_in[17];
  const float* fc2_w  = (const float*)d_in[18];
  const float* fc2_b  = (const float*)d_in[19];

  float* ws = (float*)d_ws;
  size_t off = 0;
  float* xn   = ws + off; off += (size_t)BB * S * CC;       // 1.536M
  float* XZ   = ws + off; off += (size_t)BB * S * 384;      // 6.144M
  float* xc   = ws + off; off += (size_t)GG * S * DI;       // 9.216M
  float* xdbl = ws + off; off += (size_t)GG * S * ND;       // 1.824M
  float* PA   = ws + off; off += (size_t)GG * NC * DI * NS; // 3.686M
  float* EA   = ws + off; off += (size_t)GG * NC * DI * NS; // 3.686M
  float* yg   = ws + off; off += (size_t)BB * S * 576;      // 9.216M
  float* Mcat = ws + off; off += (size_t)CC * 576;
  if (ws_size < off * sizeof(float)) return;                // ~142 MB; guard
  float* Hin  = PA;     // in-place in scanB (group loads precede stores)
  float* ores = xn;     // xn dead after Win GEMM
  float* xln2 = xc;     // xc dead after scanC
  float* h1   = XZ;     // XZ dead after proj (gate fused there)

  k_ln2<<<(BB * S + 255) / 256, 256, 0, stream>>>(x, ln_w, ln_b, mln_w, mln_b, xn);
  k_mfma<0, false, false, false, false>
      <<<dim3(BB * S / 64, 4), 256, 0, stream>>>(
      xn, Win, nullptr, nullptr, nullptr, XZ, BB * S, 384, CC);
  k_conv<<<(GG * S * DI + 255) / 256, 256, 0, stream>>>(XZ, conv_w, conv_b, xc);
  k_gemm<0, false, false, false><<<dim3(GG * S / 64, 1), 256, 0, stream>>>(
      xc, Wx, nullptr, nullptr, xdbl, GG * S, ND, DI);
  k_scanA<<<dim3(NC, GG, 2), 192, 0, stream>>>(xc, xdbl, Wdt, bdt, A_log, PA, EA);
  k_scanB<<<(GG * DI * NS + 255) / 256, 256, 0, stream>>>(PA, EA, Hin);
  k_scanC<<<dim3(NC, GG, 2), 192, 0, stream>>>(xc, xdbl, Wdt, bdt, A_log, Hin, Dp, yg);
  k_foldW<<<(CC * 576 + 255) / 256, 256, 0, stream>>>(proj_w, Wout, Mcat);
  k_mfma<0, true, true, true, true>
      <<<dim3(BB * S / 64, 1), 256, 0, stream>>>(
      yg, Mcat, proj_b, x, XZ, ores, BB * S, CC, 576);
  k_ln1<<<(BB * S + 255) / 256, 256, 0, stream>>>(ores, ln_w, ln_b, xln2);
  k_mfma<1, true, false, false, false>
      <<<dim3(BB * S / 64, 4), 256, 0, stream>>>(
      xln2, fc1_w, fc1_b, nullptr, nullptr, h1, BB * S, 384, CC);
  k_mfma<0, true, true, true, false>
      <<<dim3(BB * S / 64, 1), 256, 0, stream>>>(
      h1, fc2_w, fc2_b, ores, nullptr, (float*)d_out, BB * S, CC, 384);
}

// Round 11
// 283.055 us; speedup vs baseline: 1.7468x; 1.1053x over previous
//
#include <hip/hip_runtime.h>
#include <math.h>

// Problem constants (fixed by reference)
#define S   8000     // L = 20*20*20
#define BB  2
#define CC  96
#define DI  192      // d_inner
#define NS  16       // d_state
#define RK  6        // dt_rank
#define GG  6        // B * 3 directions
#define NC  200      // scan chunks
#define LC  40       // chunk length
#define ND  38       // dt_rank + 2*d_state

typedef __attribute__((ext_vector_type(8))) short bf16x8;
typedef __attribute__((ext_vector_type(4))) float f32x4;
typedef __attribute__((ext_vector_type(2))) float f32x2;

// l -> pos mapping per direction.
__device__ __forceinline__ int pos_from_l(int dir, int l) {
  if (dir == 0) return l;
  int a  = l / 400;
  int r  = l - a * 400;
  int bq = r / 20;
  int cq = r - bq * 20;
  if (dir == 1) return cq * 400 + a * 20 + bq;   // (h=a, w=bq, d=cq)
  return bq * 400 + cq * 20 + a;                 // (w=a, d=bq, h=cq)
}

__device__ __forceinline__ float silu(float z) {
  return z / (1.f + __expf(-z));
}

// f32 -> bf16 with round-to-nearest-even
__device__ __forceinline__ unsigned short f2bf(float x) {
  unsigned int u = __float_as_uint(x);
  u += 0x7FFFu + ((u >> 16) & 1u);
  return (unsigned short)(u >> 16);
}

// sum across lane pairs (xor 1) via DPP quad_perm [1,0,3,2]
__device__ __forceinline__ float pair_sum(float y) {
  return y + __int_as_float(__builtin_amdgcn_update_dpp(
      0, __float_as_int(y), 0xB1, 0xF, 0xF, true));
}

// ---------------- K0: double LayerNorm over channels (per position) -------
__global__ __launch_bounds__(256) void k_ln2(const float* __restrict__ x,
    const float* __restrict__ lnw, const float* __restrict__ lnb,
    const float* __restrict__ mlnw, const float* __restrict__ mlnb,
    float* __restrict__ xn) {
  int t = blockIdx.x * blockDim.x + threadIdx.x;
  if (t >= BB * S) return;
  int b = t / S, pos = t - b * S;
  const float* xp = x + (size_t)b * CC * S + pos;
  float s1 = 0.f, s2 = 0.f;
  for (int c = 0; c < CC; ++c) { float v = xp[(size_t)c * S]; s1 += v; s2 += v * v; }
  float u = s1 * (1.f / CC);
  float var = s2 * (1.f / CC) - u * u;
  float rstd = rsqrtf(var + 1e-6f);
  float t1 = 0.f, t2 = 0.f;
  for (int c = 0; c < CC; ++c) {
    float y1 = fmaf(lnw[c], (xp[(size_t)c * S] - u) * rstd, lnb[c]);
    t1 += y1; t2 += y1 * y1;
  }
  float u2 = t1 * (1.f / CC);
  float var2 = t2 * (1.f / CC) - u2 * u2;
  float rstd2 = rsqrtf(var2 + 1e-5f);
  float* o = xn + (size_t)t * CC;
  for (int c = 0; c < CC; ++c) {
    float y1 = fmaf(lnw[c], (xp[(size_t)c * S] - u) * rstd, lnb[c]);
    o[c] = fmaf(mlnw[c], (y1 - u2) * rstd2, mlnb[c]);
  }
}

// ---------------- single LayerNorm (B,C,S) -> (B*S,C) --------------------
__global__ __launch_bounds__(256) void k_ln1(const float* __restrict__ xi,
    const float* __restrict__ lnw, const float* __restrict__ lnb,
    float* __restrict__ out) {
  int t = blockIdx.x * blockDim.x + threadIdx.x;
  if (t >= BB * S) return;
  int b = t / S, pos = t - b * S;
  const float* xp = xi + (size_t)b * CC * S + pos;
  float s1 = 0.f, s2 = 0.f;
  for (int c = 0; c < CC; ++c) { float v = xp[(size_t)c * S]; s1 += v; s2 += v * v; }
  float u = s1 * (1.f / CC);
  float var = s2 * (1.f / CC) - u * u;
  float rstd = rsqrtf(var + 1e-6f);
  float* o = out + (size_t)t * CC;
  for (int c = 0; c < CC; ++c)
    o[c] = fmaf(lnw[c], (xp[(size_t)c * S] - u) * rstd, lnb[c]);
}

// -------- bf16 MFMA GEMM: C[M,N] = act(A[M,K] @ Bw[N,K]^T + bias) --------
// BM=64, BN=96, BK=32; 4 waves (2x2), each wave 32x48 = 6 mfma 16x16x32.
#define BKP 40   // 32 + 8 pad (ushorts)
template <int ACT, bool BIAS, bool RESID, bool OUT_BCS, bool GATEA>
__global__ __launch_bounds__(256) void k_mfma(const float* __restrict__ A,
    const float* __restrict__ Bw, const float* __restrict__ bias,
    const float* __restrict__ resid, const float* __restrict__ XZg,
    float* __restrict__ Cmat, int M, int N, int K) {
  __shared__ unsigned short Al[64][BKP];
  __shared__ unsigned short Bl[96][BKP];
  int tid = threadIdx.x;
  int m0 = blockIdx.x * 64, n0 = blockIdx.y * 96;
  int wid = tid >> 6, lane = tid & 63;
  int wr = wid >> 1, wc = wid & 1;
  int l16 = lane & 15, lk = (lane >> 4) * 8;
  f32x4 acc[2][3];
#pragma unroll
  for (int i = 0; i < 2; ++i)
#pragma unroll
    for (int j = 0; j < 3; ++j) acc[i][j] = (f32x4){0.f, 0.f, 0.f, 0.f};

  for (int kk = 0; kk < K; kk += 32) {
#pragma unroll
    for (int i = 0; i < 2; ++i) {
      int idx = tid + i * 256;
      int row = idx >> 3, kq = idx & 7;
      int m = m0 + row;
      float4 v = *(const float4*)&A[(size_t)m * K + kk + kq * 4];
      if (GATEA) {
        int bb = m / S, ll = m - bb * S;
        int j = kk + kq * 4;
        int dir = j / DI; int e0 = j - dir * DI;
        int p = pos_from_l(dir, ll);
        const float4 z4 = *(const float4*)&XZg[((size_t)bb * S + p) * 384 + DI + e0];
        v.x *= silu(z4.x); v.y *= silu(z4.y);
        v.z *= silu(z4.z); v.w *= silu(z4.w);
      }
      unsigned short* dst = &Al[row][kq * 4];
      dst[0] = f2bf(v.x); dst[1] = f2bf(v.y);
      dst[2] = f2bf(v.z); dst[3] = f2bf(v.w);
    }
#pragma unroll
    for (int i = 0; i < 3; ++i) {
      int idx = tid + i * 256;
      int bn = idx >> 3, kq = idx & 7;
      int n = n0 + bn;
      float4 v = make_float4(0.f, 0.f, 0.f, 0.f);
      if (n < N) v = *(const float4*)&Bw[(size_t)n * K + kk + kq * 4];
      unsigned short* dst = &Bl[bn][kq * 4];
      dst[0] = f2bf(v.x); dst[1] = f2bf(v.y);
      dst[2] = f2bf(v.z); dst[3] = f2bf(v.w);
    }
    __syncthreads();
    bf16x8 af[2], bfr[3];
#pragma unroll
    for (int i = 0; i < 2; ++i)
      af[i] = *(const bf16x8*)&Al[wr * 32 + i * 16 + l16][lk];
#pragma unroll
    for (int j = 0; j < 3; ++j)
      bfr[j] = *(const bf16x8*)&Bl[wc * 48 + j * 16 + l16][lk];
#pragma unroll
    for (int i = 0; i < 2; ++i)
#pragma unroll
      for (int j = 0; j < 3; ++j)
        acc[i][j] = __builtin_amdgcn_mfma_f32_16x16x32_bf16(
            af[i], bfr[j], acc[i][j], 0, 0, 0);
    __syncthreads();
  }
#pragma unroll
  for (int i = 0; i < 2; ++i) {
#pragma unroll
    for (int j = 0; j < 3; ++j) {
#pragma unroll
      for (int v = 0; v < 4; ++v) {
        int m = m0 + wr * 32 + i * 16 + (lane >> 4) * 4 + v;
        int n = n0 + wc * 48 + j * 16 + l16;
        if (n < N) {
          float val = acc[i][j][v];
          if (BIAS) val += bias[n];
          if (ACT == 1) val = 0.5f * val * (1.f + erff(val * 0.70710678118654752f));
          if (RESID || OUT_BCS) {
            int bb = m / S, pp = m - bb * S;
            size_t oidx = ((size_t)bb * CC + n) * S + pp;
            if (RESID) val += resid[oidx];
            if (OUT_BCS) { Cmat[oidx] = val; continue; }
          }
          Cmat[(size_t)m * N + n] = val;
        }
      }
    }
  }
}

// ------- causal depthwise conv(4) + SiLU, 4 channels per thread ----------
__global__ __launch_bounds__(256) void k_conv(const float* __restrict__ XZ,
    const float* __restrict__ cw, const float* __restrict__ cb,
    float* __restrict__ xc) {
  int t = blockIdx.x * blockDim.x + threadIdx.x;
  if (t >= GG * S * 48) return;
  int q = t % 48; int gl = t / 48; int l = gl % S; int g = gl / S;
  int e0 = q * 4;
  int b = g / 3, dir = g - (g / 3) * 3;
  float cwv[4][4];
#pragma unroll
  for (int i = 0; i < 4; ++i)
    *(float4*)cwv[i] = *(const float4*)&cw[(e0 + i) * 4];
  float4 acc = *(const float4*)&cb[e0];
#pragma unroll
  for (int k = 0; k < 4; ++k) {
    int ls = l + k - 3;
    if (ls >= 0) {
      int p = pos_from_l(dir, ls);
      const float4 xz = *(const float4*)&XZ[((size_t)b * S + p) * 384 + e0];
      acc.x = fmaf(cwv[0][k], xz.x, acc.x);
      acc.y = fmaf(cwv[1][k], xz.y, acc.y);
      acc.z = fmaf(cwv[2][k], xz.z, acc.z);
      acc.w = fmaf(cwv[3][k], xz.w, acc.w);
    }
  }
  acc.x *= 1.f / (1.f + __expf(-acc.x));
  acc.y *= 1.f / (1.f + __expf(-acc.y));
  acc.z *= 1.f / (1.f + __expf(-acc.z));
  acc.w *= 1.f / (1.f + __expf(-acc.w));
  *(float4*)&xc[(size_t)gl * DI + e0] = acc;
}

// ======== scan kernels: pair-split — 2 lanes per (g,e), 8 states each ====
// LDS tile: sBC[l][j]: j 0..5 = dt_r, j 8..23 = B, j 24..39 = C
__device__ __forceinline__ void stage_bc(float (*sBC)[40],
    const float* __restrict__ xdbl, int g, int c, int tid) {
  const float* src = xdbl + ((size_t)g * S + c * LC) * ND;
  for (int i = tid; i < LC * ND; i += 192) {
    int row = i / ND, col = i - row * ND;
    int dst = (col < RK) ? col : col + 2;
    sBC[row][dst] = src[(size_t)row * ND + col];
  }
}

// common per-step prologue: dt via fast softplus
#define DT_COMMON(l)                                                     \
  float a = bde;                                                         \
  {                                                                      \
    float4 r0 = *(const float4*)&sBC[l][0];                              \
    float2 r1 = *(const float2*)&sBC[l][4];                              \
    a = fmaf(wdt[0], r0.x, a); a = fmaf(wdt[1], r0.y, a);                \
    a = fmaf(wdt[2], r0.z, a); a = fmaf(wdt[3], r0.w, a);                \
    a = fmaf(wdt[4], r1.x, a); a = fmaf(wdt[5], r1.y, a);                \
  }                                                                      \
  float d = fmaxf(a, 0.f) + __logf(1.f + __expf(-fabsf(a)));

__global__ __launch_bounds__(192) void k_scanA(const float* __restrict__ xc,
    const float* __restrict__ xdbl, const float* __restrict__ Wdt,
    const float* __restrict__ bdt, const float* __restrict__ A_log,
    float* __restrict__ PA, float* __restrict__ EA) {
  __shared__ float sBC[LC][40];
  int c = blockIdx.x, g = blockIdx.y;
  int tid = threadIdx.x;
  int e = blockIdx.z * 96 + (tid >> 1);
  int hf = tid & 1;
  stage_bc(sBC, xdbl, g, c, tid);
  float wdt[RK];
#pragma unroll
  for (int r = 0; r < RK; ++r) wdt[r] = Wdt[e * RK + r];
  float bde = bdt[e];
  float base = -__expf(A_log[e * NS]);
  bool fast = true;
#pragma unroll
  for (int s = 1; s < NS; ++s) {
    float aes = -__expf(A_log[e * NS + s]);
    fast = fast && (fabsf(aes / base - (float)(s + 1)) < 1e-3f);
  }
  f32x2 h2[4];
#pragma unroll
  for (int k = 0; k < 4; ++k) h2[k] = (f32x2){0.f, 0.f};
  float T = 0.f;
  const float* xptr = xc + ((size_t)g * S + c * LC) * DI + e;
  __syncthreads();
  if (fast) {
    for (int l0 = 0; l0 < LC; l0 += 8) {
      float xb[8];
#pragma unroll
      for (int j = 0; j < 8; ++j) xb[j] = xptr[(size_t)(l0 + j) * DI];
#pragma unroll
      for (int j = 0; j < 8; ++j) {
        int l = l0 + j;
        DT_COMMON(l)
        T += d;
        float w = d * xb[j];
        float r = __expf(d * base);
        float r2 = r * r, r4 = r2 * r2, r8 = r4 * r4;
        float f = hf ? r8 * r : r;        // r^(8*hf+1)
        f32x2 m0 = {f, f * r};
        f32x2 r2v = {r2, r2};
        f32x2 r4v = {r4, r4};
        f32x2 m1 = m0 * r2v, m2 = m0 * r4v, m3 = m1 * r4v;
        f32x2 wv = {w, w};
        float4 Ba = *(const float4*)&sBC[l][8 + hf * 8];
        float4 Bb = *(const float4*)&sBC[l][12 + hf * 8];
        h2[0] = m0 * h2[0] + wv * (f32x2){Ba.x, Ba.y};
        h2[1] = m1 * h2[1] + wv * (f32x2){Ba.z, Ba.w};
        h2[2] = m2 * h2[2] + wv * (f32x2){Bb.x, Bb.y};
        h2[3] = m3 * h2[3] + wv * (f32x2){Bb.z, Bb.w};
      }
    }
  } else {
    float Aes[8];
#pragma unroll
    for (int k = 0; k < 8; ++k) Aes[k] = -__expf(A_log[e * NS + hf * 8 + k]);
#pragma unroll 1
    for (int l = 0; l < LC; ++l) {
      DT_COMMON(l)
      T += d;
      float w = d * xptr[(size_t)l * DI];
#pragma unroll
      for (int k = 0; k < 8; ++k) {
        float q = __expf(d * Aes[k]);
        h2[k >> 1][k & 1] = fmaf(q, h2[k >> 1][k & 1], w * sBC[l][8 + hf * 8 + k]);
      }
    }
  }
  float* pp = PA + (((size_t)g * NC + c) * DI + e) * NS + hf * 8;
  float* ep = EA + (((size_t)g * NC + c) * DI + e) * NS + hf * 8;
  float po[8];
  if (fast) {
    float r = __expf(base * T);
    float r2 = r * r, r4 = r2 * r2, r8 = r4 * r4;
    float f = hf ? r8 * r : r;
    po[0] = f; po[1] = f * r; po[2] = f * r2; po[3] = po[1] * r2;
    po[4] = f * r4; po[5] = po[1] * r4; po[6] = po[2] * r4; po[7] = po[3] * r4;
  } else {
#pragma unroll
    for (int k = 0; k < 8; ++k)
      po[k] = __expf(-__expf(A_log[e * NS + hf * 8 + k]) * T);
  }
  *(float4*)&pp[0] = make_float4(po[0], po[1], po[2], po[3]);
  *(float4*)&pp[4] = make_float4(po[4], po[5], po[6], po[7]);
  *(float4*)&ep[0] = make_float4(h2[0][0], h2[0][1], h2[1][0], h2[1][1]);
  *(float4*)&ep[4] = make_float4(h2[2][0], h2[2][1], h2[3][0], h2[3][1]);
}

// inter-chunk sequential combine (Hin aliases PA: loads precede stores)
__global__ __launch_bounds__(256) void k_scanB(const float* PA,
    const float* EA, float* Hin) {
  int idx = blockIdx.x * blockDim.x + threadIdx.x;
  if (idx >= GG * DI * NS) return;
  int g = idx / (DI * NS); int es = idx - g * (DI * NS);
  size_t stride = (size_t)DI * NS;
  size_t b0 = (size_t)g * NC * stride + es;
  float h = 0.f;
  for (int c0 = 0; c0 < NC; c0 += 8) {
    float p8[8], e8[8];
#pragma unroll
    for (int j = 0; j < 8; ++j) {
      size_t ix = b0 + (size_t)(c0 + j) * stride;
      p8[j] = PA[ix]; e8[j] = EA[ix];
    }
#pragma unroll
    for (int j = 0; j < 8; ++j) {
      size_t ix = b0 + (size_t)(c0 + j) * stride;
      Hin[ix] = h;
      h = fmaf(p8[j], h, e8[j]);
    }
  }
}

__global__ __launch_bounds__(192) void k_scanC(const float* __restrict__ xc,
    const float* __restrict__ xdbl, const float* __restrict__ Wdt,
    const float* __restrict__ bdt, const float* __restrict__ A_log,
    const float* __restrict__ Hin, const float* __restrict__ Dp,
    float* __restrict__ yg) {
  __shared__ float sBC[LC][40];
  int c = blockIdx.x, g = blockIdx.y;
  int tid = threadIdx.x;
  int e = blockIdx.z * 96 + (tid >> 1);
  int hf = tid & 1;
  const float* hp = Hin + (((size_t)g * NC + c) * DI + e) * NS + hf * 8;
  float4 h0 = *(const float4*)(hp + 0);
  float4 h1v = *(const float4*)(hp + 4);
  stage_bc(sBC, xdbl, g, c, tid);
  float wdt[RK];
#pragma unroll
  for (int r = 0; r < RK; ++r) wdt[r] = Wdt[e * RK + r];
  float bde = bdt[e];
  float dpe = Dp[e];
  float base = -__expf(A_log[e * NS]);
  bool fast = true;
#pragma unroll
  for (int s = 1; s < NS; ++s) {
    float aes = -__expf(A_log[e * NS + s]);
    fast = fast && (fabsf(aes / base - (float)(s + 1)) < 1e-3f);
  }
  f32x2 h2[4] = {{h0.x, h0.y}, {h0.z, h0.w}, {h1v.x, h1v.y}, {h1v.z, h1v.w}};
  const float* xptr = xc + ((size_t)g * S + c * LC) * DI + e;
  int b = g / 3, dir = g - (g / 3) * 3;
  float* yo = yg + ((size_t)b * S + c * LC) * 576 + dir * DI + e;
  __syncthreads();
  if (fast) {
    for (int l0 = 0; l0 < LC; l0 += 8) {
      float xb[8];
#pragma unroll
      for (int j = 0; j < 8; ++j) xb[j] = xptr[(size_t)(l0 + j) * DI];
#pragma unroll
      for (int j = 0; j < 8; ++j) {
        int l = l0 + j;
        DT_COMMON(l)
        float xv = xb[j];
        float w = d * xv;
        float r = __expf(d * base);
        float r2 = r * r, r4 = r2 * r2, r8 = r4 * r4;
        float f = hf ? r8 * r : r;        // r^(8*hf+1)
        f32x2 m0 = {f, f * r};
        f32x2 r2v = {r2, r2};
        f32x2 r4v = {r4, r4};
        f32x2 m1 = m0 * r2v, m2 = m0 * r4v, m3 = m1 * r4v;
        f32x2 wv = {w, w};
        float4 Ba = *(const float4*)&sBC[l][8 + hf * 8];
        float4 Bb = *(const float4*)&sBC[l][12 + hf * 8];
        float4 Ca = *(const float4*)&sBC[l][24 + hf * 8];
        float4 Cb = *(const float4*)&sBC[l][28 + hf * 8];
        f32x2 yacc = {hf ? 0.f : xv * dpe, 0.f};
        h2[0] = m0 * h2[0] + wv * (f32x2){Ba.x, Ba.y};
        yacc += h2[0] * (f32x2){Ca.x, Ca.y};
        h2[1] = m1 * h2[1] + wv * (f32x2){Ba.z, Ba.w};
        yacc += h2[1] * (f32x2){Ca.z, Ca.w};
        h2[2] = m2 * h2[2] + wv * (f32x2){Bb.x, Bb.y};
        yacc += h2[2] * (f32x2){Cb.x, Cb.y};
        h2[3] = m3 * h2[3] + wv * (f32x2){Bb.z, Bb.w};
        yacc += h2[3] * (f32x2){Cb.z, Cb.w};
        float ysum = pair_sum(yacc[0] + yacc[1]);
        if (!hf) yo[(size_t)l * 576] = ysum;
      }
    }
  } else {
    float Aes[8];
#pragma unroll
    for (int k = 0; k < 8; ++k) Aes[k] = -__expf(A_log[e * NS + hf * 8 + k]);
#pragma unroll 1
    for (int l = 0; l < LC; ++l) {
      DT_COMMON(l)
      float xv = xptr[(size_t)l * DI];
      float w = d * xv;
      float y = hf ? 0.f : xv * dpe;
#pragma unroll
      for (int k = 0; k < 8; ++k) {
        float q = __expf(d * Aes[k]);
        float hk = fmaf(q, h2[k >> 1][k & 1], w * sBC[l][8 + hf * 8 + k]);
        h2[k >> 1][k & 1] = hk;
        y = fmaf(hk, sBC[l][24 + hf * 8 + k], y);
      }
      float ysum = pair_sum(y);
      if (!hf) yo[(size_t)l * 576] = ysum;
    }
  }
}

// ---------------- fold Wout into proj_w: Mcat[o, dir*192+e] --------------
__global__ __launch_bounds__(256) void k_foldW(const float* __restrict__ proj_w,
    const float* __restrict__ Wout, float* __restrict__ Mcat) {
  int t = blockIdx.x * blockDim.x + threadIdx.x;
  if (t >= CC * 576) return;
  int o = t / 576; int j = t - o * 576; int dir = j / DI; int e = j - dir * DI;
  float a = 0.f;
  for (int c2 = 0; c2 < CC; ++c2)
    a = fmaf(proj_w[o * 288 + dir * CC + c2], Wout[c2 * DI + e], a);
  Mcat[t] = a;
}

extern "C" void kernel_launch(void* const* d_in, const int* in_sizes, int n_in,
                              void* d_out, int out_size, void* d_ws, size_t ws_size,
                              hipStream_t stream) {
  const float* x      = (const float*)d_in[0];
  const float* ln_w   = (const float*)d_in[1];
  const float* ln_b   = (const float*)d_in[2];
  const float* mln_w  = (const float*)d_in[3];
  const float* mln_b  = (const float*)d_in[4];
  const float* Win    = (const float*)d_in[5];
  const float* conv_w = (const float*)d_in[6];
  const float* conv_b = (const float*)d_in[7];
  const float* Wx     = (const float*)d_in[8];
  const float* Wdt    = (const float*)d_in[9];
  const float* bdt    = (const float*)d_in[10];
  const float* A_log  = (const float*)d_in[11];
  const float* Dp     = (const float*)d_in[12];
  const float* Wout   = (const float*)d_in[13];
  const float* proj_w = (const float*)d_in[14];
  const float* proj_b = (const float*)d_in[15];
  const float* fc1_w  = (const float*)d_in[16];
  const float* fc1_b  = (const float*)d_in[17];
  const float* fc2_w  = (const float*)d_in[18];
  const float* fc2_b  = (const float*)d_in[19];

  float* ws = (float*)d_ws;
  size_t off = 0;
  float* xn   = ws + off; off += (size_t)BB * S * CC;       // 1.536M
  float* XZ   = ws + off; off += (size_t)BB * S * 384;      // 6.144M
  float* xc   = ws + off; off += (size_t)GG * S * DI;       // 9.216M
  float* xdbl = ws + off; off += (size_t)GG * S * ND;       // 1.824M
  float* PA   = ws + off; off += (size_t)GG * NC * DI * NS; // 3.686M
  float* EA   = ws + off; off += (size_t)GG * NC * DI * NS; // 3.686M
  float* yg   = ws + off; off += (size_t)BB * S * 576;      // 9.216M
  float* Mcat = ws + off; off += (size_t)CC * 576;
  if (ws_size < off * sizeof(float)) return;                // ~142 MB; guard
  float* Hin  = PA;     // in-place in scanB (group loads precede stores)
  float* ores = xn;     // xn dead after Win GEMM
  float* xln2 = xc;     // xc dead after scanC
  float* h1   = XZ;     // XZ dead after proj (gate fused there)

  k_ln2<<<(BB * S + 255) / 256, 256, 0, stream>>>(x, ln_w, ln_b, mln_w, mln_b, xn);
  k_mfma<0, false, false, false, false>
      <<<dim3(BB * S / 64, 4), 256, 0, stream>>>(
      xn, Win, nullptr, nullptr, nullptr, XZ, BB * S, 384, CC);
  k_conv<<<(GG * S * 48 + 255) / 256, 256, 0, stream>>>(XZ, conv_w, conv_b, xc);
  k_mfma<0, false, false, false, false>
      <<<dim3(GG * S / 64, 1), 256, 0, stream>>>(
      xc, Wx, nullptr, nullptr, nullptr, xdbl, GG * S, ND, DI);
  k_scanA<<<dim3(NC, GG, 2), 192, 0, stream>>>(xc, xdbl, Wdt, bdt, A_log, PA, EA);
  k_scanB<<<(GG * DI * NS + 255) / 256, 256, 0, stream>>>(PA, EA, Hin);
  k_scanC<<<dim3(NC, GG, 2), 192, 0, stream>>>(xc, xdbl, Wdt, bdt, A_log, Hin, Dp, yg);
  k_foldW<<<(CC * 576 + 255) / 256, 256, 0, stream>>>(proj_w, Wout, Mcat);
  k_mfma<0, true, true, true, true>
      <<<dim3(BB * S / 64, 1), 256, 0, stream>>>(
      yg, Mcat, proj_b, x, XZ, ores, BB * S, CC, 576);
  k_ln1<<<(BB * S + 255) / 256, 256, 0, stream>>>(ores, ln_w, ln_b, xln2);
  k_mfma<1, true, false, false, false>
      <<<dim3(BB * S / 64, 4), 256, 0, stream>>>(
      xln2, fc1_w, fc1_b, nullptr, nullptr, h1, BB * S, 384, CC);
  k_mfma<0, true, true, true, false>
      <<<dim3(BB * S / 64, 1), 256, 0, stream>>>(
      h1, fc2_w, fc2_b, ores, nullptr, (float*)d_out, BB * S, CC, 384);
}

// Round 12
// 267.854 us; speedup vs baseline: 1.8459x; 1.0568x over previous
//
#include <hip/hip_runtime.h>
#include <math.h>

// Problem constants (fixed by reference)
#define S   8000     // L = 20*20*20
#define BB  2
#define CC  96
#define DI  192      // d_inner
#define NS  16       // d_state
#define RK  6        // dt_rank
#define GG  6        // B * 3 directions
#define NC  200      // scan chunks
#define LC  40       // chunk length
#define ND  38       // dt_rank + 2*d_state

typedef __attribute__((ext_vector_type(8))) short bf16x8;
typedef __attribute__((ext_vector_type(4))) float f32x4;
typedef __attribute__((ext_vector_type(2))) float f32x2;

// l -> pos mapping per direction.
__device__ __forceinline__ int pos_from_l(int dir, int l) {
  if (dir == 0) return l;
  int a  = l / 400;
  int r  = l - a * 400;
  int bq = r / 20;
  int cq = r - bq * 20;
  if (dir == 1) return cq * 400 + a * 20 + bq;   // (h=a, w=bq, d=cq)
  return bq * 400 + cq * 20 + a;                 // (w=a, d=bq, h=cq)
}

__device__ __forceinline__ float silu(float z) {
  return z / (1.f + __expf(-z));
}

// f32 -> bf16 with round-to-nearest-even
__device__ __forceinline__ unsigned short f2bf(float x) {
  unsigned int u = __float_as_uint(x);
  u += 0x7FFFu + ((u >> 16) & 1u);
  return (unsigned short)(u >> 16);
}
__device__ __forceinline__ float bf2f(unsigned short h) {
  return __uint_as_float((unsigned int)h << 16);
}

// sum across lane pairs (xor 1) via DPP quad_perm [1,0,3,2]
__device__ __forceinline__ float pair_sum(float y) {
  return y + __int_as_float(__builtin_amdgcn_update_dpp(
      0, __float_as_int(y), 0xB1, 0xF, 0xF, true));
}
// sum across quads of 4 lanes (all 4 end with total)
__device__ __forceinline__ float quad_sum(float x) {
  x += __int_as_float(__builtin_amdgcn_update_dpp(0, __float_as_int(x), 0xB1, 0xF, 0xF, true));
  x += __int_as_float(__builtin_amdgcn_update_dpp(0, __float_as_int(x), 0x4E, 0xF, 0xF, true));
  return x;
}

// ======== fused LayerNorm + bf16 MFMA GEMM over K=CC=96 ==================
// C[M,N] = act(LN(Xsrc)[M,96] @ Bw[N,96]^T + bias); Xsrc layout (B,CC,S).
// DOUBLE: ln(ln_w,ln_b,1e-6) then mln(mlnw,mlnb,1e-5). OUTBF16: bf16 out.
template <int ACT, bool DOUBLE, bool OUTBF16>
__global__ __launch_bounds__(256) void k_lnmfma(const float* __restrict__ Xsrc,
    const float* __restrict__ lnw, const float* __restrict__ lnb,
    const float* __restrict__ mlnw, const float* __restrict__ mlnb,
    const float* __restrict__ Bw, const float* __restrict__ bias,
    void* __restrict__ Cout, int M, int N) {
  __shared__ float Xf[64][97];
  __shared__ unsigned short Al[64][104];
  __shared__ unsigned short Bl[96][104];
  int tid = threadIdx.x;
  int m0 = blockIdx.x * 64, n0 = blockIdx.y * 96;
  int b = m0 / S, pos0 = m0 - b * S;    // S%64==0 -> whole block same b
  // stage X rows (coalesced over pos)
  for (int idx = tid; idx < 64 * 96; idx += 256) {
    int row = idx & 63, c = idx >> 6;
    Xf[row][c] = Xsrc[((size_t)b * CC + c) * S + pos0 + row];
  }
  // stage B -> bf16
  for (int idx = tid; idx < 96 * 24; idx += 256) {
    int bn = idx / 24, kq = idx - bn * 24;
    int n = n0 + bn;
    float4 v = make_float4(0.f, 0.f, 0.f, 0.f);
    if (n < N) v = *(const float4*)&Bw[(size_t)n * 96 + kq * 4];
    unsigned short* dst = &Bl[bn][kq * 4];
    dst[0] = f2bf(v.x); dst[1] = f2bf(v.y);
    dst[2] = f2bf(v.z); dst[3] = f2bf(v.w);
  }
  __syncthreads();
  // LN: 4 lanes per row
  {
    int row = tid >> 2, part = tid & 3;
    const float* xr = &Xf[row][part * 24];
    float s1 = 0.f, s2 = 0.f;
#pragma unroll
    for (int i = 0; i < 24; ++i) { float v = xr[i]; s1 += v; s2 += v * v; }
    s1 = quad_sum(s1); s2 = quad_sum(s2);
    float u = s1 * (1.f / 96.f);
    float var = s2 * (1.f / 96.f) - u * u;
    float rstd = rsqrtf(var + 1e-6f);
    if (DOUBLE) {
      float t1 = 0.f, t2 = 0.f;
#pragma unroll
      for (int i = 0; i < 24; ++i) {
        int c = part * 24 + i;
        float y1 = fmaf(lnw[c], (xr[i] - u) * rstd, lnb[c]);
        t1 += y1; t2 += y1 * y1;
      }
      t1 = quad_sum(t1); t2 = quad_sum(t2);
      float u2 = t1 * (1.f / 96.f);
      float var2 = t2 * (1.f / 96.f) - u2 * u2;
      float rstd2 = rsqrtf(var2 + 1e-5f);
#pragma unroll
      for (int i = 0; i < 24; ++i) {
        int c = part * 24 + i;
        float y1 = fmaf(lnw[c], (xr[i] - u) * rstd, lnb[c]);
        Al[row][c] = f2bf(fmaf(mlnw[c], (y1 - u2) * rstd2, mlnb[c]));
      }
    } else {
#pragma unroll
      for (int i = 0; i < 24; ++i) {
        int c = part * 24 + i;
        Al[row][c] = f2bf(fmaf(lnw[c], (xr[i] - u) * rstd, lnb[c]));
      }
    }
  }
  __syncthreads();
  int wid = tid >> 6, lane = tid & 63;
  int wr = wid >> 1, wc = wid & 1;
  int l16 = lane & 15, lk = (lane >> 4) * 8;
  f32x4 acc[2][3];
#pragma unroll
  for (int i = 0; i < 2; ++i)
#pragma unroll
    for (int j = 0; j < 3; ++j) acc[i][j] = (f32x4){0.f, 0.f, 0.f, 0.f};
#pragma unroll
  for (int kc = 0; kc < 96; kc += 32) {
    bf16x8 af[2], bfr[3];
#pragma unroll
    for (int i = 0; i < 2; ++i)
      af[i] = *(const bf16x8*)&Al[wr * 32 + i * 16 + l16][kc + lk];
#pragma unroll
    for (int j = 0; j < 3; ++j)
      bfr[j] = *(const bf16x8*)&Bl[wc * 48 + j * 16 + l16][kc + lk];
#pragma unroll
    for (int i = 0; i < 2; ++i)
#pragma unroll
      for (int j = 0; j < 3; ++j)
        acc[i][j] = __builtin_amdgcn_mfma_f32_16x16x32_bf16(
            af[i], bfr[j], acc[i][j], 0, 0, 0);
  }
#pragma unroll
  for (int i = 0; i < 2; ++i) {
#pragma unroll
    for (int j = 0; j < 3; ++j) {
#pragma unroll
      for (int v = 0; v < 4; ++v) {
        int m = m0 + wr * 32 + i * 16 + (lane >> 4) * 4 + v;
        int n = n0 + wc * 48 + j * 16 + l16;
        if (n < N) {
          float val = acc[i][j][v];
          val += bias ? bias[n] : 0.f;
          if (ACT == 1) val = 0.5f * val * (1.f + erff(val * 0.70710678118654752f));
          if (OUTBF16) ((unsigned short*)Cout)[(size_t)m * N + n] = f2bf(val);
          else         ((float*)Cout)[(size_t)m * N + n] = val;
        }
      }
    }
  }
}

// -------- bf16 MFMA GEMM: C[M,N] = act(A[M,K] @ Bw[N,K]^T + bias) --------
// BM=64, BN=96, BK=32. ABF16: A is bf16. GATEA: A *= silu(z gathered).
#define BKP 40   // 32 + 8 pad (ushorts)
template <int ACT, bool BIAS, bool RESID, bool OUT_BCS, bool GATEA, bool ABF16>
__global__ __launch_bounds__(256) void k_mfma(const void* __restrict__ Ap,
    const float* __restrict__ Bw, const float* __restrict__ bias,
    const float* __restrict__ resid, const float* __restrict__ XZg,
    float* __restrict__ Cmat, int M, int N, int K) {
  __shared__ unsigned short Al[64][BKP];
  __shared__ unsigned short Bl[96][BKP];
  int tid = threadIdx.x;
  int m0 = blockIdx.x * 64, n0 = blockIdx.y * 96;
  int wid = tid >> 6, lane = tid & 63;
  int wr = wid >> 1, wc = wid & 1;
  int l16 = lane & 15, lk = (lane >> 4) * 8;
  f32x4 acc[2][3];
#pragma unroll
  for (int i = 0; i < 2; ++i)
#pragma unroll
    for (int j = 0; j < 3; ++j) acc[i][j] = (f32x4){0.f, 0.f, 0.f, 0.f};

  for (int kk = 0; kk < K; kk += 32) {
    if (ABF16) {
      // 64 rows x 4 uint4 (8 bf16 each) = 256 loads
      int row = tid >> 2, kq = tid & 3;
      int m = m0 + row;
      const unsigned short* As = (const unsigned short*)Ap;
      uint4 v = *(const uint4*)&As[(size_t)m * K + kk + kq * 8];
      if (GATEA) {
        unsigned short* pv = (unsigned short*)&v;
        int bb = m / S, ll = m - bb * S;
        int j = kk + kq * 8;
        int dir = j / DI; int e0 = j - dir * DI;
        int p = pos_from_l(dir, ll);
        const float4 z1 = *(const float4*)&XZg[((size_t)bb * S + p) * 384 + DI + e0];
        const float4 z2 = *(const float4*)&XZg[((size_t)bb * S + p) * 384 + DI + e0 + 4];
        pv[0] = f2bf(bf2f(pv[0]) * silu(z1.x));
        pv[1] = f2bf(bf2f(pv[1]) * silu(z1.y));
        pv[2] = f2bf(bf2f(pv[2]) * silu(z1.z));
        pv[3] = f2bf(bf2f(pv[3]) * silu(z1.w));
        pv[4] = f2bf(bf2f(pv[4]) * silu(z2.x));
        pv[5] = f2bf(bf2f(pv[5]) * silu(z2.y));
        pv[6] = f2bf(bf2f(pv[6]) * silu(z2.z));
        pv[7] = f2bf(bf2f(pv[7]) * silu(z2.w));
      }
      *(uint4*)&Al[row][kq * 8] = v;
    } else {
#pragma unroll
      for (int i = 0; i < 2; ++i) {
        int idx = tid + i * 256;
        int row = idx >> 3, kq = idx & 7;
        int m = m0 + row;
        const float* Af = (const float*)Ap;
        float4 v = *(const float4*)&Af[(size_t)m * K + kk + kq * 4];
        unsigned short* dst = &Al[row][kq * 4];
        dst[0] = f2bf(v.x); dst[1] = f2bf(v.y);
        dst[2] = f2bf(v.z); dst[3] = f2bf(v.w);
      }
    }
#pragma unroll
    for (int i = 0; i < 3; ++i) {
      int idx = tid + i * 256;
      int bn = idx >> 3, kq = idx & 7;
      int n = n0 + bn;
      float4 v = make_float4(0.f, 0.f, 0.f, 0.f);
      if (n < N) v = *(const float4*)&Bw[(size_t)n * K + kk + kq * 4];
      unsigned short* dst = &Bl[bn][kq * 4];
      dst[0] = f2bf(v.x); dst[1] = f2bf(v.y);
      dst[2] = f2bf(v.z); dst[3] = f2bf(v.w);
    }
    __syncthreads();
    bf16x8 af[2], bfr[3];
#pragma unroll
    for (int i = 0; i < 2; ++i)
      af[i] = *(const bf16x8*)&Al[wr * 32 + i * 16 + l16][lk];
#pragma unroll
    for (int j = 0; j < 3; ++j)
      bfr[j] = *(const bf16x8*)&Bl[wc * 48 + j * 16 + l16][lk];
#pragma unroll
    for (int i = 0; i < 2; ++i)
#pragma unroll
      for (int j = 0; j < 3; ++j)
        acc[i][j] = __builtin_amdgcn_mfma_f32_16x16x32_bf16(
            af[i], bfr[j], acc[i][j], 0, 0, 0);
    __syncthreads();
  }
#pragma unroll
  for (int i = 0; i < 2; ++i) {
#pragma unroll
    for (int j = 0; j < 3; ++j) {
#pragma unroll
      for (int v = 0; v < 4; ++v) {
        int m = m0 + wr * 32 + i * 16 + (lane >> 4) * 4 + v;
        int n = n0 + wc * 48 + j * 16 + l16;
        if (n < N) {
          float val = acc[i][j][v];
          if (BIAS) val += bias[n];
          if (ACT == 1) val = 0.5f * val * (1.f + erff(val * 0.70710678118654752f));
          if (RESID || OUT_BCS) {
            int bb = m / S, pp = m - bb * S;
            size_t oidx = ((size_t)bb * CC + n) * S + pp;
            if (RESID) val += resid[oidx];
            if (OUT_BCS) { Cmat[oidx] = val; continue; }
          }
          Cmat[(size_t)m * N + n] = val;
        }
      }
    }
  }
}

// ------- causal depthwise conv(4) + SiLU, 4 channels per thread ----------
__global__ __launch_bounds__(256) void k_conv(const float* __restrict__ XZ,
    const float* __restrict__ cw, const float* __restrict__ cb,
    float* __restrict__ xc) {
  int t = blockIdx.x * blockDim.x + threadIdx.x;
  if (t >= GG * S * 48) return;
  int q = t % 48; int gl = t / 48; int l = gl % S; int g = gl / S;
  int e0 = q * 4;
  int b = g / 3, dir = g - (g / 3) * 3;
  float cwv[4][4];
#pragma unroll
  for (int i = 0; i < 4; ++i)
    *(float4*)cwv[i] = *(const float4*)&cw[(e0 + i) * 4];
  float4 acc = *(const float4*)&cb[e0];
#pragma unroll
  for (int k = 0; k < 4; ++k) {
    int ls = l + k - 3;
    if (ls >= 0) {
      int p = pos_from_l(dir, ls);
      const float4 xz = *(const float4*)&XZ[((size_t)b * S + p) * 384 + e0];
      acc.x = fmaf(cwv[0][k], xz.x, acc.x);
      acc.y = fmaf(cwv[1][k], xz.y, acc.y);
      acc.z = fmaf(cwv[2][k], xz.z, acc.z);
      acc.w = fmaf(cwv[3][k], xz.w, acc.w);
    }
  }
  acc.x *= 1.f / (1.f + __expf(-acc.x));
  acc.y *= 1.f / (1.f + __expf(-acc.y));
  acc.z *= 1.f / (1.f + __expf(-acc.z));
  acc.w *= 1.f / (1.f + __expf(-acc.w));
  *(float4*)&xc[(size_t)gl * DI + e0] = acc;
}

// ======== scan kernels: pair-split — 2 lanes per (g,e), 8 states each ====
// LDS tile: sBC[l][j]: j 0..5 = dt_r, j 8..23 = B, j 24..39 = C
__device__ __forceinline__ void stage_bc(float (*sBC)[40],
    const float* __restrict__ xdbl, int g, int c, int tid) {
  const float* src = xdbl + ((size_t)g * S + c * LC) * ND;
  for (int i = tid; i < LC * ND; i += 192) {
    int row = i / ND, col = i - row * ND;
    int dst = (col < RK) ? col : col + 2;
    sBC[row][dst] = src[(size_t)row * ND + col];
  }
}

// common per-step prologue: dt via fast softplus
#define DT_COMMON(l)                                                     \
  float a = bde;                                                         \
  {                                                                      \
    float4 r0 = *(const float4*)&sBC[l][0];                              \
    float2 r1 = *(const float2*)&sBC[l][4];                              \
    a = fmaf(wdt[0], r0.x, a); a = fmaf(wdt[1], r0.y, a);                \
    a = fmaf(wdt[2], r0.z, a); a = fmaf(wdt[3], r0.w, a);                \
    a = fmaf(wdt[4], r1.x, a); a = fmaf(wdt[5], r1.y, a);                \
  }                                                                      \
  float d = fmaxf(a, 0.f) + __logf(1.f + __expf(-fabsf(a)));

__global__ __launch_bounds__(192) void k_scanA(const float* __restrict__ xc,
    const float* __restrict__ xdbl, const float* __restrict__ Wdt,
    const float* __restrict__ bdt, const float* __restrict__ A_log,
    float* __restrict__ PA, float* __restrict__ EA) {
  __shared__ float sBC[LC][40];
  int c = blockIdx.x, g = blockIdx.y;
  int tid = threadIdx.x;
  int e = blockIdx.z * 96 + (tid >> 1);
  int hf = tid & 1;
  stage_bc(sBC, xdbl, g, c, tid);
  float wdt[RK];
#pragma unroll
  for (int r = 0; r < RK; ++r) wdt[r] = Wdt[e * RK + r];
  float bde = bdt[e];
  float base = -__expf(A_log[e * NS]);
  bool fast = true;
#pragma unroll
  for (int s = 1; s < NS; ++s) {
    float aes = -__expf(A_log[e * NS + s]);
    fast = fast && (fabsf(aes / base - (float)(s + 1)) < 1e-3f);
  }
  f32x2 h2[4];
#pragma unroll
  for (int k = 0; k < 4; ++k) h2[k] = (f32x2){0.f, 0.f};
  float T = 0.f;
  const float* xptr = xc + ((size_t)g * S + c * LC) * DI + e;
  __syncthreads();
  if (fast) {
    for (int l0 = 0; l0 < LC; l0 += 8) {
      float xb[8];
#pragma unroll
      for (int j = 0; j < 8; ++j) xb[j] = xptr[(size_t)(l0 + j) * DI];
#pragma unroll
      for (int j = 0; j < 8; ++j) {
        int l = l0 + j;
        DT_COMMON(l)
        T += d;
        float w = d * xb[j];
        float r = __expf(d * base);
        float r2 = r * r, r4 = r2 * r2, r8 = r4 * r4;
        float f = hf ? r8 * r : r;        // r^(8*hf+1)
        f32x2 m0 = {f, f * r};
        f32x2 r2v = {r2, r2};
        f32x2 r4v = {r4, r4};
        f32x2 m1 = m0 * r2v, m2 = m0 * r4v, m3 = m1 * r4v;
        f32x2 wv = {w, w};
        float4 Ba = *(const float4*)&sBC[l][8 + hf * 8];
        float4 Bb = *(const float4*)&sBC[l][12 + hf * 8];
        h2[0] = m0 * h2[0] + wv * (f32x2){Ba.x, Ba.y};
        h2[1] = m1 * h2[1] + wv * (f32x2){Ba.z, Ba.w};
        h2[2] = m2 * h2[2] + wv * (f32x2){Bb.x, Bb.y};
        h2[3] = m3 * h2[3] + wv * (f32x2){Bb.z, Bb.w};
      }
    }
  } else {
    float Aes[8];
#pragma unroll
    for (int k = 0; k < 8; ++k) Aes[k] = -__expf(A_log[e * NS + hf * 8 + k]);
#pragma unroll 1
    for (int l = 0; l < LC; ++l) {
      DT_COMMON(l)
      T += d;
      float w = d * xptr[(size_t)l * DI];
#pragma unroll
      for (int k = 0; k < 8; ++k) {
        float q = __expf(d * Aes[k]);
        h2[k >> 1][k & 1] = fmaf(q, h2[k >> 1][k & 1], w * sBC[l][8 + hf * 8 + k]);
      }
    }
  }
  float* pp = PA + (((size_t)g * NC + c) * DI + e) * NS + hf * 8;
  float* ep = EA + (((size_t)g * NC + c) * DI + e) * NS + hf * 8;
  float po[8];
  if (fast) {
    float r = __expf(base * T);
    float r2 = r * r, r4 = r2 * r2, r8 = r4 * r4;
    float f = hf ? r8 * r : r;
    po[0] = f; po[1] = f * r; po[2] = f * r2; po[3] = po[1] * r2;
    po[4] = f * r4; po[5] = po[1] * r4; po[6] = po[2] * r4; po[7] = po[3] * r4;
  } else {
#pragma unroll
    for (int k = 0; k < 8; ++k)
      po[k] = __expf(-__expf(A_log[e * NS + hf * 8 + k]) * T);
  }
  *(float4*)&pp[0] = make_float4(po[0], po[1], po[2], po[3]);
  *(float4*)&pp[4] = make_float4(po[4], po[5], po[6], po[7]);
  *(float4*)&ep[0] = make_float4(h2[0][0], h2[0][1], h2[1][0], h2[1][1]);
  *(float4*)&ep[4] = make_float4(h2[2][0], h2[2][1], h2[3][0], h2[3][1]);
}

// inter-chunk sequential combine (Hin aliases PA: loads precede stores)
__global__ __launch_bounds__(256) void k_scanB(const float* PA,
    const float* EA, float* Hin) {
  int idx = blockIdx.x * blockDim.x + threadIdx.x;
  if (idx >= GG * DI * NS) return;
  int g = idx / (DI * NS); int es = idx - g * (DI * NS);
  size_t stride = (size_t)DI * NS;
  size_t b0 = (size_t)g * NC * stride + es;
  float h = 0.f;
  for (int c0 = 0; c0 < NC; c0 += 8) {
    float p8[8], e8[8];
#pragma unroll
    for (int j = 0; j < 8; ++j) {
      size_t ix = b0 + (size_t)(c0 + j) * stride;
      p8[j] = PA[ix]; e8[j] = EA[ix];
    }
#pragma unroll
    for (int j = 0; j < 8; ++j) {
      size_t ix = b0 + (size_t)(c0 + j) * stride;
      Hin[ix] = h;
      h = fmaf(p8[j], h, e8[j]);
    }
  }
}

__global__ __launch_bounds__(192) void k_scanC(const float* __restrict__ xc,
    const float* __restrict__ xdbl, const float* __restrict__ Wdt,
    const float* __restrict__ bdt, const float* __restrict__ A_log,
    const float* __restrict__ Hin, const float* __restrict__ Dp,
    unsigned short* __restrict__ ygb) {
  __shared__ float sBC[LC][40];
  int c = blockIdx.x, g = blockIdx.y;
  int tid = threadIdx.x;
  int e = blockIdx.z * 96 + (tid >> 1);
  int hf = tid & 1;
  const float* hp = Hin + (((size_t)g * NC + c) * DI + e) * NS + hf * 8;
  float4 h0 = *(const float4*)(hp + 0);
  float4 h1v = *(const float4*)(hp + 4);
  stage_bc(sBC, xdbl, g, c, tid);
  float wdt[RK];
#pragma unroll
  for (int r = 0; r < RK; ++r) wdt[r] = Wdt[e * RK + r];
  float bde = bdt[e];
  float dpe = Dp[e];
  float base = -__expf(A_log[e * NS]);
  bool fast = true;
#pragma unroll
  for (int s = 1; s < NS; ++s) {
    float aes = -__expf(A_log[e * NS + s]);
    fast = fast && (fabsf(aes / base - (float)(s + 1)) < 1e-3f);
  }
  f32x2 h2[4] = {{h0.x, h0.y}, {h0.z, h0.w}, {h1v.x, h1v.y}, {h1v.z, h1v.w}};
  const float* xptr = xc + ((size_t)g * S + c * LC) * DI + e;
  int b = g / 3, dir = g - (g / 3) * 3;
  unsigned short* yo = ygb + ((size_t)b * S + c * LC) * 576 + dir * DI + e;
  __syncthreads();
  if (fast) {
    for (int l0 = 0; l0 < LC; l0 += 8) {
      float xb[8];
#pragma unroll
      for (int j = 0; j < 8; ++j) xb[j] = xptr[(size_t)(l0 + j) * DI];
#pragma unroll
      for (int j = 0; j < 8; ++j) {
        int l = l0 + j;
        DT_COMMON(l)
        float xv = xb[j];
        float w = d * xv;
        float r = __expf(d * base);
        float r2 = r * r, r4 = r2 * r2, r8 = r4 * r4;
        float f = hf ? r8 * r : r;        // r^(8*hf+1)
        f32x2 m0 = {f, f * r};
        f32x2 r2v = {r2, r2};
        f32x2 r4v = {r4, r4};
        f32x2 m1 = m0 * r2v, m2 = m0 * r4v, m3 = m1 * r4v;
        f32x2 wv = {w, w};
        float4 Ba = *(const float4*)&sBC[l][8 + hf * 8];
        float4 Bb = *(const float4*)&sBC[l][12 + hf * 8];
        float4 Ca = *(const float4*)&sBC[l][24 + hf * 8];
        float4 Cb = *(const float4*)&sBC[l][28 + hf * 8];
        f32x2 yacc = {hf ? 0.f : xv * dpe, 0.f};
        h2[0] = m0 * h2[0] + wv * (f32x2){Ba.x, Ba.y};
        yacc += h2[0] * (f32x2){Ca.x, Ca.y};
        h2[1] = m1 * h2[1] + wv * (f32x2){Ba.z, Ba.w};
        yacc += h2[1] * (f32x2){Ca.z, Ca.w};
        h2[2] = m2 * h2[2] + wv * (f32x2){Bb.x, Bb.y};
        yacc += h2[2] * (f32x2){Cb.x, Cb.y};
        h2[3] = m3 * h2[3] + wv * (f32x2){Bb.z, Bb.w};
        yacc += h2[3] * (f32x2){Cb.z, Cb.w};
        float ysum = pair_sum(yacc[0] + yacc[1]);
        if (!hf) yo[(size_t)l * 576] = f2bf(ysum);
      }
    }
  } else {
    float Aes[8];
#pragma unroll
    for (int k = 0; k < 8; ++k) Aes[k] = -__expf(A_log[e * NS + hf * 8 + k]);
#pragma unroll 1
    for (int l = 0; l < LC; ++l) {
      DT_COMMON(l)
      float xv = xptr[(size_t)l * DI];
      float w = d * xv;
      float y = hf ? 0.f : xv * dpe;
#pragma unroll
      for (int k = 0; k < 8; ++k) {
        float q = __expf(d * Aes[k]);
        float hk = fmaf(q, h2[k >> 1][k & 1], w * sBC[l][8 + hf * 8 + k]);
        h2[k >> 1][k & 1] = hk;
        y = fmaf(hk, sBC[l][24 + hf * 8 + k], y);
      }
      float ysum = pair_sum(y);
      if (!hf) yo[(size_t)l * 576] = f2bf(ysum);
    }
  }
}

// ---------------- fold Wout into proj_w: Mcat[o, dir*192+e] --------------
__global__ __launch_bounds__(256) void k_foldW(const float* __restrict__ proj_w,
    const float* __restrict__ Wout, float* __restrict__ Mcat) {
  int t = blockIdx.x * blockDim.x + threadIdx.x;
  if (t >= CC * 576) return;
  int o = t / 576; int j = t - o * 576; int dir = j / DI; int e = j - dir * DI;
  float a = 0.f;
  for (int c2 = 0; c2 < CC; ++c2)
    a = fmaf(proj_w[o * 288 + dir * CC + c2], Wout[c2 * DI + e], a);
  Mcat[t] = a;
}

extern "C" void kernel_launch(void* const* d_in, const int* in_sizes, int n_in,
                              void* d_out, int out_size, void* d_ws, size_t ws_size,
                              hipStream_t stream) {
  const float* x      = (const float*)d_in[0];
  const float* ln_w   = (const float*)d_in[1];
  const float* ln_b   = (const float*)d_in[2];
  const float* mln_w  = (const float*)d_in[3];
  const float* mln_b  = (const float*)d_in[4];
  const float* Win    = (const float*)d_in[5];
  const float* conv_w = (const float*)d_in[6];
  const float* conv_b = (const float*)d_in[7];
  const float* Wx     = (const float*)d_in[8];
  const float* Wdt    = (const float*)d_in[9];
  const float* bdt    = (const float*)d_in[10];
  const float* A_log  = (const float*)d_in[11];
  const float* Dp     = (const float*)d_in[12];
  const float* Wout   = (const float*)d_in[13];
  const float* proj_w = (const float*)d_in[14];
  const float* proj_b = (const float*)d_in[15];
  const float* fc1_w  = (const float*)d_in[16];
  const float* fc1_b  = (const float*)d_in[17];
  const float* fc2_w  = (const float*)d_in[18];
  const float* fc2_b  = (const float*)d_in[19];

  float* ws = (float*)d_ws;
  size_t off = 0;
  float* ores = ws + off; off += (size_t)BB * S * CC;       // 1.536M
  float* XZ   = ws + off; off += (size_t)BB * S * 384;      // 6.144M (-> h1 bf16)
  float* xc   = ws + off; off += (size_t)GG * S * DI;       // 9.216M
  float* xdbl = ws + off; off += (size_t)GG * S * ND;       // 1.824M
  float* PA   = ws + off; off += (size_t)GG * NC * DI * NS; // 3.686M
  float* EA   = ws + off; off += (size_t)GG * NC * DI * NS; // 3.686M
  float* yg   = ws + off; off += (size_t)BB * S * 576;      // bf16 used (half)
  float* Mcat = ws + off; off += (size_t)CC * 576;
  if (ws_size < off * sizeof(float)) return;                // ~142 MB; guard
  float* Hin  = PA;                       // in-place in scanB
  unsigned short* ygb = (unsigned short*)yg;
  unsigned short* h1  = (unsigned short*)XZ;  // XZ dead after proj staging

  k_lnmfma<0, true, false><<<dim3(BB * S / 64, 4), 256, 0, stream>>>(
      x, ln_w, ln_b, mln_w, mln_b, Win, nullptr, XZ, BB * S, 384);
  k_conv<<<(GG * S * 48 + 255) / 256, 256, 0, stream>>>(XZ, conv_w, conv_b, xc);
  k_mfma<0, false, false, false, false, false>
      <<<dim3(GG * S / 64, 1), 256, 0, stream>>>(
      xc, Wx, nullptr, nullptr, nullptr, xdbl, GG * S, ND, DI);
  k_scanA<<<dim3(NC, GG, 2), 192, 0, stream>>>(xc, xdbl, Wdt, bdt, A_log, PA, EA);
  k_scanB<<<(GG * DI * NS + 255) / 256, 256, 0, stream>>>(PA, EA, Hin);
  k_scanC<<<dim3(NC, GG, 2), 192, 0, stream>>>(xc, xdbl, Wdt, bdt, A_log, Hin, Dp, ygb);
  k_foldW<<<(CC * 576 + 255) / 256, 256, 0, stream>>>(proj_w, Wout, Mcat);
  k_mfma<0, true, true, true, true, true>
      <<<dim3(BB * S / 64, 1), 256, 0, stream>>>(
      ygb, Mcat, proj_b, x, XZ, ores, BB * S, CC, 576);
  k_lnmfma<1, false, true><<<dim3(BB * S / 64, 4), 256, 0, stream>>>(
      ores, ln_w, ln_b, nullptr, nullptr, fc1_w, fc1_b, h1, BB * S, 384);
  k_mfma<0, true, true, true, false, true>
      <<<dim3(BB * S / 64, 1), 256, 0, stream>>>(
      h1, fc2_w, fc2_b, ores, nullptr, (float*)d_out, BB * S, CC, 384);
}